// Round 5
// baseline (451.334 us; speedup 1.0000x reference)
//
#include <hip/hip_runtime.h>
#include <hip/hip_bf16.h>

// EnhancedGNNEncoder round 14: einsum critical-path cut in k_mega.
//  - x[col] staged per-block into LDS (12 KB aliased on S[8..10], dead before
//    phase 2 overwrites). Each lane computes its m1 A-fragment distances
//    D[mr][quad*8+jj] DIRECTLY: sqrt(nr + nc_j - 2 xr.xc_j) from registers +
//    6 broadcast ds_read_b128 (wave-uniform addr). Deletes per edge: G MFMA,
//    4-shfl dD chain, 8-shfl aD transpose (12 of 26 bpermutes, 1 of 3 MFMAs).
//  - Rest of k_mega (rad GEMM in-LDS, MLP stages, roller, scatters) unchanged.
// k_pack / k_node unchanged.
// MFMA 16x16x32: A[m=lane&15][k=quad*8+j], B[k=quad*8+j][n=lane&15],
//                D col=lane&15, row=quad*4+reg.

#define TM 64
#define TN 16
#define PAD 36

typedef __attribute__((ext_vector_type(8))) short bf16x8;
typedef __attribute__((ext_vector_type(4))) float f32x4;

__device__ __forceinline__ float siluf(float v) { return v / (1.f + __expf(-v)); }
__device__ __forceinline__ float sigmf(float v) { return 1.f / (1.f + __expf(-v)); }
__device__ __forceinline__ short f2bs(float f) {
  union { __hip_bfloat16 b; short s; } u;
  u.b = __float2bfloat16(f);
  return u.s;
}
__device__ __forceinline__ __hip_bfloat162 mk_bf162(float v0, float v1) {
  __hip_bfloat162 r;
  r.x = __float2bfloat16(v0);
  r.y = __float2bfloat16(v1);
  return r;
}

// ---- pack: weight swizzle + attrS + h_bf16 + per-node prep ----
__global__ __launch_bounds__(256) void k_pack(
    const float* __restrict__ h, const float* __restrict__ x,
    const float* __restrict__ attr, const float* __restrict__ cw,
    const float* __restrict__ rad_w, const float* __restrict__ e_w1,
    const float* __restrict__ e_w2, const float* __restrict__ c_w1,
    const float* __restrict__ n_w1, const float* __restrict__ n_w2,
    const float* __restrict__ c_w2,
    __hip_bfloat16* __restrict__ wz_rad, __hip_bfloat16* __restrict__ wz_e1,
    __hip_bfloat16* __restrict__ wz_e2, __hip_bfloat16* __restrict__ wz_c1,
    __hip_bfloat16* __restrict__ wz_n1, __hip_bfloat16* __restrict__ wz_n2,
    __hip_bfloat16* __restrict__ wz_c2,
    __hip_bfloat16* __restrict__ attrS, __hip_bfloat16* __restrict__ hb,
    float* __restrict__ pooled_x, int* __restrict__ chsum, int Nn) {
  int idx = blockIdx.x * 256 + threadIdx.x;
  if (idx < 165888) {  // weight swizzle
    int i = idx;
    if (i >= 163840) {  // c_w2: [128][14] -> [4][16][32], n=14,15 zero
      int base = i - 163840;
      int k = base >> 4, n = base & 15;
      wz_c2[(size_t)(k >> 5) * 512 + n * 32 + (k & 31)] =
          (n < 14) ? __float2bfloat16(c_w2[k * 14 + n]) : __float2bfloat16(0.f);
      return;
    }
    const float* W;
    __hip_bfloat16* O;
    int base;
    if (i < 32768) { W = rad_w; O = wz_rad; base = i; }
    else if (i < 81920) { W = e_w1; O = wz_e1; base = i - 32768; }
    else if (i < 98304) { W = e_w2; O = wz_e2; base = i - 81920; }
    else if (i < 114688) { W = c_w1; O = wz_c1; base = i - 98304; }
    else if (i < 147456) { W = n_w1; O = wz_n1; base = i - 114688; }
    else { W = n_w2; O = wz_n2; base = i - 147456; }
    int k = base >> 7, n = base & 127;
    O[(size_t)((k >> 5) * 128 + n) * 32 + (k & 31)] = __float2bfloat16(W[base]);
    return;
  }
  idx -= 165888;
  int na = Nn * 256, nh = Nn * 128;
  if (idx < na) {
    int n = idx >> 8, r = idx & 255, i2 = r >> 4, a = r & 15;
    float v = 0.f;
    if (i2 < 14) v = attr[(size_t)n * 224 + i2 * 16 + a] * cw[(size_t)n * 14 + i2];
    attrS[(size_t)n * 256 + a * 16 + i2] = __float2bfloat16(v);
    return;
  }
  idx -= na;
  if (idx < nh) {
    hb[idx] = __float2bfloat16(h[idx]);
    return;
  }
  idx -= nh;
  if (idx >= Nn) return;
  int n = idx;
  int cnt = 0;
  float sx = 0.f, sy = 0.f, sz = 0.f;
#pragma unroll
  for (int c = 0; c < 14; c++) {
    float w = cw[n * 14 + c];
    if (w != 0.f) {
      cnt++;
      sx += x[n * 42 + c * 3 + 0];
      sy += x[n * 42 + c * 3 + 1];
      sz += x[n * 42 + c * 3 + 2];
    }
  }
  chsum[n] = cnt;
  float inv = 1.f / (float)(cnt > 0 ? cnt : 1);
  pooled_x[n * 3 + 0] = sx * inv;
  pooled_x[n * 3 + 1] = sy * inv;
  pooled_x[n * 3 + 2] = sz * inv;
}

// ---- k_mega: einsum + rad GEMM + edge MLP + gate + roller + scatters ----
// 12 aliased swizzled LDS slots; xc-stage S[8..10] (phase1), radial S[0..7],
// radf S[8..11], then h_row/h_col overwrite S[0..7]. 51.5 KB -> 3 blocks/CU.
__global__ __launch_bounds__(256, 3) void k_mega(
    const __hip_bfloat16* __restrict__ hb, const float* __restrict__ x,
    const __hip_bfloat16* __restrict__ attrS,
    const int* __restrict__ row, const int* __restrict__ col,
    const float* __restrict__ pooled_x, const int* __restrict__ chsum,
    const __hip_bfloat16* __restrict__ wz_rad, const float* __restrict__ rad_b,
    const __hip_bfloat16* __restrict__ wz_e1, const float* __restrict__ e_b1,
    const __hip_bfloat16* __restrict__ wz_e2, const float* __restrict__ e_b2,
    const float* __restrict__ att_w, const float* __restrict__ att_b,
    const __hip_bfloat16* __restrict__ wz_c1, const float* __restrict__ c_b1,
    const __hip_bfloat16* __restrict__ wz_c2, const float* __restrict__ c_b2,
    unsigned* __restrict__ cnt_row, unsigned* __restrict__ cnt_col,
    __hip_bfloat162* __restrict__ x_acc, __hip_bfloat162* __restrict__ agg,
    int Ee) {
  // 12 slots of [64][32] bf16; XOR col-block swizzle: phys_blk = blk ^ ((row>>1)&3)
  __shared__ __hip_bfloat16 S[12][TM][32];
  __shared__ float s_att[TM];
  __shared__ float s_red[4][TM];
  __shared__ float s_rn[TM];
  __shared__ int s_row[TM], s_col[TM], s_cs[TM];
  float* s_cm   = (float*)&S[0][0][0];  // [64*14] f32 (slot 0; ef1 dead there)
  float* s_pool = (float*)&S[1][0][0];  // [64*14] f32 (slot 1)
  float* s_xc   = (float*)&S[8][0][0];  // [64][3][16] f32 = 12 KB (phase 1 only)

  const int t = threadIdx.x;
  const int e0 = blockIdx.x * TM;
  const int ne = min(TM, Ee - e0);
  const int lane = t & 63, wave = t >> 6, quad = lane >> 4, mr = lane & 15;
  const int n0 = wave * 32;
  const f32x4 zacc = {0.f, 0.f, 0.f, 0.f};
  const bf16x8 zero8 = {0, 0, 0, 0, 0, 0, 0, 0};

  // ---- phase 0: edge meta + degree atomics + xc staging ----
  if (t < TM) {
    int ge = e0 + min(t, ne - 1);
    int r = row[ge], c = col[ge];
    s_row[t] = r;
    s_col[t] = c;
    s_cs[t] = chsum[r];
    if (t < ne) {
      atomicAdd(&cnt_row[r], 1u);
      atomicAdd(&cnt_col[c], 1u);
    }
  }
  // xc: [e][comp][chan16], chan>=14 zeroed (killed by attrS zeros downstream)
  for (int i = t; i < TM * 48; i += 256) {
    int e = i / 48, j = i % 48;
    int comp = j >> 4, chan = j & 15;
    int ge = e0 + min(e, ne - 1);
    int ce = col[ge];
    float v = 0.f;
    if (chan < 14) v = x[(size_t)ce * 42 + chan * 3 + comp];
    s_xc[e * 48 + comp * 16 + chan] = v;
  }
  __syncthreads();

  // ---- phase 1: einsum, 16 edges/wave in 4 batches of 4 ----
#pragma unroll 1
  for (int b = 0; b < 4; b++) {
    float xr0v[4], xr1v[4], xr2v[4];
    bf16x8 bCv[4], aRv[4];
#pragma unroll
    for (int p = 0; p < 4; p++) {
      const int e = wave * 16 + b * 4 + p;
      const int ge = e0 + min(e, ne - 1);
      const int re = row[ge], ce = col[ge];  // wave-uniform -> scalar loads
      const int mrc = min(mr, 13);
      const float* xp = x + (size_t)re * 42 + mrc * 3;
      xr0v[p] = xp[0]; xr1v[p] = xp[1]; xr2v[p] = xp[2];
      bCv[p] = zero8; aRv[p] = zero8;
      if (quad < 2) {
        bCv[p] = *(const bf16x8*)&attrS[(size_t)ce * 256 + mr * 16 + quad * 8];
        aRv[p] = *(const bf16x8*)&attrS[(size_t)re * 256 + mr * 16 + quad * 8];
      }
    }
#pragma unroll
    for (int p = 0; p < 4; p++) {
      const int e = wave * 16 + b * 4 + p;
      const float xr0 = xr0v[p], xr1 = xr1v[p], xr2 = xr2v[p];
      const float nr = xr0 * xr0 + xr1 * xr1 + xr2 * xr2;
      // D[mr][quad*8+jj] computed directly (no G MFMA, no transpose shfls)
      bf16x8 aD = zero8;
      if (quad < 2) {
        const float* xcp = s_xc + e * 48 + quad * 8;
        float4 a0 = *(const float4*)(xcp);
        float4 a1 = *(const float4*)(xcp + 4);
        float4 b0 = *(const float4*)(xcp + 16);
        float4 b1 = *(const float4*)(xcp + 20);
        float4 c0 = *(const float4*)(xcp + 32);
        float4 c1 = *(const float4*)(xcp + 36);
        float cxv[8] = {a0.x, a0.y, a0.z, a0.w, a1.x, a1.y, a1.z, a1.w};
        float cyv[8] = {b0.x, b0.y, b0.z, b0.w, b1.x, b1.y, b1.z, b1.w};
        float czv[8] = {c0.x, c0.y, c0.z, c0.w, c1.x, c1.y, c1.z, c1.w};
#pragma unroll
        for (int jj = 0; jj < 8; jj++) {
          float nc = cxv[jj] * cxv[jj] + cyv[jj] * cyv[jj] + czv[jj] * czv[jj];
          float dot = xr0 * cxv[jj] + xr1 * cyv[jj] + xr2 * czv[jj];
          aD[jj] = f2bs(sqrtf(fmaxf(nr + nc - 2.f * dot, 0.f)));
        }
      }
      f32x4 m1 = __builtin_amdgcn_mfma_f32_16x16x32_bf16(aD, bCv[p], zacc, 0, 0, 0);
      bf16x8 bM;
#pragma unroll
      for (int jj = 0; jj < 8; jj++) {
        const int qs = (quad * 2 + (jj >> 2)) & 3;
        float mv = __shfl(m1[jj & 3], (qs << 4) | mr);
        if (quad >= 2) mv = 0.f;
        bM[jj] = f2bs(mv);
      }
      f32x4 rd = __builtin_amdgcn_mfma_f32_16x16x32_bf16(aRv[p], bM, zacc, 0, 0, 0);
      float ss = rd[0] * rd[0] + rd[1] * rd[1] + rd[2] * rd[2] + rd[3] * rd[3];
      ss += __shfl_xor(ss, 32); ss += __shfl_xor(ss, 16); ss += __shfl_xor(ss, 8);
      ss += __shfl_xor(ss, 4);  ss += __shfl_xor(ss, 2);  ss += __shfl_xor(ss, 1);
      if (lane == 0) s_rn[e] = sqrtf(ss) + 1.0f;
      // radial -> S[0..7], slot kb=aa>>1, logical col ((aa&1)<<4)|mr, e-swizzled
#pragma unroll
      for (int r = 0; r < 4; r++) {
        const int aa = quad * 4 + r;
        const int c = ((aa & 1) << 4) | mr;
        const int pcol = (((c >> 3) ^ ((e >> 1) & 3)) << 3) | (c & 7);
        S[aa >> 1][e][pcol] = __float2bfloat16(rd[r]);
      }
    }
  }
  __syncthreads();

  const int acol = ((quad ^ ((mr >> 1) & 3)) << 3);  // swizzled frag-read col

  // ---- phase 2: rad GEMM radial@rad_w -> radf in S[8..11] ----
  {
    f32x4 a0[4], a1[4];
#pragma unroll
    for (int mf = 0; mf < 4; mf++) { a0[mf] = zacc; a1[mf] = zacc; }
#pragma unroll
    for (int kb = 0; kb < 8; kb++) {
      const __hip_bfloat16* wp = wz_rad + ((size_t)(kb * 128 + n0 + mr) * 32 + quad * 8);
      bf16x8 b0 = *(const bf16x8*)wp;
      bf16x8 b1 = *(const bf16x8*)(wp + 16 * 32);
#pragma unroll
      for (int mf = 0; mf < 4; mf++) {
        bf16x8 a = *(const bf16x8*)&S[kb][mf * 16 + mr][acol];
        a0[mf] = __builtin_amdgcn_mfma_f32_16x16x32_bf16(a, b0, a0[mf], 0, 0, 0);
        a1[mf] = __builtin_amdgcn_mfma_f32_16x16x32_bf16(a, b1, a1[mf], 0, 0, 0);
      }
    }
    float rb0 = rad_b[n0 + mr], rb1 = rad_b[n0 + 16 + mr];
#pragma unroll
    for (int mf = 0; mf < 4; mf++)
#pragma unroll
      for (int r = 0; r < 4; r++) {
        int e = mf * 16 + quad * 4 + r;
        int es = (e >> 1) & 3;
        int c0 = (((mr >> 3) ^ es) << 3) | (mr & 7);
        int c1 = (((2 | (mr >> 3)) ^ es) << 3) | (mr & 7);
        float inv = 1.f / s_rn[e];
        S[8 + wave][e][c0] = __float2bfloat16((a0[mf][r] + rb0) * inv);
        S[8 + wave][e][c1] = __float2bfloat16((a1[mf][r] + rb1) * inv);
      }
  }
  __syncthreads();

  // ---- phase 3: stage h_row -> S[0..3], h_col -> S[4..7] ----
  {
    const int m = t >> 2, part = t & 3;
    const int pc = ((part ^ ((m >> 1) & 3)) << 3);
    const __hip_bfloat16* hr = hb + (size_t)s_row[m] * 128 + part * 8;
    const __hip_bfloat16* hc = hb + (size_t)s_col[m] * 128 + part * 8;
#pragma unroll
    for (int kb = 0; kb < 4; kb++) {
      *(int4*)&S[kb][m][pc]     = *(const int4*)&hr[kb * 32];
      *(int4*)&S[4 + kb][m][pc] = *(const int4*)&hc[kb * 32];
    }
  }
  __syncthreads();

  // ---- stage 1: ef1 = silu(A @ e_w1 + e_b1), K=384, M=64 (acc in regs) ----
  f32x4 s1a0[4], s1a1[4];
#pragma unroll
  for (int mf = 0; mf < 4; mf++) { s1a0[mf] = zacc; s1a1[mf] = zacc; }
#pragma unroll
  for (int kb = 0; kb < 12; kb++) {
    const __hip_bfloat16* wp = wz_e1 + ((size_t)(kb * 128 + n0 + mr) * 32 + quad * 8);
    bf16x8 b0 = *(const bf16x8*)wp;
    bf16x8 b1 = *(const bf16x8*)(wp + 16 * 32);
#pragma unroll
    for (int mf = 0; mf < 4; mf++) {
      bf16x8 a = *(const bf16x8*)&S[kb][mf * 16 + mr][acol];
      s1a0[mf] = __builtin_amdgcn_mfma_f32_16x16x32_bf16(a, b0, s1a0[mf], 0, 0, 0);
      s1a1[mf] = __builtin_amdgcn_mfma_f32_16x16x32_bf16(a, b1, s1a1[mf], 0, 0, 0);
    }
  }
  __syncthreads();  // all waves done reading A before ef1 overwrites S[0..3]
  {
    float bias0 = e_b1[n0 + mr], bias1 = e_b1[n0 + 16 + mr];
#pragma unroll
    for (int mf = 0; mf < 4; mf++)
#pragma unroll
      for (int r = 0; r < 4; r++) {
        int e = mf * 16 + quad * 4 + r;
        int es = (e >> 1) & 3;
        int c0 = (((mr >> 3) ^ es) << 3) | (mr & 7);
        int c1 = (((2 | (mr >> 3)) ^ es) << 3) | (mr & 7);
        S[wave][e][c0] = __float2bfloat16(siluf(s1a0[mf][r] + bias0));
        S[wave][e][c1] = __float2bfloat16(siluf(s1a1[mf][r] + bias1));
      }
  }
  __syncthreads();

  // ---- stage 2: ef2 = silu(ef1 @ e_w2 + e_b2) -> S[4..7]; gate partials ----
  const float aw0 = att_w[n0 + mr], aw1 = att_w[n0 + 16 + mr];
  {
    f32x4 a0[4], a1[4];
#pragma unroll
    for (int mf = 0; mf < 4; mf++) { a0[mf] = zacc; a1[mf] = zacc; }
#pragma unroll
    for (int kb = 0; kb < 4; kb++) {
      const __hip_bfloat16* wp = wz_e2 + ((size_t)(kb * 128 + n0 + mr) * 32 + quad * 8);
      bf16x8 b0 = *(const bf16x8*)wp;
      bf16x8 b1 = *(const bf16x8*)(wp + 16 * 32);
#pragma unroll
      for (int mf = 0; mf < 4; mf++) {
        bf16x8 a = *(const bf16x8*)&S[kb][mf * 16 + mr][acol];
        a0[mf] = __builtin_amdgcn_mfma_f32_16x16x32_bf16(a, b0, a0[mf], 0, 0, 0);
        a1[mf] = __builtin_amdgcn_mfma_f32_16x16x32_bf16(a, b1, a1[mf], 0, 0, 0);
      }
    }
    float bias0 = e_b2[n0 + mr], bias1 = e_b2[n0 + 16 + mr];
    float part[4][4];
#pragma unroll
    for (int mf = 0; mf < 4; mf++)
#pragma unroll
      for (int r = 0; r < 4; r++) {
        int e = mf * 16 + quad * 4 + r;
        int es = (e >> 1) & 3;
        int c0 = (((mr >> 3) ^ es) << 3) | (mr & 7);
        int c1 = (((2 | (mr >> 3)) ^ es) << 3) | (mr & 7);
        float v0 = siluf(a0[mf][r] + bias0);
        float v1 = siluf(a1[mf][r] + bias1);
        S[4 + wave][e][c0] = __float2bfloat16(v0);
        S[4 + wave][e][c1] = __float2bfloat16(v1);
        part[mf][r] = v0 * aw0 + v1 * aw1;
      }
#pragma unroll
    for (int msk = 1; msk < 16; msk <<= 1)
#pragma unroll
      for (int mf = 0; mf < 4; mf++)
#pragma unroll
        for (int r = 0; r < 4; r++) part[mf][r] += __shfl_xor(part[mf][r], msk);
    if (mr == 0) {
#pragma unroll
      for (int mf = 0; mf < 4; mf++)
#pragma unroll
        for (int r = 0; r < 4; r++)
          s_red[wave][mf * 16 + quad * 4 + r] = part[mf][r];
    }
  }
  __syncthreads();
  if (t < TM) {
    float s = s_red[0][t] + s_red[1][t] + s_red[2][t] + s_red[3][t];
    s_att[t] = sigmf(s + att_b[0]);
  }
  __syncthreads();

  // ---- stage 3: cmh = silu(att*(ef2 @ c_w1) + c_b1) -> S[8..11] ----
  {
    f32x4 a0[4], a1[4];
#pragma unroll
    for (int mf = 0; mf < 4; mf++) { a0[mf] = zacc; a1[mf] = zacc; }
#pragma unroll
    for (int kb = 0; kb < 4; kb++) {
      const __hip_bfloat16* wp = wz_c1 + ((size_t)(kb * 128 + n0 + mr) * 32 + quad * 8);
      bf16x8 b0 = *(const bf16x8*)wp;
      bf16x8 b1 = *(const bf16x8*)(wp + 16 * 32);
#pragma unroll
      for (int mf = 0; mf < 4; mf++) {
        bf16x8 a = *(const bf16x8*)&S[4 + kb][mf * 16 + mr][acol];
        a0[mf] = __builtin_amdgcn_mfma_f32_16x16x32_bf16(a, b0, a0[mf], 0, 0, 0);
        a1[mf] = __builtin_amdgcn_mfma_f32_16x16x32_bf16(a, b1, a1[mf], 0, 0, 0);
      }
    }
    float bias0 = c_b1[n0 + mr], bias1 = c_b1[n0 + 16 + mr];
#pragma unroll
    for (int mf = 0; mf < 4; mf++)
#pragma unroll
      for (int r = 0; r < 4; r++) {
        int e = mf * 16 + quad * 4 + r;
        int es = (e >> 1) & 3;
        int c0 = (((mr >> 3) ^ es) << 3) | (mr & 7);
        int c1 = (((2 | (mr >> 3)) ^ es) << 3) | (mr & 7);
        float av = s_att[e];
        S[8 + wave][e][c0] = __float2bfloat16(siluf(av * a0[mf][r] + bias0));
        S[8 + wave][e][c1] = __float2bfloat16(siluf(av * a1[mf][r] + bias1));
      }
  }
  __syncthreads();

  // ---- cm = cmh @ c_w2 + c_b2 (each wave one 16-row tile) -> s_cm (S[0]) ----
  {
    f32x4 acc = zacc;
#pragma unroll
    for (int kb = 0; kb < 4; kb++) {
      bf16x8 a = *(const bf16x8*)&S[8 + kb][wave * 16 + mr][acol];
      bf16x8 b = *(const bf16x8*)(wz_c2 + ((size_t)(kb * 16 + mr) * 32 + quad * 8));
      acc = __builtin_amdgcn_mfma_f32_16x16x32_bf16(a, b, acc, 0, 0, 0);
    }
    if (mr < 14) {
      float bias = c_b2[mr];
#pragma unroll
      for (int r = 0; r < 4; r++)
        s_cm[(wave * 16 + quad * 4 + r) * 14 + mr] = acc[r] + bias;
    }
  }
  __syncthreads();

  // ---- RollerPooling ----
  for (int i = t; i < TM * 14; i += 256) {
    int e = i / 14, c = i % 14;
    int wsz = 15 - s_cs[e];
    int hi = min(c + wsz, 14);
    float s = 0.f;
    for (int j = c; j < hi; j++) s += s_cm[e * 14 + j];
    s_pool[e * 14 + c] = s / (float)wsz;
  }
  __syncthreads();

  // ---- trans scatter (x re-gathered from L2; packed bf16 atomics) ----
  for (int i = t; i < TM * 21; i += 256) {
    int e = i / 21, pr = i % 21;
    if (e < ne) {
      int r0 = pr * 2, r1 = r0 + 1;
      const float* xp = x + (size_t)s_row[e] * 42;
      const float* pc = pooled_x + (size_t)s_col[e] * 3;
      float v0 = (xp[r0] - pc[r0 % 3]) * s_pool[e * 14 + r0 / 3];
      float v1 = (xp[r1] - pc[r1 % 3]) * s_pool[e * 14 + r1 / 3];
      unsafeAtomicAdd(&x_acc[(size_t)s_row[e] * 21 + pr], mk_bf162(v0, v1));
    }
  }
  // ---- agg scatter (gated ef2 from S[4..7], swizzled reads) ----
  for (int i = t; i < TM * 64; i += 256) {
    int e = i >> 6, o2 = i & 63;
    if (e < ne) {
      float av = s_att[e];
      int c = (o2 & 15) * 2;
      int pc = (((c >> 3) ^ ((e >> 1) & 3)) << 3) | (c & 7);
      const __hip_bfloat16* wp2 = &S[4 + (o2 >> 4)][e][pc];
      float v0 = __bfloat162float(wp2[0]) * av;
      float v1 = __bfloat162float(wp2[1]) * av;
      unsafeAtomicAdd(&agg[(size_t)s_col[e] * 64 + o2], mk_bf162(v0, v1));
    }
  }
}

// ---- node MLP (MFMA) + residual + in-wave LayerNorm + fused x_new ----
__global__ __launch_bounds__(256) void k_node(
    const float* __restrict__ h, const __hip_bfloat162* __restrict__ agg,
    const unsigned* __restrict__ cnt_col,
    const __hip_bfloat16* __restrict__ wz_n1, const float* __restrict__ n_b1,
    const __hip_bfloat16* __restrict__ wz_n2, const float* __restrict__ n_b2,
    const float* __restrict__ ln_g, const float* __restrict__ ln_b,
    const float* __restrict__ x, const __hip_bfloat162* __restrict__ x_acc,
    const unsigned* __restrict__ cnt_row,
    float* __restrict__ out_h, float* __restrict__ out_x, int Nn) {
  __shared__ __hip_bfloat16 sA[8][16][PAD];
  __shared__ __hip_bfloat16 sT[4][16][PAD];
  __shared__ float s_h[TN][128];
  __shared__ float s_o[TN][132];
  const int t = threadIdx.x;
  const int nb0 = blockIdx.x * TN;
  const int nn = min(TN, Nn - nb0);

  // fused x_new
  for (int i = t; i < TN * 21; i += 256) {
    int n = i / 21, pr = i % 21;
    if (n < nn) {
      int gn = nb0 + n;
      unsigned c = cnt_row[gn];
      float inv = 1.f / (float)(c > 0 ? c : 1);
      float2 xa = __bfloat1622float2(x_acc[(size_t)gn * 21 + pr]);
      size_t gi = (size_t)gn * 42 + pr * 2;
      out_x[gi]     = x[gi] + xa.x * inv;
      out_x[gi + 1] = x[gi + 1] + xa.y * inv;
    }
  }

  for (int i = t; i < TN * 64; i += 256) {
    int m = i >> 6, kp = (i & 63) << 1;
    int kb = kp >> 5, kk = kp & 31;
    int gn = nb0 + min(m, nn - 1);
    const float2 hv = *(const float2*)&h[(size_t)gn * 128 + kp];
    sA[kb][m][kk]     = __float2bfloat16(hv.x);
    sA[kb][m][kk + 1] = __float2bfloat16(hv.y);
    s_h[m][kp]     = hv.x;
    s_h[m][kp + 1] = hv.y;
    unsigned c = cnt_col[gn];
    float inv = 1.f / (float)(c > 0 ? c : 1);
    float2 gv = __bfloat1622float2(agg[(size_t)gn * 64 + (kp >> 1)]);
    sA[4 + kb][m][kk]     = __float2bfloat16(gv.x * inv);
    sA[4 + kb][m][kk + 1] = __float2bfloat16(gv.y * inv);
  }
  __syncthreads();
  const int lane = t & 63, wave = t >> 6, quad = lane >> 4, mr = lane & 15;
  const int n0 = wave * 32;
  f32x4 zacc = {0.f, 0.f, 0.f, 0.f};
  {
    f32x4 acc0 = zacc, acc1 = zacc;
#pragma unroll
    for (int kb = 0; kb < 8; kb++) {
      bf16x8 a = *(const bf16x8*)&sA[kb][mr][quad * 8];
      const __hip_bfloat16* wp = wz_n1 + ((size_t)(kb * 128 + n0 + mr) * 32 + quad * 8);
      bf16x8 b0 = *(const bf16x8*)wp;
      bf16x8 b1 = *(const bf16x8*)(wp + 16 * 32);
      acc0 = __builtin_amdgcn_mfma_f32_16x16x32_bf16(a, b0, acc0, 0, 0, 0);
      acc1 = __builtin_amdgcn_mfma_f32_16x16x32_bf16(a, b1, acc1, 0, 0, 0);
    }
    float bias0 = n_b1[n0 + mr], bias1 = n_b1[n0 + 16 + mr];
#pragma unroll
    for (int r = 0; r < 4; r++) {
      int m = quad * 4 + r;
      sT[wave][m][mr]      = __float2bfloat16(siluf(acc0[r] + bias0));
      sT[wave][m][16 + mr] = __float2bfloat16(siluf(acc1[r] + bias1));
    }
  }
  __syncthreads();
  {
    f32x4 acc0 = zacc, acc1 = zacc;
#pragma unroll
    for (int kb = 0; kb < 4; kb++) {
      bf16x8 a = *(const bf16x8*)&sT[kb][mr][quad * 8];
      const __hip_bfloat16* wp = wz_n2 + ((size_t)(kb * 128 + n0 + mr) * 32 + quad * 8);
      bf16x8 b0 = *(const bf16x8*)wp;
      bf16x8 b1 = *(const bf16x8*)(wp + 16 * 32);
      acc0 = __builtin_amdgcn_mfma_f32_16x16x32_bf16(a, b0, acc0, 0, 0, 0);
      acc1 = __builtin_amdgcn_mfma_f32_16x16x32_bf16(a, b1, acc1, 0, 0, 0);
    }
    float bias0 = n_b2[n0 + mr], bias1 = n_b2[n0 + 16 + mr];
#pragma unroll
    for (int r = 0; r < 4; r++) {
      int m = quad * 4 + r;
      s_o[m][n0 + mr]      = s_h[m][n0 + mr] + acc0[r] + bias0;
      s_o[m][n0 + 16 + mr] = s_h[m][n0 + 16 + mr] + acc1[r] + bias1;
    }
  }
  __syncthreads();
  // ---- in-wave LayerNorm: node n's 16 threads are contiguous lanes ----
  {
    int n = t >> 4, p = t & 15;
    float v[8];
    float s = 0.f;
#pragma unroll
    for (int j = 0; j < 8; j++) {
      v[j] = s_o[n][p * 8 + j];
      s += v[j];
    }
    s += __shfl_xor(s, 1); s += __shfl_xor(s, 2);
    s += __shfl_xor(s, 4); s += __shfl_xor(s, 8);
    float mu = s * (1.f / 128.f);
    float var = 0.f;
#pragma unroll
    for (int j = 0; j < 8; j++) {
      float d = v[j] - mu;
      var += d * d;
    }
    var += __shfl_xor(var, 1); var += __shfl_xor(var, 2);
    var += __shfl_xor(var, 4); var += __shfl_xor(var, 8);
    float rs = rsqrtf(var * (1.f / 128.f) + 1e-5f);
    if (n < nn) {
      size_t base = (size_t)(nb0 + n) * 128 + p * 8;
#pragma unroll
      for (int j = 0; j < 8; j++)
        out_h[base + j] = (v[j] - mu) * rs * ln_g[p * 8 + j] + ln_b[p * 8 + j];
    }
  }
}

extern "C" void kernel_launch(void* const* d_in, const int* in_sizes, int n_in,
                              void* d_out, int out_size, void* d_ws, size_t ws_size,
                              hipStream_t stream) {
  const float* h     = (const float*)d_in[0];
  const float* x     = (const float*)d_in[1];
  const float* attr  = (const float*)d_in[2];
  const float* cw    = (const float*)d_in[3];
  const int*   row   = (const int*)d_in[4];
  const int*   col   = (const int*)d_in[5];
  const float* rad_w = (const float*)d_in[6];
  const float* rad_b = (const float*)d_in[7];
  const float* e_w1  = (const float*)d_in[8];
  const float* e_b1  = (const float*)d_in[9];
  const float* e_w2  = (const float*)d_in[10];
  const float* e_b2  = (const float*)d_in[11];
  const float* att_w = (const float*)d_in[12];
  const float* att_b = (const float*)d_in[13];
  const float* c_w1  = (const float*)d_in[14];
  const float* c_b1  = (const float*)d_in[15];
  const float* c_w2  = (const float*)d_in[16];
  const float* c_b2  = (const float*)d_in[17];
  const float* n_w1  = (const float*)d_in[18];
  const float* n_b1  = (const float*)d_in[19];
  const float* n_w2  = (const float*)d_in[20];
  const float* n_b2  = (const float*)d_in[21];
  const float* ln_g  = (const float*)d_in[22];
  const float* ln_b  = (const float*)d_in[23];

  const int N = in_sizes[0] / 128;
  const int E = in_sizes[4];

  char* ws = (char*)d_ws;
  size_t off = 0;
  auto alloc = [&](size_t bytes) {
    size_t o = off;
    off += (bytes + 255) & ~(size_t)255;
    return o;
  };
  size_t off_wzr  = alloc(32768 * sizeof(__hip_bfloat16));
  size_t off_wz1  = alloc(49152 * sizeof(__hip_bfloat16));
  size_t off_wz2  = alloc(16384 * sizeof(__hip_bfloat16));
  size_t off_wzc  = alloc(16384 * sizeof(__hip_bfloat16));
  size_t off_wzn1 = alloc(32768 * sizeof(__hip_bfloat16));
  size_t off_wzn2 = alloc(16384 * sizeof(__hip_bfloat16));
  size_t off_wzc2 = alloc(2048 * sizeof(__hip_bfloat16));
  size_t off_atS  = alloc((size_t)N * 256 * sizeof(__hip_bfloat16));
  size_t off_hb   = alloc((size_t)N * 128 * sizeof(__hip_bfloat16));
  size_t off_px   = alloc((size_t)N * 3 * sizeof(float));
  size_t off_cs   = alloc((size_t)N * sizeof(int));
  size_t off_cntr = alloc((size_t)N * sizeof(unsigned));
  size_t off_cntc = alloc((size_t)N * sizeof(unsigned));
  size_t off_xacc = alloc((size_t)N * 21 * sizeof(__hip_bfloat162));
  size_t off_agg  = alloc((size_t)N * 64 * sizeof(__hip_bfloat162));

  __hip_bfloat16* wz_rad = (__hip_bfloat16*)(ws + off_wzr);
  __hip_bfloat16* wz_e1  = (__hip_bfloat16*)(ws + off_wz1);
  __hip_bfloat16* wz_e2  = (__hip_bfloat16*)(ws + off_wz2);
  __hip_bfloat16* wz_c1  = (__hip_bfloat16*)(ws + off_wzc);
  __hip_bfloat16* wz_n1  = (__hip_bfloat16*)(ws + off_wzn1);
  __hip_bfloat16* wz_n2  = (__hip_bfloat16*)(ws + off_wzn2);
  __hip_bfloat16* wz_c2  = (__hip_bfloat16*)(ws + off_wzc2);
  __hip_bfloat16* attrS  = (__hip_bfloat16*)(ws + off_atS);
  __hip_bfloat16* hb     = (__hip_bfloat16*)(ws + off_hb);
  float* pooled_x   = (float*)(ws + off_px);
  int* chsum        = (int*)(ws + off_cs);
  unsigned* cnt_row = (unsigned*)(ws + off_cntr);
  unsigned* cnt_col = (unsigned*)(ws + off_cntc);
  __hip_bfloat162* x_acc = (__hip_bfloat162*)(ws + off_xacc);
  __hip_bfloat162* agg   = (__hip_bfloat162*)(ws + off_agg);

  (void)hipMemsetAsync(ws + off_cntr, 0, off - off_cntr, stream);

  const int pack_items = 165888 + N * 256 + N * 128 + N;
  k_pack<<<dim3((pack_items + 255) / 256), dim3(256), 0, stream>>>(
      h, x, attr, cw, rad_w, e_w1, e_w2, c_w1, n_w1, n_w2, c_w2,
      wz_rad, wz_e1, wz_e2, wz_c1, wz_n1, wz_n2, wz_c2,
      attrS, hb, pooled_x, chsum, N);
  k_mega<<<dim3((E + TM - 1) / TM), dim3(256), 0, stream>>>(
      hb, x, attrS, row, col, pooled_x, chsum,
      wz_rad, rad_b, wz_e1, e_b1, wz_e2, e_b2, att_w, att_b,
      wz_c1, c_b1, wz_c2, c_b2, cnt_row, cnt_col, x_acc, agg, E);
  k_node<<<dim3((N + TN - 1) / TN), dim3(256), 0, stream>>>(
      h, agg, cnt_col, wz_n1, n_b1, wz_n2, n_b2, ln_g, ln_b,
      x, x_acc, cnt_row, (float*)d_out, (float*)d_out + (size_t)N * 128, N);
}

// Round 6
// 395.767 us; speedup vs baseline: 1.1404x; 1.1404x over previous
//
#include <hip/hip_runtime.h>
#include <hip/hip_bf16.h>

// EnhancedGNNEncoder round 15: revert r14 einsum change (VALU-bound: direct
// distance calc added work); k_mega = round-13 version. k_node rebuilt at
// TN=64 with the proven M=64 aliased-slot structure:
//   A: hb S[0..3], agg/deg S[4..7]; ef1 -> S[8..11]; stage-2 out f32 s_o over
//   S[0..7]; LN 4 lanes/node (shfl_xor 1,2), residual h re-read f32.
// Weight loads + barriers per node /4 (96 KB/block x 1250 -> x 313 blocks).
// MFMA 16x16x32: A[m=lane&15][k=quad*8+j], B[k=quad*8+j][n=lane&15],
//                D col=lane&15, row=quad*4+reg.

#define TM 64
#define TN 64
#define PAD 36

typedef __attribute__((ext_vector_type(8))) short bf16x8;
typedef __attribute__((ext_vector_type(4))) float f32x4;

__device__ __forceinline__ float siluf(float v) { return v / (1.f + __expf(-v)); }
__device__ __forceinline__ float sigmf(float v) { return 1.f / (1.f + __expf(-v)); }
__device__ __forceinline__ short f2bs(float f) {
  union { __hip_bfloat16 b; short s; } u;
  u.b = __float2bfloat16(f);
  return u.s;
}
__device__ __forceinline__ __hip_bfloat162 mk_bf162(float v0, float v1) {
  __hip_bfloat162 r;
  r.x = __float2bfloat16(v0);
  r.y = __float2bfloat16(v1);
  return r;
}

// ---- pack: weight swizzle + attrS + h_bf16 + per-node prep ----
__global__ __launch_bounds__(256) void k_pack(
    const float* __restrict__ h, const float* __restrict__ x,
    const float* __restrict__ attr, const float* __restrict__ cw,
    const float* __restrict__ rad_w, const float* __restrict__ e_w1,
    const float* __restrict__ e_w2, const float* __restrict__ c_w1,
    const float* __restrict__ n_w1, const float* __restrict__ n_w2,
    const float* __restrict__ c_w2,
    __hip_bfloat16* __restrict__ wz_rad, __hip_bfloat16* __restrict__ wz_e1,
    __hip_bfloat16* __restrict__ wz_e2, __hip_bfloat16* __restrict__ wz_c1,
    __hip_bfloat16* __restrict__ wz_n1, __hip_bfloat16* __restrict__ wz_n2,
    __hip_bfloat16* __restrict__ wz_c2,
    __hip_bfloat16* __restrict__ attrS, __hip_bfloat16* __restrict__ hb,
    float* __restrict__ pooled_x, int* __restrict__ chsum, int Nn) {
  int idx = blockIdx.x * 256 + threadIdx.x;
  if (idx < 165888) {  // weight swizzle
    int i = idx;
    if (i >= 163840) {  // c_w2: [128][14] -> [4][16][32], n=14,15 zero
      int base = i - 163840;
      int k = base >> 4, n = base & 15;
      wz_c2[(size_t)(k >> 5) * 512 + n * 32 + (k & 31)] =
          (n < 14) ? __float2bfloat16(c_w2[k * 14 + n]) : __float2bfloat16(0.f);
      return;
    }
    const float* W;
    __hip_bfloat16* O;
    int base;
    if (i < 32768) { W = rad_w; O = wz_rad; base = i; }
    else if (i < 81920) { W = e_w1; O = wz_e1; base = i - 32768; }
    else if (i < 98304) { W = e_w2; O = wz_e2; base = i - 81920; }
    else if (i < 114688) { W = c_w1; O = wz_c1; base = i - 98304; }
    else if (i < 147456) { W = n_w1; O = wz_n1; base = i - 114688; }
    else { W = n_w2; O = wz_n2; base = i - 147456; }
    int k = base >> 7, n = base & 127;
    O[(size_t)((k >> 5) * 128 + n) * 32 + (k & 31)] = __float2bfloat16(W[base]);
    return;
  }
  idx -= 165888;
  int na = Nn * 256, nh = Nn * 128;
  if (idx < na) {
    int n = idx >> 8, r = idx & 255, i2 = r >> 4, a = r & 15;
    float v = 0.f;
    if (i2 < 14) v = attr[(size_t)n * 224 + i2 * 16 + a] * cw[(size_t)n * 14 + i2];
    attrS[(size_t)n * 256 + a * 16 + i2] = __float2bfloat16(v);
    return;
  }
  idx -= na;
  if (idx < nh) {
    hb[idx] = __float2bfloat16(h[idx]);
    return;
  }
  idx -= nh;
  if (idx >= Nn) return;
  int n = idx;
  int cnt = 0;
  float sx = 0.f, sy = 0.f, sz = 0.f;
#pragma unroll
  for (int c = 0; c < 14; c++) {
    float w = cw[n * 14 + c];
    if (w != 0.f) {
      cnt++;
      sx += x[n * 42 + c * 3 + 0];
      sy += x[n * 42 + c * 3 + 1];
      sz += x[n * 42 + c * 3 + 2];
    }
  }
  chsum[n] = cnt;
  float inv = 1.f / (float)(cnt > 0 ? cnt : 1);
  pooled_x[n * 3 + 0] = sx * inv;
  pooled_x[n * 3 + 1] = sy * inv;
  pooled_x[n * 3 + 2] = sz * inv;
}

// ---- k_mega: einsum + rad GEMM + edge MLP + gate + roller + scatters ----
// (round-13 version) 12 aliased swizzled LDS slots; 51.5 KB -> 3 blocks/CU.
__global__ __launch_bounds__(256, 3) void k_mega(
    const __hip_bfloat16* __restrict__ hb, const float* __restrict__ x,
    const __hip_bfloat16* __restrict__ attrS,
    const int* __restrict__ row, const int* __restrict__ col,
    const float* __restrict__ pooled_x, const int* __restrict__ chsum,
    const __hip_bfloat16* __restrict__ wz_rad, const float* __restrict__ rad_b,
    const __hip_bfloat16* __restrict__ wz_e1, const float* __restrict__ e_b1,
    const __hip_bfloat16* __restrict__ wz_e2, const float* __restrict__ e_b2,
    const float* __restrict__ att_w, const float* __restrict__ att_b,
    const __hip_bfloat16* __restrict__ wz_c1, const float* __restrict__ c_b1,
    const __hip_bfloat16* __restrict__ wz_c2, const float* __restrict__ c_b2,
    unsigned* __restrict__ cnt_row, unsigned* __restrict__ cnt_col,
    __hip_bfloat162* __restrict__ x_acc, __hip_bfloat162* __restrict__ agg,
    int Ee) {
  __shared__ __hip_bfloat16 S[12][TM][32];
  __shared__ float s_att[TM];
  __shared__ float s_red[4][TM];
  __shared__ float s_rn[TM];
  __shared__ int s_row[TM], s_col[TM], s_cs[TM];
  float* s_cm   = (float*)&S[0][0][0];
  float* s_pool = (float*)&S[1][0][0];

  const int t = threadIdx.x;
  const int e0 = blockIdx.x * TM;
  const int ne = min(TM, Ee - e0);
  const int lane = t & 63, wave = t >> 6, quad = lane >> 4, mr = lane & 15;
  const int n0 = wave * 32;
  const f32x4 zacc = {0.f, 0.f, 0.f, 0.f};
  const bf16x8 zero8 = {0, 0, 0, 0, 0, 0, 0, 0};

  // ---- phase 0: edge meta + degree atomics ----
  if (t < TM) {
    int ge = e0 + min(t, ne - 1);
    int r = row[ge], c = col[ge];
    s_row[t] = r;
    s_col[t] = c;
    s_cs[t] = chsum[r];
    if (t < ne) {
      atomicAdd(&cnt_row[r], 1u);
      atomicAdd(&cnt_col[c], 1u);
    }
  }

  // ---- phase 1: einsum, 16 edges/wave in 4 batches of 4 ----
#pragma unroll 1
  for (int b = 0; b < 4; b++) {
    float xr0v[4], xr1v[4], xr2v[4], xc0v[4], xc1v[4], xc2v[4];
    bf16x8 bCv[4], aRv[4];
#pragma unroll
    for (int p = 0; p < 4; p++) {
      const int e = wave * 16 + b * 4 + p;
      const int ge = e0 + min(e, ne - 1);
      const int re = row[ge], ce = col[ge];  // wave-uniform -> scalar loads
      const int mrc = min(mr, 13);
      const float* xp = x + (size_t)re * 42 + mrc * 3;
      xr0v[p] = xp[0]; xr1v[p] = xp[1]; xr2v[p] = xp[2];
      const float* xq = x + (size_t)ce * 42 + mrc * 3;
      xc0v[p] = xq[0]; xc1v[p] = xq[1]; xc2v[p] = xq[2];
      bCv[p] = zero8; aRv[p] = zero8;
      if (quad < 2) {
        bCv[p] = *(const bf16x8*)&attrS[(size_t)ce * 256 + mr * 16 + quad * 8];
        aRv[p] = *(const bf16x8*)&attrS[(size_t)re * 256 + mr * 16 + quad * 8];
      }
    }
#pragma unroll
    for (int p = 0; p < 4; p++) {
      const int e = wave * 16 + b * 4 + p;
      const float xr0 = xr0v[p], xr1 = xr1v[p], xr2 = xr2v[p];
      const float xc0 = xc0v[p], xc1 = xc1v[p], xc2 = xc2v[p];
      bf16x8 aX = zero8, bX = zero8;
      if (quad == 0) {
        aX[0] = f2bs(xc0); aX[1] = f2bs(xc1); aX[2] = f2bs(xc2);
        bX[0] = f2bs(xr0); bX[1] = f2bs(xr1); bX[2] = f2bs(xr2);
      }
      f32x4 G = __builtin_amdgcn_mfma_f32_16x16x32_bf16(aX, bX, zacc, 0, 0, 0);
      const float nr = xr0 * xr0 + xr1 * xr1 + xr2 * xr2;
      const float nc = xc0 * xc0 + xc1 * xc1 + xc2 * xc2;
      float dD[4];
#pragma unroll
      for (int r = 0; r < 4; r++) {
        float ncj = __shfl(nc, quad * 4 + r);
        dD[r] = sqrtf(fmaxf(ncj + nr - 2.f * G[r], 0.f));
      }
      bf16x8 aD;
#pragma unroll
      for (int jj = 0; jj < 8; jj++) {
        const int qs = (quad * 2 + (jj >> 2)) & 3;
        float dv = __shfl(dD[jj & 3], (qs << 4) | mr);
        if (quad >= 2) dv = 0.f;
        aD[jj] = f2bs(dv);
      }
      f32x4 m1 = __builtin_amdgcn_mfma_f32_16x16x32_bf16(aD, bCv[p], zacc, 0, 0, 0);
      bf16x8 bM;
#pragma unroll
      for (int jj = 0; jj < 8; jj++) {
        const int qs = (quad * 2 + (jj >> 2)) & 3;
        float mv = __shfl(m1[jj & 3], (qs << 4) | mr);
        if (quad >= 2) mv = 0.f;
        bM[jj] = f2bs(mv);
      }
      f32x4 rd = __builtin_amdgcn_mfma_f32_16x16x32_bf16(aRv[p], bM, zacc, 0, 0, 0);
      float ss = rd[0] * rd[0] + rd[1] * rd[1] + rd[2] * rd[2] + rd[3] * rd[3];
      ss += __shfl_xor(ss, 32); ss += __shfl_xor(ss, 16); ss += __shfl_xor(ss, 8);
      ss += __shfl_xor(ss, 4);  ss += __shfl_xor(ss, 2);  ss += __shfl_xor(ss, 1);
      if (lane == 0) s_rn[e] = sqrtf(ss) + 1.0f;
#pragma unroll
      for (int r = 0; r < 4; r++) {
        const int aa = quad * 4 + r;
        const int c = ((aa & 1) << 4) | mr;
        const int pcol = (((c >> 3) ^ ((e >> 1) & 3)) << 3) | (c & 7);
        S[aa >> 1][e][pcol] = __float2bfloat16(rd[r]);
      }
    }
  }
  __syncthreads();

  const int acol = ((quad ^ ((mr >> 1) & 3)) << 3);  // swizzled frag-read col

  // ---- phase 2: rad GEMM radial@rad_w -> radf in S[8..11] ----
  {
    f32x4 a0[4], a1[4];
#pragma unroll
    for (int mf = 0; mf < 4; mf++) { a0[mf] = zacc; a1[mf] = zacc; }
#pragma unroll
    for (int kb = 0; kb < 8; kb++) {
      const __hip_bfloat16* wp = wz_rad + ((size_t)(kb * 128 + n0 + mr) * 32 + quad * 8);
      bf16x8 b0 = *(const bf16x8*)wp;
      bf16x8 b1 = *(const bf16x8*)(wp + 16 * 32);
#pragma unroll
      for (int mf = 0; mf < 4; mf++) {
        bf16x8 a = *(const bf16x8*)&S[kb][mf * 16 + mr][acol];
        a0[mf] = __builtin_amdgcn_mfma_f32_16x16x32_bf16(a, b0, a0[mf], 0, 0, 0);
        a1[mf] = __builtin_amdgcn_mfma_f32_16x16x32_bf16(a, b1, a1[mf], 0, 0, 0);
      }
    }
    float rb0 = rad_b[n0 + mr], rb1 = rad_b[n0 + 16 + mr];
#pragma unroll
    for (int mf = 0; mf < 4; mf++)
#pragma unroll
      for (int r = 0; r < 4; r++) {
        int e = mf * 16 + quad * 4 + r;
        int es = (e >> 1) & 3;
        int c0 = (((mr >> 3) ^ es) << 3) | (mr & 7);
        int c1 = (((2 | (mr >> 3)) ^ es) << 3) | (mr & 7);
        float inv = 1.f / s_rn[e];
        S[8 + wave][e][c0] = __float2bfloat16((a0[mf][r] + rb0) * inv);
        S[8 + wave][e][c1] = __float2bfloat16((a1[mf][r] + rb1) * inv);
      }
  }
  __syncthreads();

  // ---- phase 3: stage h_row -> S[0..3], h_col -> S[4..7] ----
  {
    const int m = t >> 2, part = t & 3;
    const int pc = ((part ^ ((m >> 1) & 3)) << 3);
    const __hip_bfloat16* hr = hb + (size_t)s_row[m] * 128 + part * 8;
    const __hip_bfloat16* hc = hb + (size_t)s_col[m] * 128 + part * 8;
#pragma unroll
    for (int kb = 0; kb < 4; kb++) {
      *(int4*)&S[kb][m][pc]     = *(const int4*)&hr[kb * 32];
      *(int4*)&S[4 + kb][m][pc] = *(const int4*)&hc[kb * 32];
    }
  }
  __syncthreads();

  // ---- stage 1: ef1 = silu(A @ e_w1 + e_b1), K=384, M=64 (acc in regs) ----
  f32x4 s1a0[4], s1a1[4];
#pragma unroll
  for (int mf = 0; mf < 4; mf++) { s1a0[mf] = zacc; s1a1[mf] = zacc; }
#pragma unroll
  for (int kb = 0; kb < 12; kb++) {
    const __hip_bfloat16* wp = wz_e1 + ((size_t)(kb * 128 + n0 + mr) * 32 + quad * 8);
    bf16x8 b0 = *(const bf16x8*)wp;
    bf16x8 b1 = *(const bf16x8*)(wp + 16 * 32);
#pragma unroll
    for (int mf = 0; mf < 4; mf++) {
      bf16x8 a = *(const bf16x8*)&S[kb][mf * 16 + mr][acol];
      s1a0[mf] = __builtin_amdgcn_mfma_f32_16x16x32_bf16(a, b0, s1a0[mf], 0, 0, 0);
      s1a1[mf] = __builtin_amdgcn_mfma_f32_16x16x32_bf16(a, b1, s1a1[mf], 0, 0, 0);
    }
  }
  __syncthreads();  // all waves done reading A before ef1 overwrites S[0..3]
  {
    float bias0 = e_b1[n0 + mr], bias1 = e_b1[n0 + 16 + mr];
#pragma unroll
    for (int mf = 0; mf < 4; mf++)
#pragma unroll
      for (int r = 0; r < 4; r++) {
        int e = mf * 16 + quad * 4 + r;
        int es = (e >> 1) & 3;
        int c0 = (((mr >> 3) ^ es) << 3) | (mr & 7);
        int c1 = (((2 | (mr >> 3)) ^ es) << 3) | (mr & 7);
        S[wave][e][c0] = __float2bfloat16(siluf(s1a0[mf][r] + bias0));
        S[wave][e][c1] = __float2bfloat16(siluf(s1a1[mf][r] + bias1));
      }
  }
  __syncthreads();

  // ---- stage 2: ef2 = silu(ef1 @ e_w2 + e_b2) -> S[4..7]; gate partials ----
  const float aw0 = att_w[n0 + mr], aw1 = att_w[n0 + 16 + mr];
  {
    f32x4 a0[4], a1[4];
#pragma unroll
    for (int mf = 0; mf < 4; mf++) { a0[mf] = zacc; a1[mf] = zacc; }
#pragma unroll
    for (int kb = 0; kb < 4; kb++) {
      const __hip_bfloat16* wp = wz_e2 + ((size_t)(kb * 128 + n0 + mr) * 32 + quad * 8);
      bf16x8 b0 = *(const bf16x8*)wp;
      bf16x8 b1 = *(const bf16x8*)(wp + 16 * 32);
#pragma unroll
      for (int mf = 0; mf < 4; mf++) {
        bf16x8 a = *(const bf16x8*)&S[kb][mf * 16 + mr][acol];
        a0[mf] = __builtin_amdgcn_mfma_f32_16x16x32_bf16(a, b0, a0[mf], 0, 0, 0);
        a1[mf] = __builtin_amdgcn_mfma_f32_16x16x32_bf16(a, b1, a1[mf], 0, 0, 0);
      }
    }
    float bias0 = e_b2[n0 + mr], bias1 = e_b2[n0 + 16 + mr];
    float part[4][4];
#pragma unroll
    for (int mf = 0; mf < 4; mf++)
#pragma unroll
      for (int r = 0; r < 4; r++) {
        int e = mf * 16 + quad * 4 + r;
        int es = (e >> 1) & 3;
        int c0 = (((mr >> 3) ^ es) << 3) | (mr & 7);
        int c1 = (((2 | (mr >> 3)) ^ es) << 3) | (mr & 7);
        float v0 = siluf(a0[mf][r] + bias0);
        float v1 = siluf(a1[mf][r] + bias1);
        S[4 + wave][e][c0] = __float2bfloat16(v0);
        S[4 + wave][e][c1] = __float2bfloat16(v1);
        part[mf][r] = v0 * aw0 + v1 * aw1;
      }
#pragma unroll
    for (int msk = 1; msk < 16; msk <<= 1)
#pragma unroll
      for (int mf = 0; mf < 4; mf++)
#pragma unroll
        for (int r = 0; r < 4; r++) part[mf][r] += __shfl_xor(part[mf][r], msk);
    if (mr == 0) {
#pragma unroll
      for (int mf = 0; mf < 4; mf++)
#pragma unroll
        for (int r = 0; r < 4; r++)
          s_red[wave][mf * 16 + quad * 4 + r] = part[mf][r];
    }
  }
  __syncthreads();
  if (t < TM) {
    float s = s_red[0][t] + s_red[1][t] + s_red[2][t] + s_red[3][t];
    s_att[t] = sigmf(s + att_b[0]);
  }
  __syncthreads();

  // ---- stage 3: cmh = silu(att*(ef2 @ c_w1) + c_b1) -> S[8..11] ----
  {
    f32x4 a0[4], a1[4];
#pragma unroll
    for (int mf = 0; mf < 4; mf++) { a0[mf] = zacc; a1[mf] = zacc; }
#pragma unroll
    for (int kb = 0; kb < 4; kb++) {
      const __hip_bfloat16* wp = wz_c1 + ((size_t)(kb * 128 + n0 + mr) * 32 + quad * 8);
      bf16x8 b0 = *(const bf16x8*)wp;
      bf16x8 b1 = *(const bf16x8*)(wp + 16 * 32);
#pragma unroll
      for (int mf = 0; mf < 4; mf++) {
        bf16x8 a = *(const bf16x8*)&S[4 + kb][mf * 16 + mr][acol];
        a0[mf] = __builtin_amdgcn_mfma_f32_16x16x32_bf16(a, b0, a0[mf], 0, 0, 0);
        a1[mf] = __builtin_amdgcn_mfma_f32_16x16x32_bf16(a, b1, a1[mf], 0, 0, 0);
      }
    }
    float bias0 = c_b1[n0 + mr], bias1 = c_b1[n0 + 16 + mr];
#pragma unroll
    for (int mf = 0; mf < 4; mf++)
#pragma unroll
      for (int r = 0; r < 4; r++) {
        int e = mf * 16 + quad * 4 + r;
        int es = (e >> 1) & 3;
        int c0 = (((mr >> 3) ^ es) << 3) | (mr & 7);
        int c1 = (((2 | (mr >> 3)) ^ es) << 3) | (mr & 7);
        float av = s_att[e];
        S[8 + wave][e][c0] = __float2bfloat16(siluf(av * a0[mf][r] + bias0));
        S[8 + wave][e][c1] = __float2bfloat16(siluf(av * a1[mf][r] + bias1));
      }
  }
  __syncthreads();

  // ---- cm = cmh @ c_w2 + c_b2 (each wave one 16-row tile) -> s_cm (S[0]) ----
  {
    f32x4 acc = zacc;
#pragma unroll
    for (int kb = 0; kb < 4; kb++) {
      bf16x8 a = *(const bf16x8*)&S[8 + kb][wave * 16 + mr][acol];
      bf16x8 b = *(const bf16x8*)(wz_c2 + ((size_t)(kb * 16 + mr) * 32 + quad * 8));
      acc = __builtin_amdgcn_mfma_f32_16x16x32_bf16(a, b, acc, 0, 0, 0);
    }
    if (mr < 14) {
      float bias = c_b2[mr];
#pragma unroll
      for (int r = 0; r < 4; r++)
        s_cm[(wave * 16 + quad * 4 + r) * 14 + mr] = acc[r] + bias;
    }
  }
  __syncthreads();

  // ---- RollerPooling ----
  for (int i = t; i < TM * 14; i += 256) {
    int e = i / 14, c = i % 14;
    int wsz = 15 - s_cs[e];
    int hi = min(c + wsz, 14);
    float s = 0.f;
    for (int j = c; j < hi; j++) s += s_cm[e * 14 + j];
    s_pool[e * 14 + c] = s / (float)wsz;
  }
  __syncthreads();

  // ---- trans scatter (x re-gathered from L2; packed bf16 atomics) ----
  for (int i = t; i < TM * 21; i += 256) {
    int e = i / 21, pr = i % 21;
    if (e < ne) {
      int r0 = pr * 2, r1 = r0 + 1;
      const float* xp = x + (size_t)s_row[e] * 42;
      const float* pc = pooled_x + (size_t)s_col[e] * 3;
      float v0 = (xp[r0] - pc[r0 % 3]) * s_pool[e * 14 + r0 / 3];
      float v1 = (xp[r1] - pc[r1 % 3]) * s_pool[e * 14 + r1 / 3];
      unsafeAtomicAdd(&x_acc[(size_t)s_row[e] * 21 + pr], mk_bf162(v0, v1));
    }
  }
  // ---- agg scatter (gated ef2 from S[4..7], swizzled reads) ----
  for (int i = t; i < TM * 64; i += 256) {
    int e = i >> 6, o2 = i & 63;
    if (e < ne) {
      float av = s_att[e];
      int c = (o2 & 15) * 2;
      int pc = (((c >> 3) ^ ((e >> 1) & 3)) << 3) | (c & 7);
      const __hip_bfloat16* wp2 = &S[4 + (o2 >> 4)][e][pc];
      float v0 = __bfloat162float(wp2[0]) * av;
      float v1 = __bfloat162float(wp2[1]) * av;
      unsafeAtomicAdd(&agg[(size_t)s_col[e] * 64 + o2], mk_bf162(v0, v1));
    }
  }
}

// ---- k_node: node MLP at TN=64 (M=64 structure) + residual + LN + x_new ----
// A: hb S[0..3], agg/deg S[4..7]; ef1 -> S[8..11]; stage-2 out f32 s_o over
// S[0..7]; LN 4 lanes/node, residual h re-read f32. 49.2 KB -> 3 blocks/CU.
__global__ __launch_bounds__(256, 3) void k_node(
    const float* __restrict__ h, const __hip_bfloat16* __restrict__ hb,
    const __hip_bfloat162* __restrict__ agg,
    const unsigned* __restrict__ cnt_col,
    const __hip_bfloat16* __restrict__ wz_n1, const float* __restrict__ n_b1,
    const __hip_bfloat16* __restrict__ wz_n2, const float* __restrict__ n_b2,
    const float* __restrict__ ln_g, const float* __restrict__ ln_b,
    const float* __restrict__ x, const __hip_bfloat162* __restrict__ x_acc,
    const unsigned* __restrict__ cnt_row,
    float* __restrict__ out_h, float* __restrict__ out_x, int Nn) {
  __shared__ __hip_bfloat16 S[12][TN][32];
  float* s_o = (float*)&S[0][0][0];  // [64][128] f32 over S[0..7] (stage 2 out)

  const int t = threadIdx.x;
  const int nb0 = blockIdx.x * TN;
  const int nn = min(TN, Nn - nb0);
  const int lane = t & 63, wave = t >> 6, quad = lane >> 4, mr = lane & 15;
  const int n0 = wave * 32;
  const f32x4 zacc = {0.f, 0.f, 0.f, 0.f};

  // fused x_new
  for (int i = t; i < TN * 21; i += 256) {
    int n = i / 21, pr = i % 21;
    if (n < nn) {
      int gn = nb0 + n;
      unsigned c = cnt_row[gn];
      float inv = 1.f / (float)(c > 0 ? c : 1);
      float2 xa = __bfloat1622float2(x_acc[(size_t)gn * 21 + pr]);
      size_t gi = (size_t)gn * 42 + pr * 2;
      out_x[gi]     = x[gi] + xa.x * inv;
      out_x[gi + 1] = x[gi + 1] + xa.y * inv;
    }
  }

  // ---- A staging: hb -> S[0..3], agg/deg -> S[4..7] (swizzled cols) ----
  {
    const int m = t >> 2, part = t & 3;
    const int gn = nb0 + min(m, nn - 1);
    const int pc = ((part ^ ((m >> 1) & 3)) << 3);
    const __hip_bfloat16* hr = hb + (size_t)gn * 128 + part * 8;
    unsigned c = cnt_col[gn];
    float inv = 1.f / (float)(c > 0 ? c : 1);
    const __hip_bfloat162* ag = agg + (size_t)gn * 64 + part * 4;
#pragma unroll
    for (int kb = 0; kb < 4; kb++) {
      *(int4*)&S[kb][m][pc] = *(const int4*)&hr[kb * 32];
      __hip_bfloat162 g0 = ag[kb * 16 + 0];
      __hip_bfloat162 g1 = ag[kb * 16 + 1];
      __hip_bfloat162 g2 = ag[kb * 16 + 2];
      __hip_bfloat162 g3 = ag[kb * 16 + 3];
      __hip_bfloat16* dst = &S[4 + kb][m][pc];
      float2 f0 = __bfloat1622float2(g0);
      float2 f1 = __bfloat1622float2(g1);
      float2 f2 = __bfloat1622float2(g2);
      float2 f3 = __bfloat1622float2(g3);
      dst[0] = __float2bfloat16(f0.x * inv);
      dst[1] = __float2bfloat16(f0.y * inv);
      dst[2] = __float2bfloat16(f1.x * inv);
      dst[3] = __float2bfloat16(f1.y * inv);
      dst[4] = __float2bfloat16(f2.x * inv);
      dst[5] = __float2bfloat16(f2.y * inv);
      dst[6] = __float2bfloat16(f3.x * inv);
      dst[7] = __float2bfloat16(f3.y * inv);
    }
  }
  __syncthreads();

  const int acol = ((quad ^ ((mr >> 1) & 3)) << 3);  // swizzled frag-read col

  // ---- stage 1: ef1 = silu(A @ n_w1 + n_b1), K=256, M=64 -> S[8..11] ----
  {
    f32x4 a0[4], a1[4];
#pragma unroll
    for (int mf = 0; mf < 4; mf++) { a0[mf] = zacc; a1[mf] = zacc; }
#pragma unroll
    for (int kb = 0; kb < 8; kb++) {
      const __hip_bfloat16* wp = wz_n1 + ((size_t)(kb * 128 + n0 + mr) * 32 + quad * 8);
      bf16x8 b0 = *(const bf16x8*)wp;
      bf16x8 b1 = *(const bf16x8*)(wp + 16 * 32);
#pragma unroll
      for (int mf = 0; mf < 4; mf++) {
        bf16x8 a = *(const bf16x8*)&S[kb][mf * 16 + mr][acol];
        a0[mf] = __builtin_amdgcn_mfma_f32_16x16x32_bf16(a, b0, a0[mf], 0, 0, 0);
        a1[mf] = __builtin_amdgcn_mfma_f32_16x16x32_bf16(a, b1, a1[mf], 0, 0, 0);
      }
    }
    float bias0 = n_b1[n0 + mr], bias1 = n_b1[n0 + 16 + mr];
#pragma unroll
    for (int mf = 0; mf < 4; mf++)
#pragma unroll
      for (int r = 0; r < 4; r++) {
        int e = mf * 16 + quad * 4 + r;
        int es = (e >> 1) & 3;
        int c0 = (((mr >> 3) ^ es) << 3) | (mr & 7);
        int c1 = (((2 | (mr >> 3)) ^ es) << 3) | (mr & 7);
        S[8 + wave][e][c0] = __float2bfloat16(siluf(a0[mf][r] + bias0));
        S[8 + wave][e][c1] = __float2bfloat16(siluf(a1[mf][r] + bias1));
      }
  }
  __syncthreads();  // ef1 complete; S[0..7] now dead -> reused as f32 s_o

  // ---- stage 2: nh = ef1 @ n_w2 + n_b2 -> s_o (f32, S[0..7]) ----
  {
    f32x4 a0[4], a1[4];
#pragma unroll
    for (int mf = 0; mf < 4; mf++) { a0[mf] = zacc; a1[mf] = zacc; }
#pragma unroll
    for (int kb = 0; kb < 4; kb++) {
      const __hip_bfloat16* wp = wz_n2 + ((size_t)(kb * 128 + n0 + mr) * 32 + quad * 8);
      bf16x8 b0 = *(const bf16x8*)wp;
      bf16x8 b1 = *(const bf16x8*)(wp + 16 * 32);
#pragma unroll
      for (int mf = 0; mf < 4; mf++) {
        bf16x8 a = *(const bf16x8*)&S[8 + kb][mf * 16 + mr][acol];
        a0[mf] = __builtin_amdgcn_mfma_f32_16x16x32_bf16(a, b0, a0[mf], 0, 0, 0);
        a1[mf] = __builtin_amdgcn_mfma_f32_16x16x32_bf16(a, b1, a1[mf], 0, 0, 0);
      }
    }
    float bias0 = n_b2[n0 + mr], bias1 = n_b2[n0 + 16 + mr];
#pragma unroll
    for (int mf = 0; mf < 4; mf++)
#pragma unroll
      for (int r = 0; r < 4; r++) {
        int e = mf * 16 + quad * 4 + r;
        s_o[e * 128 + n0 + mr]      = a0[mf][r] + bias0;
        s_o[e * 128 + n0 + 16 + mr] = a1[mf][r] + bias1;
      }
  }
  __syncthreads();

  // ---- LayerNorm: 4 lanes/node, 32 features each; residual h f32 ----
  {
    int n = t >> 2, q = t & 3;
    int gn = nb0 + min(n, nn - 1);
    const float* hp = h + (size_t)gn * 128 + q * 32;
    const float* op = s_o + n * 128 + q * 32;
    float v[32];
    float s = 0.f;
#pragma unroll
    for (int j = 0; j < 32; j++) {
      v[j] = hp[j] + op[j];
      s += v[j];
    }
    s += __shfl_xor(s, 1); s += __shfl_xor(s, 2);
    float mu = s * (1.f / 128.f);
    float var = 0.f;
#pragma unroll
    for (int j = 0; j < 32; j++) {
      float d = v[j] - mu;
      var += d * d;
    }
    var += __shfl_xor(var, 1); var += __shfl_xor(var, 2);
    float rs = rsqrtf(var * (1.f / 128.f) + 1e-5f);
    if (n < nn) {
      size_t base = (size_t)gn * 128 + q * 32;
#pragma unroll
      for (int j = 0; j < 32; j++)
        out_h[base + j] = (v[j] - mu) * rs * ln_g[q * 32 + j] + ln_b[q * 32 + j];
    }
  }
}

extern "C" void kernel_launch(void* const* d_in, const int* in_sizes, int n_in,
                              void* d_out, int out_size, void* d_ws, size_t ws_size,
                              hipStream_t stream) {
  const float* h     = (const float*)d_in[0];
  const float* x     = (const float*)d_in[1];
  const float* attr  = (const float*)d_in[2];
  const float* cw    = (const float*)d_in[3];
  const int*   row   = (const int*)d_in[4];
  const int*   col   = (const int*)d_in[5];
  const float* rad_w = (const float*)d_in[6];
  const float* rad_b = (const float*)d_in[7];
  const float* e_w1  = (const float*)d_in[8];
  const float* e_b1  = (const float*)d_in[9];
  const float* e_w2  = (const float*)d_in[10];
  const float* e_b2  = (const float*)d_in[11];
  const float* att_w = (const float*)d_in[12];
  const float* att_b = (const float*)d_in[13];
  const float* c_w1  = (const float*)d_in[14];
  const float* c_b1  = (const float*)d_in[15];
  const float* c_w2  = (const float*)d_in[16];
  const float* c_b2  = (const float*)d_in[17];
  const float* n_w1  = (const float*)d_in[18];
  const float* n_b1  = (const float*)d_in[19];
  const float* n_w2  = (const float*)d_in[20];
  const float* n_b2  = (const float*)d_in[21];
  const float* ln_g  = (const float*)d_in[22];
  const float* ln_b  = (const float*)d_in[23];

  const int N = in_sizes[0] / 128;
  const int E = in_sizes[4];

  char* ws = (char*)d_ws;
  size_t off = 0;
  auto alloc = [&](size_t bytes) {
    size_t o = off;
    off += (bytes + 255) & ~(size_t)255;
    return o;
  };
  size_t off_wzr  = alloc(32768 * sizeof(__hip_bfloat16));
  size_t off_wz1  = alloc(49152 * sizeof(__hip_bfloat16));
  size_t off_wz2  = alloc(16384 * sizeof(__hip_bfloat16));
  size_t off_wzc  = alloc(16384 * sizeof(__hip_bfloat16));
  size_t off_wzn1 = alloc(32768 * sizeof(__hip_bfloat16));
  size_t off_wzn2 = alloc(16384 * sizeof(__hip_bfloat16));
  size_t off_wzc2 = alloc(2048 * sizeof(__hip_bfloat16));
  size_t off_atS  = alloc((size_t)N * 256 * sizeof(__hip_bfloat16));
  size_t off_hb   = alloc((size_t)N * 128 * sizeof(__hip_bfloat16));
  size_t off_px   = alloc((size_t)N * 3 * sizeof(float));
  size_t off_cs   = alloc((size_t)N * sizeof(int));
  size_t off_cntr = alloc((size_t)N * sizeof(unsigned));
  size_t off_cntc = alloc((size_t)N * sizeof(unsigned));
  size_t off_xacc = alloc((size_t)N * 21 * sizeof(__hip_bfloat162));
  size_t off_agg  = alloc((size_t)N * 64 * sizeof(__hip_bfloat162));

  __hip_bfloat16* wz_rad = (__hip_bfloat16*)(ws + off_wzr);
  __hip_bfloat16* wz_e1  = (__hip_bfloat16*)(ws + off_wz1);
  __hip_bfloat16* wz_e2  = (__hip_bfloat16*)(ws + off_wz2);
  __hip_bfloat16* wz_c1  = (__hip_bfloat16*)(ws + off_wzc);
  __hip_bfloat16* wz_n1  = (__hip_bfloat16*)(ws + off_wzn1);
  __hip_bfloat16* wz_n2  = (__hip_bfloat16*)(ws + off_wzn2);
  __hip_bfloat16* wz_c2  = (__hip_bfloat16*)(ws + off_wzc2);
  __hip_bfloat16* attrS  = (__hip_bfloat16*)(ws + off_atS);
  __hip_bfloat16* hb     = (__hip_bfloat16*)(ws + off_hb);
  float* pooled_x   = (float*)(ws + off_px);
  int* chsum        = (int*)(ws + off_cs);
  unsigned* cnt_row = (unsigned*)(ws + off_cntr);
  unsigned* cnt_col = (unsigned*)(ws + off_cntc);
  __hip_bfloat162* x_acc = (__hip_bfloat162*)(ws + off_xacc);
  __hip_bfloat162* agg   = (__hip_bfloat162*)(ws + off_agg);

  (void)hipMemsetAsync(ws + off_cntr, 0, off - off_cntr, stream);

  const int pack_items = 165888 + N * 256 + N * 128 + N;
  k_pack<<<dim3((pack_items + 255) / 256), dim3(256), 0, stream>>>(
      h, x, attr, cw, rad_w, e_w1, e_w2, c_w1, n_w1, n_w2, c_w2,
      wz_rad, wz_e1, wz_e2, wz_c1, wz_n1, wz_n2, wz_c2,
      attrS, hb, pooled_x, chsum, N);
  k_mega<<<dim3((E + TM - 1) / TM), dim3(256), 0, stream>>>(
      hb, x, attrS, row, col, pooled_x, chsum,
      wz_rad, rad_b, wz_e1, e_b1, wz_e2, e_b2, att_w, att_b,
      wz_c1, c_b1, wz_c2, c_b2, cnt_row, cnt_col, x_acc, agg, E);
  k_node<<<dim3((N + TN - 1) / TN), dim3(256), 0, stream>>>(
      h, hb, agg, cnt_col, wz_n1, n_b1, wz_n2, n_b2, ln_g, ln_b,
      x, x_acc, cnt_row, (float*)d_out, (float*)d_out + (size_t)N * 128, N);
}

// Round 7
// 349.916 us; speedup vs baseline: 1.2898x; 1.1310x over previous
//
#include <hip/hip_runtime.h>
#include <hip/hip_bf16.h>

// EnhancedGNNEncoder round 16: k_mega instruction-count cuts.
//  - Einsum via mfma_f32_16x16x16bf16_1k: dD (per-lane direct) IS the A-frag
//    of m1; m1's D-layout IS the B-frag of the radial MFMA. Deletes 16
//    bpermute + 16 cvt per edge (the aD/bM transposes).
//  - Paired weight swizzle: lane mr computes cols n0+2mr, n0+2mr+1 ->
//    epilogues write one bf162 (cvt_pk) instead of 2x cvt + 2x ds_write_b16;
//    biases load as float2. Applied to rad/e1/e2/c1 (k_mega) + n1/n2 (k_node).
//  - k_node reverted to round-13 TN=16 (TN=64 LN regressed) + packed epilogue.
// MFMA 16x16x32: A[m=lane&15][k=quad*8+j], B[k=quad*8+j][n=lane&15].
// MFMA 16x16x16: A[m=lane&15][k=quad*4+j], B[k=quad*4+j][n=lane&15].
// D (both): col=lane&15, row=quad*4+reg.

#define TM 64
#define TN 16
#define PAD 36

typedef __attribute__((ext_vector_type(8))) short bf16x8;
typedef __attribute__((ext_vector_type(4))) short bf16x4;
typedef __attribute__((ext_vector_type(4))) float f32x4;

__device__ __forceinline__ float siluf(float v) { return v / (1.f + __expf(-v)); }
__device__ __forceinline__ float sigmf(float v) { return 1.f / (1.f + __expf(-v)); }
__device__ __forceinline__ short f2bs(float f) {
  union { __hip_bfloat16 b; short s; } u;
  u.b = __float2bfloat16(f);
  return u.s;
}
__device__ __forceinline__ __hip_bfloat162 mk_bf162(float v0, float v1) {
  __hip_bfloat162 r;
  r.x = __float2bfloat16(v0);
  r.y = __float2bfloat16(v1);
  return r;
}

// ---- pack: weight swizzle (paired-col) + attrS + h_bf16 + per-node prep ----
__global__ __launch_bounds__(256) void k_pack(
    const float* __restrict__ h, const float* __restrict__ x,
    const float* __restrict__ attr, const float* __restrict__ cw,
    const float* __restrict__ rad_w, const float* __restrict__ e_w1,
    const float* __restrict__ e_w2, const float* __restrict__ c_w1,
    const float* __restrict__ n_w1, const float* __restrict__ n_w2,
    const float* __restrict__ c_w2,
    __hip_bfloat16* __restrict__ wz_rad, __hip_bfloat16* __restrict__ wz_e1,
    __hip_bfloat16* __restrict__ wz_e2, __hip_bfloat16* __restrict__ wz_c1,
    __hip_bfloat16* __restrict__ wz_n1, __hip_bfloat16* __restrict__ wz_n2,
    __hip_bfloat16* __restrict__ wz_c2,
    __hip_bfloat16* __restrict__ attrS, __hip_bfloat16* __restrict__ hb,
    float* __restrict__ pooled_x, int* __restrict__ chsum, int Nn) {
  int idx = blockIdx.x * 256 + threadIdx.x;
  if (idx < 165888) {  // weight swizzle
    int i = idx;
    if (i >= 163840) {  // c_w2: [128][14] -> [4][16][32], n=14,15 zero
      int base = i - 163840;
      int k = base >> 4, n = base & 15;
      wz_c2[(size_t)(k >> 5) * 512 + n * 32 + (k & 31)] =
          (n < 14) ? __float2bfloat16(c_w2[k * 14 + n]) : __float2bfloat16(0.f);
      return;
    }
    const float* W;
    __hip_bfloat16* O;
    int base;
    if (i < 32768) { W = rad_w; O = wz_rad; base = i; }
    else if (i < 81920) { W = e_w1; O = wz_e1; base = i - 32768; }
    else if (i < 98304) { W = e_w2; O = wz_e2; base = i - 81920; }
    else if (i < 114688) { W = c_w1; O = wz_c1; base = i - 98304; }
    else if (i < 147456) { W = n_w1; O = wz_n1; base = i - 114688; }
    else { W = n_w2; O = wz_n2; base = i - 147456; }
    int k = base >> 7, n = base & 127;
    // paired-col storage row: b0 slot (row g*32+mr) holds col g*32+2mr,
    // b1 slot (row g*32+16+mr) holds col g*32+2mr+1
    int nr_ = ((n >> 5) << 5) | ((n & 1) << 4) | ((n & 31) >> 1);
    O[(size_t)((k >> 5) * 128 + nr_) * 32 + (k & 31)] = __float2bfloat16(W[base]);
    return;
  }
  idx -= 165888;
  int na = Nn * 256, nh = Nn * 128;
  if (idx < na) {
    int n = idx >> 8, r = idx & 255, i2 = r >> 4, a = r & 15;
    float v = 0.f;
    if (i2 < 14) v = attr[(size_t)n * 224 + i2 * 16 + a] * cw[(size_t)n * 14 + i2];
    attrS[(size_t)n * 256 + a * 16 + i2] = __float2bfloat16(v);
    return;
  }
  idx -= na;
  if (idx < nh) {
    hb[idx] = __float2bfloat16(h[idx]);
    return;
  }
  idx -= nh;
  if (idx >= Nn) return;
  int n = idx;
  int cnt = 0;
  float sx = 0.f, sy = 0.f, sz = 0.f;
#pragma unroll
  for (int c = 0; c < 14; c++) {
    float w = cw[n * 14 + c];
    if (w != 0.f) {
      cnt++;
      sx += x[n * 42 + c * 3 + 0];
      sy += x[n * 42 + c * 3 + 1];
      sz += x[n * 42 + c * 3 + 2];
    }
  }
  chsum[n] = cnt;
  float inv = 1.f / (float)(cnt > 0 ? cnt : 1);
  pooled_x[n * 3 + 0] = sx * inv;
  pooled_x[n * 3 + 1] = sy * inv;
  pooled_x[n * 3 + 2] = sz * inv;
}

// ---- k_mega: einsum + rad GEMM + edge MLP + gate + roller + scatters ----
__global__ __launch_bounds__(256, 3) void k_mega(
    const __hip_bfloat16* __restrict__ hb, const float* __restrict__ x,
    const __hip_bfloat16* __restrict__ attrS,
    const int* __restrict__ row, const int* __restrict__ col,
    const float* __restrict__ pooled_x, const int* __restrict__ chsum,
    const __hip_bfloat16* __restrict__ wz_rad, const float* __restrict__ rad_b,
    const __hip_bfloat16* __restrict__ wz_e1, const float* __restrict__ e_b1,
    const __hip_bfloat16* __restrict__ wz_e2, const float* __restrict__ e_b2,
    const float* __restrict__ att_w, const float* __restrict__ att_b,
    const __hip_bfloat16* __restrict__ wz_c1, const float* __restrict__ c_b1,
    const __hip_bfloat16* __restrict__ wz_c2, const float* __restrict__ c_b2,
    unsigned* __restrict__ cnt_row, unsigned* __restrict__ cnt_col,
    __hip_bfloat162* __restrict__ x_acc, __hip_bfloat162* __restrict__ agg,
    int Ee) {
  __shared__ __hip_bfloat16 S[12][TM][32];
  __shared__ float s_att[TM];
  __shared__ float s_red[4][TM];
  __shared__ float s_rn[TM];
  __shared__ int s_row[TM], s_col[TM], s_cs[TM];
  float* s_cm   = (float*)&S[0][0][0];
  float* s_pool = (float*)&S[1][0][0];

  const int t = threadIdx.x;
  const int e0 = blockIdx.x * TM;
  const int ne = min(TM, Ee - e0);
  const int lane = t & 63, wave = t >> 6, quad = lane >> 4, mr = lane & 15;
  const int n0 = wave * 32;
  const f32x4 zacc = {0.f, 0.f, 0.f, 0.f};
  const bf16x4 zero4 = {0, 0, 0, 0};

  // ---- phase 0: edge meta + degree atomics ----
  if (t < TM) {
    int ge = e0 + min(t, ne - 1);
    int r = row[ge], c = col[ge];
    s_row[t] = r;
    s_col[t] = c;
    s_cs[t] = chsum[r];
    if (t < ne) {
      atomicAdd(&cnt_row[r], 1u);
      atomicAdd(&cnt_col[c], 1u);
    }
  }

  // ---- phase 1: einsum via 16x16x16 MFMAs (no transpose shfls) ----
#pragma unroll 1
  for (int b = 0; b < 4; b++) {
    float xr0v[4], xr1v[4], xr2v[4], xc0v[4], xc1v[4], xc2v[4];
    bf16x4 bCv[4], aRv[4];
#pragma unroll
    for (int p = 0; p < 4; p++) {
      const int e = wave * 16 + b * 4 + p;
      const int ge = e0 + min(e, ne - 1);
      const int re = row[ge], ce = col[ge];  // wave-uniform -> scalar loads
      const int mrc = min(mr, 13);
      const float* xp = x + (size_t)re * 42 + mrc * 3;
      xr0v[p] = xp[0]; xr1v[p] = xp[1]; xr2v[p] = xp[2];
      const float* xq = x + (size_t)ce * 42 + mrc * 3;
      xc0v[p] = xq[0]; xc1v[p] = xq[1]; xc2v[p] = xq[2];
      // B-frag (16x16x16): attr[ch=quad*4+j][dim=mr]
      bCv[p] = *(const bf16x4*)&attrS[(size_t)ce * 256 + mr * 16 + quad * 4];
      aRv[p] = *(const bf16x4*)&attrS[(size_t)re * 256 + mr * 16 + quad * 4];
    }
#pragma unroll
    for (int p = 0; p < 4; p++) {
      const int e = wave * 16 + b * 4 + p;
      const float xr0 = xr0v[p], xr1 = xr1v[p], xr2 = xr2v[p];
      const float xc0 = xc0v[p], xc1 = xc1v[p], xc2 = xc2v[p];
      const float nr = xr0 * xr0 + xr1 * xr1 + xr2 * xr2;
      const float nc = xc0 * xc0 + xc1 * xc1 + xc2 * xc2;
      // G[quad*4+r][mr] = xc_{quad*4+r} . xr_{mr}
      bf16x4 aX = zero4, bX = zero4;
      if (quad == 0) {
        aX[0] = f2bs(xc0); aX[1] = f2bs(xc1); aX[2] = f2bs(xc2);
        bX[0] = f2bs(xr0); bX[1] = f2bs(xr1); bX[2] = f2bs(xr2);
      }
      f32x4 G = __builtin_amdgcn_mfma_f32_16x16x16bf16_1k(aX, bX, zacc, 0, 0, 0);
      // dD[r] = ||xr_mr - xc_{quad*4+r}|| -> directly the A-frag of m1
      bf16x4 aM;
#pragma unroll
      for (int r = 0; r < 4; r++) {
        float ncj = __shfl(nc, quad * 4 + r);
        aM[r] = f2bs(sqrtf(fmaxf(ncj + nr - 2.f * G[r], 0.f)));
      }
      f32x4 m1 = __builtin_amdgcn_mfma_f32_16x16x16bf16_1k(aM, bCv[p], zacc, 0, 0, 0);
      // m1 D-layout [c=quad*4+r][b=mr] IS the B-frag of the radial MFMA
      bf16x4 bM;
#pragma unroll
      for (int r = 0; r < 4; r++) bM[r] = f2bs(m1[r]);
      f32x4 rd = __builtin_amdgcn_mfma_f32_16x16x16bf16_1k(aRv[p], bM, zacc, 0, 0, 0);
      float ss = rd[0] * rd[0] + rd[1] * rd[1] + rd[2] * rd[2] + rd[3] * rd[3];
      ss += __shfl_xor(ss, 32); ss += __shfl_xor(ss, 16); ss += __shfl_xor(ss, 8);
      ss += __shfl_xor(ss, 4);  ss += __shfl_xor(ss, 2);  ss += __shfl_xor(ss, 1);
      if (lane == 0) s_rn[e] = sqrtf(ss) + 1.0f;
      // radial[a=quad*4+r][b=mr] -> feature aa*16+mr, natural order, e-swizzled
#pragma unroll
      for (int r = 0; r < 4; r++) {
        const int aa = quad * 4 + r;
        const int c = ((aa & 1) << 4) | mr;
        const int pcol = (((c >> 3) ^ ((e >> 1) & 3)) << 3) | (c & 7);
        S[aa >> 1][e][pcol] = __float2bfloat16(rd[r]);
      }
    }
  }
  __syncthreads();

  const int acol = ((quad ^ ((mr >> 1) & 3)) << 3);  // swizzled frag-read col
  const int m2 = 2 * mr;                             // paired output col base

  // ---- phase 2: rad GEMM radial@rad_w -> radf in S[8..11] (packed writes) ----
  {
    f32x4 a0[4], a1[4];
#pragma unroll
    for (int mf = 0; mf < 4; mf++) { a0[mf] = zacc; a1[mf] = zacc; }
#pragma unroll
    for (int kb = 0; kb < 8; kb++) {
      const __hip_bfloat16* wp = wz_rad + ((size_t)(kb * 128 + n0 + mr) * 32 + quad * 8);
      bf16x8 b0 = *(const bf16x8*)wp;
      bf16x8 b1 = *(const bf16x8*)(wp + 16 * 32);
#pragma unroll
      for (int mf = 0; mf < 4; mf++) {
        bf16x8 a = *(const bf16x8*)&S[kb][mf * 16 + mr][acol];
        a0[mf] = __builtin_amdgcn_mfma_f32_16x16x32_bf16(a, b0, a0[mf], 0, 0, 0);
        a1[mf] = __builtin_amdgcn_mfma_f32_16x16x32_bf16(a, b1, a1[mf], 0, 0, 0);
      }
    }
    const float2 rbp = *(const float2*)&rad_b[n0 + m2];
#pragma unroll
    for (int mf = 0; mf < 4; mf++)
#pragma unroll
      for (int r = 0; r < 4; r++) {
        int e = mf * 16 + quad * 4 + r;
        int pc2 = ((((m2) >> 3) ^ ((e >> 1) & 3)) << 3) | (m2 & 7);
        float inv = 1.f / s_rn[e];
        *(__hip_bfloat162*)&S[8 + wave][e][pc2] =
            mk_bf162((a0[mf][r] + rbp.x) * inv, (a1[mf][r] + rbp.y) * inv);
      }
  }
  __syncthreads();

  // ---- phase 3: stage h_row -> S[0..3], h_col -> S[4..7] ----
  {
    const int m = t >> 2, part = t & 3;
    const int pc = ((part ^ ((m >> 1) & 3)) << 3);
    const __hip_bfloat16* hr = hb + (size_t)s_row[m] * 128 + part * 8;
    const __hip_bfloat16* hc = hb + (size_t)s_col[m] * 128 + part * 8;
#pragma unroll
    for (int kb = 0; kb < 4; kb++) {
      *(int4*)&S[kb][m][pc]     = *(const int4*)&hr[kb * 32];
      *(int4*)&S[4 + kb][m][pc] = *(const int4*)&hc[kb * 32];
    }
  }
  __syncthreads();

  // ---- stage 1: ef1 = silu(A @ e_w1 + e_b1), K=384, M=64 (acc in regs) ----
  f32x4 s1a0[4], s1a1[4];
#pragma unroll
  for (int mf = 0; mf < 4; mf++) { s1a0[mf] = zacc; s1a1[mf] = zacc; }
#pragma unroll
  for (int kb = 0; kb < 12; kb++) {
    const __hip_bfloat16* wp = wz_e1 + ((size_t)(kb * 128 + n0 + mr) * 32 + quad * 8);
    bf16x8 b0 = *(const bf16x8*)wp;
    bf16x8 b1 = *(const bf16x8*)(wp + 16 * 32);
#pragma unroll
    for (int mf = 0; mf < 4; mf++) {
      bf16x8 a = *(const bf16x8*)&S[kb][mf * 16 + mr][acol];
      s1a0[mf] = __builtin_amdgcn_mfma_f32_16x16x32_bf16(a, b0, s1a0[mf], 0, 0, 0);
      s1a1[mf] = __builtin_amdgcn_mfma_f32_16x16x32_bf16(a, b1, s1a1[mf], 0, 0, 0);
    }
  }
  __syncthreads();  // all waves done reading A before ef1 overwrites S[0..3]
  {
    const float2 b1p = *(const float2*)&e_b1[n0 + m2];
#pragma unroll
    for (int mf = 0; mf < 4; mf++)
#pragma unroll
      for (int r = 0; r < 4; r++) {
        int e = mf * 16 + quad * 4 + r;
        int pc2 = (((m2 >> 3) ^ ((e >> 1) & 3)) << 3) | (m2 & 7);
        *(__hip_bfloat162*)&S[wave][e][pc2] =
            mk_bf162(siluf(s1a0[mf][r] + b1p.x), siluf(s1a1[mf][r] + b1p.y));
      }
  }
  __syncthreads();

  // ---- stage 2: ef2 = silu(ef1 @ e_w2 + e_b2) -> S[4..7]; gate partials ----
  const float2 awp = *(const float2*)&att_w[n0 + m2];
  {
    f32x4 a0[4], a1[4];
#pragma unroll
    for (int mf = 0; mf < 4; mf++) { a0[mf] = zacc; a1[mf] = zacc; }
#pragma unroll
    for (int kb = 0; kb < 4; kb++) {
      const __hip_bfloat16* wp = wz_e2 + ((size_t)(kb * 128 + n0 + mr) * 32 + quad * 8);
      bf16x8 b0 = *(const bf16x8*)wp;
      bf16x8 b1 = *(const bf16x8*)(wp + 16 * 32);
#pragma unroll
      for (int mf = 0; mf < 4; mf++) {
        bf16x8 a = *(const bf16x8*)&S[kb][mf * 16 + mr][acol];
        a0[mf] = __builtin_amdgcn_mfma_f32_16x16x32_bf16(a, b0, a0[mf], 0, 0, 0);
        a1[mf] = __builtin_amdgcn_mfma_f32_16x16x32_bf16(a, b1, a1[mf], 0, 0, 0);
      }
    }
    const float2 b2p = *(const float2*)&e_b2[n0 + m2];
    float part[4][4];
#pragma unroll
    for (int mf = 0; mf < 4; mf++)
#pragma unroll
      for (int r = 0; r < 4; r++) {
        int e = mf * 16 + quad * 4 + r;
        int pc2 = (((m2 >> 3) ^ ((e >> 1) & 3)) << 3) | (m2 & 7);
        float v0 = siluf(a0[mf][r] + b2p.x);
        float v1 = siluf(a1[mf][r] + b2p.y);
        *(__hip_bfloat162*)&S[4 + wave][e][pc2] = mk_bf162(v0, v1);
        part[mf][r] = v0 * awp.x + v1 * awp.y;
      }
#pragma unroll
    for (int msk = 1; msk < 16; msk <<= 1)
#pragma unroll
      for (int mf = 0; mf < 4; mf++)
#pragma unroll
        for (int r = 0; r < 4; r++) part[mf][r] += __shfl_xor(part[mf][r], msk);
    if (mr == 0) {
#pragma unroll
      for (int mf = 0; mf < 4; mf++)
#pragma unroll
        for (int r = 0; r < 4; r++)
          s_red[wave][mf * 16 + quad * 4 + r] = part[mf][r];
    }
  }
  __syncthreads();
  if (t < TM) {
    float s = s_red[0][t] + s_red[1][t] + s_red[2][t] + s_red[3][t];
    s_att[t] = sigmf(s + att_b[0]);
  }
  __syncthreads();

  // ---- stage 3: cmh = silu(att*(ef2 @ c_w1) + c_b1) -> S[8..11] ----
  {
    f32x4 a0[4], a1[4];
#pragma unroll
    for (int mf = 0; mf < 4; mf++) { a0[mf] = zacc; a1[mf] = zacc; }
#pragma unroll
    for (int kb = 0; kb < 4; kb++) {
      const __hip_bfloat16* wp = wz_c1 + ((size_t)(kb * 128 + n0 + mr) * 32 + quad * 8);
      bf16x8 b0 = *(const bf16x8*)wp;
      bf16x8 b1 = *(const bf16x8*)(wp + 16 * 32);
#pragma unroll
      for (int mf = 0; mf < 4; mf++) {
        bf16x8 a = *(const bf16x8*)&S[4 + kb][mf * 16 + mr][acol];
        a0[mf] = __builtin_amdgcn_mfma_f32_16x16x32_bf16(a, b0, a0[mf], 0, 0, 0);
        a1[mf] = __builtin_amdgcn_mfma_f32_16x16x32_bf16(a, b1, a1[mf], 0, 0, 0);
      }
    }
    const float2 cbp = *(const float2*)&c_b1[n0 + m2];
#pragma unroll
    for (int mf = 0; mf < 4; mf++)
#pragma unroll
      for (int r = 0; r < 4; r++) {
        int e = mf * 16 + quad * 4 + r;
        int pc2 = (((m2 >> 3) ^ ((e >> 1) & 3)) << 3) | (m2 & 7);
        float av = s_att[e];
        *(__hip_bfloat162*)&S[8 + wave][e][pc2] =
            mk_bf162(siluf(av * a0[mf][r] + cbp.x), siluf(av * a1[mf][r] + cbp.y));
      }
  }
  __syncthreads();

  // ---- cm = cmh @ c_w2 + c_b2 (each wave one 16-row tile) -> s_cm (S[0]) ----
  {
    f32x4 acc = zacc;
#pragma unroll
    for (int kb = 0; kb < 4; kb++) {
      bf16x8 a = *(const bf16x8*)&S[8 + kb][wave * 16 + mr][acol];
      bf16x8 b = *(const bf16x8*)(wz_c2 + ((size_t)(kb * 16 + mr) * 32 + quad * 8));
      acc = __builtin_amdgcn_mfma_f32_16x16x32_bf16(a, b, acc, 0, 0, 0);
    }
    if (mr < 14) {
      float bias = c_b2[mr];
#pragma unroll
      for (int r = 0; r < 4; r++)
        s_cm[(wave * 16 + quad * 4 + r) * 14 + mr] = acc[r] + bias;
    }
  }
  __syncthreads();

  // ---- RollerPooling ----
  for (int i = t; i < TM * 14; i += 256) {
    int e = i / 14, c = i % 14;
    int wsz = 15 - s_cs[e];
    int hi = min(c + wsz, 14);
    float s = 0.f;
    for (int j = c; j < hi; j++) s += s_cm[e * 14 + j];
    s_pool[e * 14 + c] = s / (float)wsz;
  }
  __syncthreads();

  // ---- trans scatter (x re-gathered from L2; packed bf16 atomics) ----
  for (int i = t; i < TM * 21; i += 256) {
    int e = i / 21, pr = i % 21;
    if (e < ne) {
      int r0 = pr * 2, r1 = r0 + 1;
      const float* xp = x + (size_t)s_row[e] * 42;
      const float* pc = pooled_x + (size_t)s_col[e] * 3;
      float v0 = (xp[r0] - pc[r0 % 3]) * s_pool[e * 14 + r0 / 3];
      float v1 = (xp[r1] - pc[r1 % 3]) * s_pool[e * 14 + r1 / 3];
      unsafeAtomicAdd(&x_acc[(size_t)s_row[e] * 21 + pr], mk_bf162(v0, v1));
    }
  }
  // ---- agg scatter (gated ef2 from S[4..7], swizzled reads) ----
  for (int i = t; i < TM * 64; i += 256) {
    int e = i >> 6, o2 = i & 63;
    if (e < ne) {
      float av = s_att[e];
      int c = (o2 & 15) * 2;
      int pc = (((c >> 3) ^ ((e >> 1) & 3)) << 3) | (c & 7);
      const __hip_bfloat16* wp2 = &S[4 + (o2 >> 4)][e][pc];
      float v0 = __bfloat162float(wp2[0]) * av;
      float v1 = __bfloat162float(wp2[1]) * av;
      unsafeAtomicAdd(&agg[(size_t)s_col[e] * 64 + o2], mk_bf162(v0, v1));
    }
  }
}

// ---- node MLP (MFMA) + residual + in-wave LayerNorm + fused x_new ----
__global__ __launch_bounds__(256) void k_node(
    const float* __restrict__ h, const __hip_bfloat162* __restrict__ agg,
    const unsigned* __restrict__ cnt_col,
    const __hip_bfloat16* __restrict__ wz_n1, const float* __restrict__ n_b1,
    const __hip_bfloat16* __restrict__ wz_n2, const float* __restrict__ n_b2,
    const float* __restrict__ ln_g, const float* __restrict__ ln_b,
    const float* __restrict__ x, const __hip_bfloat162* __restrict__ x_acc,
    const unsigned* __restrict__ cnt_row,
    float* __restrict__ out_h, float* __restrict__ out_x, int Nn) {
  __shared__ __hip_bfloat16 sA[8][16][PAD];
  __shared__ __hip_bfloat16 sT[4][16][PAD];
  __shared__ float s_h[TN][128];
  __shared__ float s_o[TN][132];
  const int t = threadIdx.x;
  const int nb0 = blockIdx.x * TN;
  const int nn = min(TN, Nn - nb0);

  // fused x_new
  for (int i = t; i < TN * 21; i += 256) {
    int n = i / 21, pr = i % 21;
    if (n < nn) {
      int gn = nb0 + n;
      unsigned c = cnt_row[gn];
      float inv = 1.f / (float)(c > 0 ? c : 1);
      float2 xa = __bfloat1622float2(x_acc[(size_t)gn * 21 + pr]);
      size_t gi = (size_t)gn * 42 + pr * 2;
      out_x[gi]     = x[gi] + xa.x * inv;
      out_x[gi + 1] = x[gi + 1] + xa.y * inv;
    }
  }

  for (int i = t; i < TN * 64; i += 256) {
    int m = i >> 6, kp = (i & 63) << 1;
    int kb = kp >> 5, kk = kp & 31;
    int gn = nb0 + min(m, nn - 1);
    const float2 hv = *(const float2*)&h[(size_t)gn * 128 + kp];
    sA[kb][m][kk]     = __float2bfloat16(hv.x);
    sA[kb][m][kk + 1] = __float2bfloat16(hv.y);
    s_h[m][kp]     = hv.x;
    s_h[m][kp + 1] = hv.y;
    unsigned c = cnt_col[gn];
    float inv = 1.f / (float)(c > 0 ? c : 1);
    float2 gv = __bfloat1622float2(agg[(size_t)gn * 64 + (kp >> 1)]);
    sA[4 + kb][m][kk]     = __float2bfloat16(gv.x * inv);
    sA[4 + kb][m][kk + 1] = __float2bfloat16(gv.y * inv);
  }
  __syncthreads();
  const int lane = t & 63, wave = t >> 6, quad = lane >> 4, mr = lane & 15;
  const int n0 = wave * 32;
  const int m2 = 2 * mr;
  f32x4 zacc = {0.f, 0.f, 0.f, 0.f};
  {
    f32x4 acc0 = zacc, acc1 = zacc;
#pragma unroll
    for (int kb = 0; kb < 8; kb++) {
      bf16x8 a = *(const bf16x8*)&sA[kb][mr][quad * 8];
      const __hip_bfloat16* wp = wz_n1 + ((size_t)(kb * 128 + n0 + mr) * 32 + quad * 8);
      bf16x8 b0 = *(const bf16x8*)wp;
      bf16x8 b1 = *(const bf16x8*)(wp + 16 * 32);
      acc0 = __builtin_amdgcn_mfma_f32_16x16x32_bf16(a, b0, acc0, 0, 0, 0);
      acc1 = __builtin_amdgcn_mfma_f32_16x16x32_bf16(a, b1, acc1, 0, 0, 0);
    }
    const float2 b1p = *(const float2*)&n_b1[n0 + m2];
#pragma unroll
    for (int r = 0; r < 4; r++) {
      int m = quad * 4 + r;
      *(__hip_bfloat162*)&sT[wave][m][m2] =
          mk_bf162(siluf(acc0[r] + b1p.x), siluf(acc1[r] + b1p.y));
    }
  }
  __syncthreads();
  {
    f32x4 acc0 = zacc, acc1 = zacc;
#pragma unroll
    for (int kb = 0; kb < 4; kb++) {
      bf16x8 a = *(const bf16x8*)&sT[kb][mr][quad * 8];
      const __hip_bfloat16* wp = wz_n2 + ((size_t)(kb * 128 + n0 + mr) * 32 + quad * 8);
      bf16x8 b0 = *(const bf16x8*)wp;
      bf16x8 b1 = *(const bf16x8*)(wp + 16 * 32);
      acc0 = __builtin_amdgcn_mfma_f32_16x16x32_bf16(a, b0, acc0, 0, 0, 0);
      acc1 = __builtin_amdgcn_mfma_f32_16x16x32_bf16(a, b1, acc1, 0, 0, 0);
    }
    const float2 b2p = *(const float2*)&n_b2[n0 + m2];
#pragma unroll
    for (int r = 0; r < 4; r++) {
      int m = quad * 4 + r;
      s_o[m][n0 + m2]     = s_h[m][n0 + m2] + acc0[r] + b2p.x;
      s_o[m][n0 + m2 + 1] = s_h[m][n0 + m2 + 1] + acc1[r] + b2p.y;
    }
  }
  __syncthreads();
  // ---- in-wave LayerNorm: node n's 16 threads are contiguous lanes ----
  {
    int n = t >> 4, p = t & 15;
    float v[8];
    float s = 0.f;
#pragma unroll
    for (int j = 0; j < 8; j++) {
      v[j] = s_o[n][p * 8 + j];
      s += v[j];
    }
    s += __shfl_xor(s, 1); s += __shfl_xor(s, 2);
    s += __shfl_xor(s, 4); s += __shfl_xor(s, 8);
    float mu = s * (1.f / 128.f);
    float var = 0.f;
#pragma unroll
    for (int j = 0; j < 8; j++) {
      float d = v[j] - mu;
      var += d * d;
    }
    var += __shfl_xor(var, 1); var += __shfl_xor(var, 2);
    var += __shfl_xor(var, 4); var += __shfl_xor(var, 8);
    float rs = rsqrtf(var * (1.f / 128.f) + 1e-5f);
    if (n < nn) {
      size_t base = (size_t)(nb0 + n) * 128 + p * 8;
#pragma unroll
      for (int j = 0; j < 8; j++)
        out_h[base + j] = (v[j] - mu) * rs * ln_g[p * 8 + j] + ln_b[p * 8 + j];
    }
  }
}

extern "C" void kernel_launch(void* const* d_in, const int* in_sizes, int n_in,
                              void* d_out, int out_size, void* d_ws, size_t ws_size,
                              hipStream_t stream) {
  const float* h     = (const float*)d_in[0];
  const float* x     = (const float*)d_in[1];
  const float* attr  = (const float*)d_in[2];
  const float* cw    = (const float*)d_in[3];
  const int*   row   = (const int*)d_in[4];
  const int*   col   = (const int*)d_in[5];
  const float* rad_w = (const float*)d_in[6];
  const float* rad_b = (const float*)d_in[7];
  const float* e_w1  = (const float*)d_in[8];
  const float* e_b1  = (const float*)d_in[9];
  const float* e_w2  = (const float*)d_in[10];
  const float* e_b2  = (const float*)d_in[11];
  const float* att_w = (const float*)d_in[12];
  const float* att_b = (const float*)d_in[13];
  const float* c_w1  = (const float*)d_in[14];
  const float* c_b1  = (const float*)d_in[15];
  const float* c_w2  = (const float*)d_in[16];
  const float* c_b2  = (const float*)d_in[17];
  const float* n_w1  = (const float*)d_in[18];
  const float* n_b1  = (const float*)d_in[19];
  const float* n_w2  = (const float*)d_in[20];
  const float* n_b2  = (const float*)d_in[21];
  const float* ln_g  = (const float*)d_in[22];
  const float* ln_b  = (const float*)d_in[23];

  const int N = in_sizes[0] / 128;
  const int E = in_sizes[4];

  char* ws = (char*)d_ws;
  size_t off = 0;
  auto alloc = [&](size_t bytes) {
    size_t o = off;
    off += (bytes + 255) & ~(size_t)255;
    return o;
  };
  size_t off_wzr  = alloc(32768 * sizeof(__hip_bfloat16));
  size_t off_wz1  = alloc(49152 * sizeof(__hip_bfloat16));
  size_t off_wz2  = alloc(16384 * sizeof(__hip_bfloat16));
  size_t off_wzc  = alloc(16384 * sizeof(__hip_bfloat16));
  size_t off_wzn1 = alloc(32768 * sizeof(__hip_bfloat16));
  size_t off_wzn2 = alloc(16384 * sizeof(__hip_bfloat16));
  size_t off_wzc2 = alloc(2048 * sizeof(__hip_bfloat16));
  size_t off_atS  = alloc((size_t)N * 256 * sizeof(__hip_bfloat16));
  size_t off_hb   = alloc((size_t)N * 128 * sizeof(__hip_bfloat16));
  size_t off_px   = alloc((size_t)N * 3 * sizeof(float));
  size_t off_cs   = alloc((size_t)N * sizeof(int));
  size_t off_cntr = alloc((size_t)N * sizeof(unsigned));
  size_t off_cntc = alloc((size_t)N * sizeof(unsigned));
  size_t off_xacc = alloc((size_t)N * 21 * sizeof(__hip_bfloat162));
  size_t off_agg  = alloc((size_t)N * 64 * sizeof(__hip_bfloat162));

  __hip_bfloat16* wz_rad = (__hip_bfloat16*)(ws + off_wzr);
  __hip_bfloat16* wz_e1  = (__hip_bfloat16*)(ws + off_wz1);
  __hip_bfloat16* wz_e2  = (__hip_bfloat16*)(ws + off_wz2);
  __hip_bfloat16* wz_c1  = (__hip_bfloat16*)(ws + off_wzc);
  __hip_bfloat16* wz_n1  = (__hip_bfloat16*)(ws + off_wzn1);
  __hip_bfloat16* wz_n2  = (__hip_bfloat16*)(ws + off_wzn2);
  __hip_bfloat16* wz_c2  = (__hip_bfloat16*)(ws + off_wzc2);
  __hip_bfloat16* attrS  = (__hip_bfloat16*)(ws + off_atS);
  __hip_bfloat16* hb     = (__hip_bfloat16*)(ws + off_hb);
  float* pooled_x   = (float*)(ws + off_px);
  int* chsum        = (int*)(ws + off_cs);
  unsigned* cnt_row = (unsigned*)(ws + off_cntr);
  unsigned* cnt_col = (unsigned*)(ws + off_cntc);
  __hip_bfloat162* x_acc = (__hip_bfloat162*)(ws + off_xacc);
  __hip_bfloat162* agg   = (__hip_bfloat162*)(ws + off_agg);

  (void)hipMemsetAsync(ws + off_cntr, 0, off - off_cntr, stream);

  const int pack_items = 165888 + N * 256 + N * 128 + N;
  k_pack<<<dim3((pack_items + 255) / 256), dim3(256), 0, stream>>>(
      h, x, attr, cw, rad_w, e_w1, e_w2, c_w1, n_w1, n_w2, c_w2,
      wz_rad, wz_e1, wz_e2, wz_c1, wz_n1, wz_n2, wz_c2,
      attrS, hb, pooled_x, chsum, N);
  k_mega<<<dim3((E + TM - 1) / TM), dim3(256), 0, stream>>>(
      hb, x, attrS, row, col, pooled_x, chsum,
      wz_rad, rad_b, wz_e1, e_b1, wz_e2, e_b2, att_w, att_b,
      wz_c1, c_b1, wz_c2, c_b2, cnt_row, cnt_col, x_acc, agg, E);
  k_node<<<dim3((N + TN - 1) / TN), dim3(256), 0, stream>>>(
      h, agg, cnt_col, wz_n1, n_b1, wz_n2, n_b2, ln_g, ln_b,
      x, x_acc, cnt_row, (float*)d_out, (float*)d_out + (size_t)N * 128, N);
}

// Round 8
// 349.442 us; speedup vs baseline: 1.2916x; 1.0014x over previous
//
#include <hip/hip_runtime.h>
#include <hip/hip_bf16.h>

// EnhancedGNNEncoder round 17: k_node -> TN=64 (M=64 structure done right) +
// k_pack vectorized.
//  - k_node: A = [hb | agg/deg] S[0..7]; ef1 -> S[8..11] (paired writes);
//    stage-2 out f32 s_o over S[0..7] with XOR col swizzle s=(e&3)^((e>>2)&3)
//    (kills row-stride-512B bank conflicts); LN = proven 16-lane/node v[8]
//    looped 4x; residual h re-read f32 from L2. 3 barriers / 64 nodes.
//    Weight loads per node /4. 49.2 KB LDS -> 3 blocks/CU.
//  - k_pack: attrS + hb sections write int4 (8 elems/thread) not scalar bf16.
//  - k_mega unchanged from round 16 (218 us).
// MFMA 16x16x32: A[m=lane&15][k=quad*8+j], B[k=quad*8+j][n=lane&15].
// MFMA 16x16x16: A[m=lane&15][k=quad*4+j], B[k=quad*4+j][n=lane&15].
// D (both): col=lane&15, row=quad*4+reg.

#define TM 64
#define TN 64

typedef __attribute__((ext_vector_type(8))) short bf16x8;
typedef __attribute__((ext_vector_type(4))) short bf16x4;
typedef __attribute__((ext_vector_type(4))) float f32x4;

__device__ __forceinline__ float siluf(float v) { return v / (1.f + __expf(-v)); }
__device__ __forceinline__ float sigmf(float v) { return 1.f / (1.f + __expf(-v)); }
__device__ __forceinline__ short f2bs(float f) {
  union { __hip_bfloat16 b; short s; } u;
  u.b = __float2bfloat16(f);
  return u.s;
}
__device__ __forceinline__ __hip_bfloat162 mk_bf162(float v0, float v1) {
  __hip_bfloat162 r;
  r.x = __float2bfloat16(v0);
  r.y = __float2bfloat16(v1);
  return r;
}

// ---- pack: weight swizzle (paired-col) + attrS + h_bf16 + per-node prep ----
__global__ __launch_bounds__(256) void k_pack(
    const float* __restrict__ h, const float* __restrict__ x,
    const float* __restrict__ attr, const float* __restrict__ cw,
    const float* __restrict__ rad_w, const float* __restrict__ e_w1,
    const float* __restrict__ e_w2, const float* __restrict__ c_w1,
    const float* __restrict__ n_w1, const float* __restrict__ n_w2,
    const float* __restrict__ c_w2,
    __hip_bfloat16* __restrict__ wz_rad, __hip_bfloat16* __restrict__ wz_e1,
    __hip_bfloat16* __restrict__ wz_e2, __hip_bfloat16* __restrict__ wz_c1,
    __hip_bfloat16* __restrict__ wz_n1, __hip_bfloat16* __restrict__ wz_n2,
    __hip_bfloat16* __restrict__ wz_c2,
    __hip_bfloat16* __restrict__ attrS, __hip_bfloat16* __restrict__ hb,
    float* __restrict__ pooled_x, int* __restrict__ chsum, int Nn) {
  int idx = blockIdx.x * 256 + threadIdx.x;
  if (idx < 165888) {  // weight swizzle
    int i = idx;
    if (i >= 163840) {  // c_w2: [128][14] -> [4][16][32], n=14,15 zero
      int base = i - 163840;
      int k = base >> 4, n = base & 15;
      wz_c2[(size_t)(k >> 5) * 512 + n * 32 + (k & 31)] =
          (n < 14) ? __float2bfloat16(c_w2[k * 14 + n]) : __float2bfloat16(0.f);
      return;
    }
    const float* W;
    __hip_bfloat16* O;
    int base;
    if (i < 32768) { W = rad_w; O = wz_rad; base = i; }
    else if (i < 81920) { W = e_w1; O = wz_e1; base = i - 32768; }
    else if (i < 98304) { W = e_w2; O = wz_e2; base = i - 81920; }
    else if (i < 114688) { W = c_w1; O = wz_c1; base = i - 98304; }
    else if (i < 147456) { W = n_w1; O = wz_n1; base = i - 114688; }
    else { W = n_w2; O = wz_n2; base = i - 147456; }
    int k = base >> 7, n = base & 127;
    // paired-col storage row: b0 slot (row g*32+mr) holds col g*32+2mr,
    // b1 slot (row g*32+16+mr) holds col g*32+2mr+1
    int nr_ = ((n >> 5) << 5) | ((n & 1) << 4) | ((n & 31) >> 1);
    O[(size_t)((k >> 5) * 128 + nr_) * 32 + (k & 31)] = __float2bfloat16(W[base]);
    return;
  }
  idx -= 165888;
  int na = Nn * 32, nh = Nn * 16;
  if (idx < na) {  // attrS: 8 outputs along channel dim, int4 write
    int n = idx >> 5, r = idx & 31, a = r >> 1, h8 = r & 1;
    __hip_bfloat16 outv[8];
#pragma unroll
    for (int j = 0; j < 8; j++) {
      int i2 = h8 * 8 + j;
      float v = 0.f;
      if (i2 < 14) v = attr[(size_t)n * 224 + i2 * 16 + a] * cw[(size_t)n * 14 + i2];
      outv[j] = __float2bfloat16(v);
    }
    *(int4*)&attrS[(size_t)n * 256 + a * 16 + h8 * 8] = *(int4*)outv;
    return;
  }
  idx -= na;
  if (idx < nh) {  // hb: 8 elems/thread, int4 write
    int n = idx >> 4, q = idx & 15;
    const float4 f0 = *(const float4*)&h[(size_t)n * 128 + q * 8];
    const float4 f1 = *(const float4*)&h[(size_t)n * 128 + q * 8 + 4];
    __hip_bfloat16 outv[8];
    outv[0] = __float2bfloat16(f0.x); outv[1] = __float2bfloat16(f0.y);
    outv[2] = __float2bfloat16(f0.z); outv[3] = __float2bfloat16(f0.w);
    outv[4] = __float2bfloat16(f1.x); outv[5] = __float2bfloat16(f1.y);
    outv[6] = __float2bfloat16(f1.z); outv[7] = __float2bfloat16(f1.w);
    *(int4*)&hb[(size_t)n * 128 + q * 8] = *(int4*)outv;
    return;
  }
  idx -= nh;
  if (idx >= Nn) return;
  int n = idx;
  int cnt = 0;
  float sx = 0.f, sy = 0.f, sz = 0.f;
#pragma unroll
  for (int c = 0; c < 14; c++) {
    float w = cw[n * 14 + c];
    if (w != 0.f) {
      cnt++;
      sx += x[n * 42 + c * 3 + 0];
      sy += x[n * 42 + c * 3 + 1];
      sz += x[n * 42 + c * 3 + 2];
    }
  }
  chsum[n] = cnt;
  float inv = 1.f / (float)(cnt > 0 ? cnt : 1);
  pooled_x[n * 3 + 0] = sx * inv;
  pooled_x[n * 3 + 1] = sy * inv;
  pooled_x[n * 3 + 2] = sz * inv;
}

// ---- k_mega: einsum + rad GEMM + edge MLP + gate + roller + scatters ----
__global__ __launch_bounds__(256, 3) void k_mega(
    const __hip_bfloat16* __restrict__ hb, const float* __restrict__ x,
    const __hip_bfloat16* __restrict__ attrS,
    const int* __restrict__ row, const int* __restrict__ col,
    const float* __restrict__ pooled_x, const int* __restrict__ chsum,
    const __hip_bfloat16* __restrict__ wz_rad, const float* __restrict__ rad_b,
    const __hip_bfloat16* __restrict__ wz_e1, const float* __restrict__ e_b1,
    const __hip_bfloat16* __restrict__ wz_e2, const float* __restrict__ e_b2,
    const float* __restrict__ att_w, const float* __restrict__ att_b,
    const __hip_bfloat16* __restrict__ wz_c1, const float* __restrict__ c_b1,
    const __hip_bfloat16* __restrict__ wz_c2, const float* __restrict__ c_b2,
    unsigned* __restrict__ cnt_row, unsigned* __restrict__ cnt_col,
    __hip_bfloat162* __restrict__ x_acc, __hip_bfloat162* __restrict__ agg,
    int Ee) {
  __shared__ __hip_bfloat16 S[12][TM][32];
  __shared__ float s_att[TM];
  __shared__ float s_red[4][TM];
  __shared__ float s_rn[TM];
  __shared__ int s_row[TM], s_col[TM], s_cs[TM];
  float* s_cm   = (float*)&S[0][0][0];
  float* s_pool = (float*)&S[1][0][0];

  const int t = threadIdx.x;
  const int e0 = blockIdx.x * TM;
  const int ne = min(TM, Ee - e0);
  const int lane = t & 63, wave = t >> 6, quad = lane >> 4, mr = lane & 15;
  const int n0 = wave * 32;
  const f32x4 zacc = {0.f, 0.f, 0.f, 0.f};
  const bf16x4 zero4 = {0, 0, 0, 0};

  // ---- phase 0: edge meta + degree atomics ----
  if (t < TM) {
    int ge = e0 + min(t, ne - 1);
    int r = row[ge], c = col[ge];
    s_row[t] = r;
    s_col[t] = c;
    s_cs[t] = chsum[r];
    if (t < ne) {
      atomicAdd(&cnt_row[r], 1u);
      atomicAdd(&cnt_col[c], 1u);
    }
  }

  // ---- phase 1: einsum via 16x16x16 MFMAs (no transpose shfls) ----
#pragma unroll 1
  for (int b = 0; b < 4; b++) {
    float xr0v[4], xr1v[4], xr2v[4], xc0v[4], xc1v[4], xc2v[4];
    bf16x4 bCv[4], aRv[4];
#pragma unroll
    for (int p = 0; p < 4; p++) {
      const int e = wave * 16 + b * 4 + p;
      const int ge = e0 + min(e, ne - 1);
      const int re = row[ge], ce = col[ge];  // wave-uniform -> scalar loads
      const int mrc = min(mr, 13);
      const float* xp = x + (size_t)re * 42 + mrc * 3;
      xr0v[p] = xp[0]; xr1v[p] = xp[1]; xr2v[p] = xp[2];
      const float* xq = x + (size_t)ce * 42 + mrc * 3;
      xc0v[p] = xq[0]; xc1v[p] = xq[1]; xc2v[p] = xq[2];
      // B-frag (16x16x16): attr[ch=quad*4+j][dim=mr]
      bCv[p] = *(const bf16x4*)&attrS[(size_t)ce * 256 + mr * 16 + quad * 4];
      aRv[p] = *(const bf16x4*)&attrS[(size_t)re * 256 + mr * 16 + quad * 4];
    }
#pragma unroll
    for (int p = 0; p < 4; p++) {
      const int e = wave * 16 + b * 4 + p;
      const float xr0 = xr0v[p], xr1 = xr1v[p], xr2 = xr2v[p];
      const float xc0 = xc0v[p], xc1 = xc1v[p], xc2 = xc2v[p];
      const float nr = xr0 * xr0 + xr1 * xr1 + xr2 * xr2;
      const float nc = xc0 * xc0 + xc1 * xc1 + xc2 * xc2;
      // G[quad*4+r][mr] = xc_{quad*4+r} . xr_{mr}
      bf16x4 aX = zero4, bX = zero4;
      if (quad == 0) {
        aX[0] = f2bs(xc0); aX[1] = f2bs(xc1); aX[2] = f2bs(xc2);
        bX[0] = f2bs(xr0); bX[1] = f2bs(xr1); bX[2] = f2bs(xr2);
      }
      f32x4 G = __builtin_amdgcn_mfma_f32_16x16x16bf16_1k(aX, bX, zacc, 0, 0, 0);
      // dD[r] = ||xr_mr - xc_{quad*4+r}|| -> directly the A-frag of m1
      bf16x4 aM;
#pragma unroll
      for (int r = 0; r < 4; r++) {
        float ncj = __shfl(nc, quad * 4 + r);
        aM[r] = f2bs(sqrtf(fmaxf(ncj + nr - 2.f * G[r], 0.f)));
      }
      f32x4 m1 = __builtin_amdgcn_mfma_f32_16x16x16bf16_1k(aM, bCv[p], zacc, 0, 0, 0);
      // m1 D-layout [c=quad*4+r][b=mr] IS the B-frag of the radial MFMA
      bf16x4 bM;
#pragma unroll
      for (int r = 0; r < 4; r++) bM[r] = f2bs(m1[r]);
      f32x4 rd = __builtin_amdgcn_mfma_f32_16x16x16bf16_1k(aRv[p], bM, zacc, 0, 0, 0);
      float ss = rd[0] * rd[0] + rd[1] * rd[1] + rd[2] * rd[2] + rd[3] * rd[3];
      ss += __shfl_xor(ss, 32); ss += __shfl_xor(ss, 16); ss += __shfl_xor(ss, 8);
      ss += __shfl_xor(ss, 4);  ss += __shfl_xor(ss, 2);  ss += __shfl_xor(ss, 1);
      if (lane == 0) s_rn[e] = sqrtf(ss) + 1.0f;
      // radial[a=quad*4+r][b=mr] -> feature aa*16+mr, natural order, e-swizzled
#pragma unroll
      for (int r = 0; r < 4; r++) {
        const int aa = quad * 4 + r;
        const int c = ((aa & 1) << 4) | mr;
        const int pcol = (((c >> 3) ^ ((e >> 1) & 3)) << 3) | (c & 7);
        S[aa >> 1][e][pcol] = __float2bfloat16(rd[r]);
      }
    }
  }
  __syncthreads();

  const int acol = ((quad ^ ((mr >> 1) & 3)) << 3);  // swizzled frag-read col
  const int m2 = 2 * mr;                             // paired output col base

  // ---- phase 2: rad GEMM radial@rad_w -> radf in S[8..11] (packed writes) ----
  {
    f32x4 a0[4], a1[4];
#pragma unroll
    for (int mf = 0; mf < 4; mf++) { a0[mf] = zacc; a1[mf] = zacc; }
#pragma unroll
    for (int kb = 0; kb < 8; kb++) {
      const __hip_bfloat16* wp = wz_rad + ((size_t)(kb * 128 + n0 + mr) * 32 + quad * 8);
      bf16x8 b0 = *(const bf16x8*)wp;
      bf16x8 b1 = *(const bf16x8*)(wp + 16 * 32);
#pragma unroll
      for (int mf = 0; mf < 4; mf++) {
        bf16x8 a = *(const bf16x8*)&S[kb][mf * 16 + mr][acol];
        a0[mf] = __builtin_amdgcn_mfma_f32_16x16x32_bf16(a, b0, a0[mf], 0, 0, 0);
        a1[mf] = __builtin_amdgcn_mfma_f32_16x16x32_bf16(a, b1, a1[mf], 0, 0, 0);
      }
    }
    const float2 rbp = *(const float2*)&rad_b[n0 + m2];
#pragma unroll
    for (int mf = 0; mf < 4; mf++)
#pragma unroll
      for (int r = 0; r < 4; r++) {
        int e = mf * 16 + quad * 4 + r;
        int pc2 = ((((m2) >> 3) ^ ((e >> 1) & 3)) << 3) | (m2 & 7);
        float inv = 1.f / s_rn[e];
        *(__hip_bfloat162*)&S[8 + wave][e][pc2] =
            mk_bf162((a0[mf][r] + rbp.x) * inv, (a1[mf][r] + rbp.y) * inv);
      }
  }
  __syncthreads();

  // ---- phase 3: stage h_row -> S[0..3], h_col -> S[4..7] ----
  {
    const int m = t >> 2, part = t & 3;
    const int pc = ((part ^ ((m >> 1) & 3)) << 3);
    const __hip_bfloat16* hr = hb + (size_t)s_row[m] * 128 + part * 8;
    const __hip_bfloat16* hc = hb + (size_t)s_col[m] * 128 + part * 8;
#pragma unroll
    for (int kb = 0; kb < 4; kb++) {
      *(int4*)&S[kb][m][pc]     = *(const int4*)&hr[kb * 32];
      *(int4*)&S[4 + kb][m][pc] = *(const int4*)&hc[kb * 32];
    }
  }
  __syncthreads();

  // ---- stage 1: ef1 = silu(A @ e_w1 + e_b1), K=384, M=64 (acc in regs) ----
  f32x4 s1a0[4], s1a1[4];
#pragma unroll
  for (int mf = 0; mf < 4; mf++) { s1a0[mf] = zacc; s1a1[mf] = zacc; }
#pragma unroll
  for (int kb = 0; kb < 12; kb++) {
    const __hip_bfloat16* wp = wz_e1 + ((size_t)(kb * 128 + n0 + mr) * 32 + quad * 8);
    bf16x8 b0 = *(const bf16x8*)wp;
    bf16x8 b1 = *(const bf16x8*)(wp + 16 * 32);
#pragma unroll
    for (int mf = 0; mf < 4; mf++) {
      bf16x8 a = *(const bf16x8*)&S[kb][mf * 16 + mr][acol];
      s1a0[mf] = __builtin_amdgcn_mfma_f32_16x16x32_bf16(a, b0, s1a0[mf], 0, 0, 0);
      s1a1[mf] = __builtin_amdgcn_mfma_f32_16x16x32_bf16(a, b1, s1a1[mf], 0, 0, 0);
    }
  }
  __syncthreads();  // all waves done reading A before ef1 overwrites S[0..3]
  {
    const float2 b1p = *(const float2*)&e_b1[n0 + m2];
#pragma unroll
    for (int mf = 0; mf < 4; mf++)
#pragma unroll
      for (int r = 0; r < 4; r++) {
        int e = mf * 16 + quad * 4 + r;
        int pc2 = (((m2 >> 3) ^ ((e >> 1) & 3)) << 3) | (m2 & 7);
        *(__hip_bfloat162*)&S[wave][e][pc2] =
            mk_bf162(siluf(s1a0[mf][r] + b1p.x), siluf(s1a1[mf][r] + b1p.y));
      }
  }
  __syncthreads();

  // ---- stage 2: ef2 = silu(ef1 @ e_w2 + e_b2) -> S[4..7]; gate partials ----
  const float2 awp = *(const float2*)&att_w[n0 + m2];
  {
    f32x4 a0[4], a1[4];
#pragma unroll
    for (int mf = 0; mf < 4; mf++) { a0[mf] = zacc; a1[mf] = zacc; }
#pragma unroll
    for (int kb = 0; kb < 4; kb++) {
      const __hip_bfloat16* wp = wz_e2 + ((size_t)(kb * 128 + n0 + mr) * 32 + quad * 8);
      bf16x8 b0 = *(const bf16x8*)wp;
      bf16x8 b1 = *(const bf16x8*)(wp + 16 * 32);
#pragma unroll
      for (int mf = 0; mf < 4; mf++) {
        bf16x8 a = *(const bf16x8*)&S[kb][mf * 16 + mr][acol];
        a0[mf] = __builtin_amdgcn_mfma_f32_16x16x32_bf16(a, b0, a0[mf], 0, 0, 0);
        a1[mf] = __builtin_amdgcn_mfma_f32_16x16x32_bf16(a, b1, a1[mf], 0, 0, 0);
      }
    }
    const float2 b2p = *(const float2*)&e_b2[n0 + m2];
    float part[4][4];
#pragma unroll
    for (int mf = 0; mf < 4; mf++)
#pragma unroll
      for (int r = 0; r < 4; r++) {
        int e = mf * 16 + quad * 4 + r;
        int pc2 = (((m2 >> 3) ^ ((e >> 1) & 3)) << 3) | (m2 & 7);
        float v0 = siluf(a0[mf][r] + b2p.x);
        float v1 = siluf(a1[mf][r] + b2p.y);
        *(__hip_bfloat162*)&S[4 + wave][e][pc2] = mk_bf162(v0, v1);
        part[mf][r] = v0 * awp.x + v1 * awp.y;
      }
#pragma unroll
    for (int msk = 1; msk < 16; msk <<= 1)
#pragma unroll
      for (int mf = 0; mf < 4; mf++)
#pragma unroll
        for (int r = 0; r < 4; r++) part[mf][r] += __shfl_xor(part[mf][r], msk);
    if (mr == 0) {
#pragma unroll
      for (int mf = 0; mf < 4; mf++)
#pragma unroll
        for (int r = 0; r < 4; r++)
          s_red[wave][mf * 16 + quad * 4 + r] = part[mf][r];
    }
  }
  __syncthreads();
  if (t < TM) {
    float s = s_red[0][t] + s_red[1][t] + s_red[2][t] + s_red[3][t];
    s_att[t] = sigmf(s + att_b[0]);
  }
  __syncthreads();

  // ---- stage 3: cmh = silu(att*(ef2 @ c_w1) + c_b1) -> S[8..11] ----
  {
    f32x4 a0[4], a1[4];
#pragma unroll
    for (int mf = 0; mf < 4; mf++) { a0[mf] = zacc; a1[mf] = zacc; }
#pragma unroll
    for (int kb = 0; kb < 4; kb++) {
      const __hip_bfloat16* wp = wz_c1 + ((size_t)(kb * 128 + n0 + mr) * 32 + quad * 8);
      bf16x8 b0 = *(const bf16x8*)wp;
      bf16x8 b1 = *(const bf16x8*)(wp + 16 * 32);
#pragma unroll
      for (int mf = 0; mf < 4; mf++) {
        bf16x8 a = *(const bf16x8*)&S[4 + kb][mf * 16 + mr][acol];
        a0[mf] = __builtin_amdgcn_mfma_f32_16x16x32_bf16(a, b0, a0[mf], 0, 0, 0);
        a1[mf] = __builtin_amdgcn_mfma_f32_16x16x32_bf16(a, b1, a1[mf], 0, 0, 0);
      }
    }
    const float2 cbp = *(const float2*)&c_b1[n0 + m2];
#pragma unroll
    for (int mf = 0; mf < 4; mf++)
#pragma unroll
      for (int r = 0; r < 4; r++) {
        int e = mf * 16 + quad * 4 + r;
        int pc2 = (((m2 >> 3) ^ ((e >> 1) & 3)) << 3) | (m2 & 7);
        float av = s_att[e];
        *(__hip_bfloat162*)&S[8 + wave][e][pc2] =
            mk_bf162(siluf(av * a0[mf][r] + cbp.x), siluf(av * a1[mf][r] + cbp.y));
      }
  }
  __syncthreads();

  // ---- cm = cmh @ c_w2 + c_b2 (each wave one 16-row tile) -> s_cm (S[0]) ----
  {
    f32x4 acc = zacc;
#pragma unroll
    for (int kb = 0; kb < 4; kb++) {
      bf16x8 a = *(const bf16x8*)&S[8 + kb][wave * 16 + mr][acol];
      bf16x8 b = *(const bf16x8*)(wz_c2 + ((size_t)(kb * 16 + mr) * 32 + quad * 8));
      acc = __builtin_amdgcn_mfma_f32_16x16x32_bf16(a, b, acc, 0, 0, 0);
    }
    if (mr < 14) {
      float bias = c_b2[mr];
#pragma unroll
      for (int r = 0; r < 4; r++)
        s_cm[(wave * 16 + quad * 4 + r) * 14 + mr] = acc[r] + bias;
    }
  }
  __syncthreads();

  // ---- RollerPooling ----
  for (int i = t; i < TM * 14; i += 256) {
    int e = i / 14, c = i % 14;
    int wsz = 15 - s_cs[e];
    int hi = min(c + wsz, 14);
    float s = 0.f;
    for (int j = c; j < hi; j++) s += s_cm[e * 14 + j];
    s_pool[e * 14 + c] = s / (float)wsz;
  }
  __syncthreads();

  // ---- trans scatter (x re-gathered from L2; packed bf16 atomics) ----
  for (int i = t; i < TM * 21; i += 256) {
    int e = i / 21, pr = i % 21;
    if (e < ne) {
      int r0 = pr * 2, r1 = r0 + 1;
      const float* xp = x + (size_t)s_row[e] * 42;
      const float* pc = pooled_x + (size_t)s_col[e] * 3;
      float v0 = (xp[r0] - pc[r0 % 3]) * s_pool[e * 14 + r0 / 3];
      float v1 = (xp[r1] - pc[r1 % 3]) * s_pool[e * 14 + r1 / 3];
      unsafeAtomicAdd(&x_acc[(size_t)s_row[e] * 21 + pr], mk_bf162(v0, v1));
    }
  }
  // ---- agg scatter (gated ef2 from S[4..7], swizzled reads) ----
  for (int i = t; i < TM * 64; i += 256) {
    int e = i >> 6, o2 = i & 63;
    if (e < ne) {
      float av = s_att[e];
      int c = (o2 & 15) * 2;
      int pc = (((c >> 3) ^ ((e >> 1) & 3)) << 3) | (c & 7);
      const __hip_bfloat16* wp2 = &S[4 + (o2 >> 4)][e][pc];
      float v0 = __bfloat162float(wp2[0]) * av;
      float v1 = __bfloat162float(wp2[1]) * av;
      unsafeAtomicAdd(&agg[(size_t)s_col[e] * 64 + o2], mk_bf162(v0, v1));
    }
  }
}

// ---- k_node: TN=64 node MLP (M=64) + residual + 16-lane LN x4 + x_new ----
__global__ __launch_bounds__(256, 3) void k_node(
    const float* __restrict__ h, const __hip_bfloat16* __restrict__ hb,
    const __hip_bfloat162* __restrict__ agg,
    const unsigned* __restrict__ cnt_col,
    const __hip_bfloat16* __restrict__ wz_n1, const float* __restrict__ n_b1,
    const __hip_bfloat16* __restrict__ wz_n2, const float* __restrict__ n_b2,
    const float* __restrict__ ln_g, const float* __restrict__ ln_b,
    const float* __restrict__ x, const __hip_bfloat162* __restrict__ x_acc,
    const unsigned* __restrict__ cnt_row,
    float* __restrict__ out_h, float* __restrict__ out_x, int Nn) {
  __shared__ __hip_bfloat16 S[12][TN][32];
  float* s_o = (float*)&S[0][0][0];  // [64][128] f32 over S[0..7], col-swizzled

  const int t = threadIdx.x;
  const int nb0 = blockIdx.x * TN;
  const int nn = min(TN, Nn - nb0);
  const int lane = t & 63, wave = t >> 6, quad = lane >> 4, mr = lane & 15;
  const int n0 = wave * 32;
  const int m2 = 2 * mr;
  const f32x4 zacc = {0.f, 0.f, 0.f, 0.f};

  // fused x_new
  for (int i = t; i < TN * 21; i += 256) {
    int n = i / 21, pr = i % 21;
    if (n < nn) {
      int gn = nb0 + n;
      unsigned c = cnt_row[gn];
      float inv = 1.f / (float)(c > 0 ? c : 1);
      float2 xa = __bfloat1622float2(x_acc[(size_t)gn * 21 + pr]);
      size_t gi = (size_t)gn * 42 + pr * 2;
      out_x[gi]     = x[gi] + xa.x * inv;
      out_x[gi + 1] = x[gi + 1] + xa.y * inv;
    }
  }

  // ---- A staging: hb -> S[0..3], agg/deg -> S[4..7] (swizzled cols) ----
  {
    const int m = t >> 2, part = t & 3;
    const int gn = nb0 + min(m, nn - 1);
    const int pc = ((part ^ ((m >> 1) & 3)) << 3);
    const __hip_bfloat16* hr = hb + (size_t)gn * 128 + part * 8;
    unsigned c = cnt_col[gn];
    float inv = 1.f / (float)(c > 0 ? c : 1);
    const __hip_bfloat162* ag = agg + (size_t)gn * 64 + part * 4;
#pragma unroll
    for (int kb = 0; kb < 4; kb++) {
      *(int4*)&S[kb][m][pc] = *(const int4*)&hr[kb * 32];
      float2 f0 = __bfloat1622float2(ag[kb * 16 + 0]);
      float2 f1 = __bfloat1622float2(ag[kb * 16 + 1]);
      float2 f2 = __bfloat1622float2(ag[kb * 16 + 2]);
      float2 f3 = __bfloat1622float2(ag[kb * 16 + 3]);
      __hip_bfloat162 pk[4];
      pk[0] = mk_bf162(f0.x * inv, f0.y * inv);
      pk[1] = mk_bf162(f1.x * inv, f1.y * inv);
      pk[2] = mk_bf162(f2.x * inv, f2.y * inv);
      pk[3] = mk_bf162(f3.x * inv, f3.y * inv);
      *(int4*)&S[4 + kb][m][pc] = *(int4*)pk;
    }
  }
  __syncthreads();

  const int acol = ((quad ^ ((mr >> 1) & 3)) << 3);  // swizzled frag-read col

  // ---- stage 1: ef1 = silu(A @ n_w1 + n_b1), K=256, M=64 -> S[8..11] ----
  {
    f32x4 a0[4], a1[4];
#pragma unroll
    for (int mf = 0; mf < 4; mf++) { a0[mf] = zacc; a1[mf] = zacc; }
#pragma unroll
    for (int kb = 0; kb < 8; kb++) {
      const __hip_bfloat16* wp = wz_n1 + ((size_t)(kb * 128 + n0 + mr) * 32 + quad * 8);
      bf16x8 b0 = *(const bf16x8*)wp;
      bf16x8 b1 = *(const bf16x8*)(wp + 16 * 32);
#pragma unroll
      for (int mf = 0; mf < 4; mf++) {
        bf16x8 a = *(const bf16x8*)&S[kb][mf * 16 + mr][acol];
        a0[mf] = __builtin_amdgcn_mfma_f32_16x16x32_bf16(a, b0, a0[mf], 0, 0, 0);
        a1[mf] = __builtin_amdgcn_mfma_f32_16x16x32_bf16(a, b1, a1[mf], 0, 0, 0);
      }
    }
    // writes go to S[8..11] (disjoint from A reads) -> no barrier needed here
    const float2 b1p = *(const float2*)&n_b1[n0 + m2];
#pragma unroll
    for (int mf = 0; mf < 4; mf++)
#pragma unroll
      for (int r = 0; r < 4; r++) {
        int e = mf * 16 + quad * 4 + r;
        int pc2 = (((m2 >> 3) ^ ((e >> 1) & 3)) << 3) | (m2 & 7);
        *(__hip_bfloat162*)&S[8 + wave][e][pc2] =
            mk_bf162(siluf(a0[mf][r] + b1p.x), siluf(a1[mf][r] + b1p.y));
      }
  }
  __syncthreads();

  // ---- stage 2: nh = ef1 @ n_w2 + n_b2 -> s_o f32 (S[0..7], col-swizzled) ----
  {
    f32x4 a0[4], a1[4];
#pragma unroll
    for (int mf = 0; mf < 4; mf++) { a0[mf] = zacc; a1[mf] = zacc; }
#pragma unroll
    for (int kb = 0; kb < 4; kb++) {
      const __hip_bfloat16* wp = wz_n2 + ((size_t)(kb * 128 + n0 + mr) * 32 + quad * 8);
      bf16x8 b0 = *(const bf16x8*)wp;
      bf16x8 b1 = *(const bf16x8*)(wp + 16 * 32);
#pragma unroll
      for (int mf = 0; mf < 4; mf++) {
        bf16x8 a = *(const bf16x8*)&S[8 + kb][mf * 16 + mr][acol];
        a0[mf] = __builtin_amdgcn_mfma_f32_16x16x32_bf16(a, b0, a0[mf], 0, 0, 0);
        a1[mf] = __builtin_amdgcn_mfma_f32_16x16x32_bf16(a, b1, a1[mf], 0, 0, 0);
      }
    }
    const float2 b2p = *(const float2*)&n_b2[n0 + m2];
#pragma unroll
    for (int mf = 0; mf < 4; mf++)
#pragma unroll
      for (int r = 0; r < 4; r++) {
        int e = mf * 16 + quad * 4 + r;
        int s = (e & 3) ^ ((e >> 2) & 3);
        int colp = (n0 + m2) ^ (s << 3);
        *(float2*)&s_o[e * 128 + colp] =
            make_float2(a0[mf][r] + b2p.x, a1[mf][r] + b2p.y);
      }
  }
  __syncthreads();

  // ---- LayerNorm: 16 lanes/node (v[8]), looped over 4 groups of 16 nodes ----
#pragma unroll 1
  for (int g = 0; g < 4; g++) {
    int n = g * 16 + (t >> 4), p = t & 15;
    int gn = nb0 + min(n, nn - 1);
    int sw = (n & 3) ^ ((n >> 2) & 3);
    const float* op = s_o + n * 128 + ((p ^ sw) << 3);
    const float* hp = h + (size_t)gn * 128 + p * 8;
    float v[8];
    float s = 0.f;
#pragma unroll
    for (int j = 0; j < 8; j++) {
      v[j] = op[j] + hp[j];
      s += v[j];
    }
    s += __shfl_xor(s, 1); s += __shfl_xor(s, 2);
    s += __shfl_xor(s, 4); s += __shfl_xor(s, 8);
    float mu = s * (1.f / 128.f);
    float var = 0.f;
#pragma unroll
    for (int j = 0; j < 8; j++) {
      float d = v[j] - mu;
      var += d * d;
    }
    var += __shfl_xor(var, 1); var += __shfl_xor(var, 2);
    var += __shfl_xor(var, 4); var += __shfl_xor(var, 8);
    float rs = rsqrtf(var * (1.f / 128.f) + 1e-5f);
    if (n < nn) {
      size_t base = (size_t)gn * 128 + p * 8;
#pragma unroll
      for (int j = 0; j < 8; j++)
        out_h[base + j] = (v[j] - mu) * rs * ln_g[p * 8 + j] + ln_b[p * 8 + j];
    }
  }
}

extern "C" void kernel_launch(void* const* d_in, const int* in_sizes, int n_in,
                              void* d_out, int out_size, void* d_ws, size_t ws_size,
                              hipStream_t stream) {
  const float* h     = (const float*)d_in[0];
  const float* x     = (const float*)d_in[1];
  const float* attr  = (const float*)d_in[2];
  const float* cw    = (const float*)d_in[3];
  const int*   row   = (const int*)d_in[4];
  const int*   col   = (const int*)d_in[5];
  const float* rad_w = (const float*)d_in[6];
  const float* rad_b = (const float*)d_in[7];
  const float* e_w1  = (const float*)d_in[8];
  const float* e_b1  = (const float*)d_in[9];
  const float* e_w2  = (const float*)d_in[10];
  const float* e_b2  = (const float*)d_in[11];
  const float* att_w = (const float*)d_in[12];
  const float* att_b = (const float*)d_in[13];
  const float* c_w1  = (const float*)d_in[14];
  const float* c_b1  = (const float*)d_in[15];
  const float* c_w2  = (const float*)d_in[16];
  const float* c_b2  = (const float*)d_in[17];
  const float* n_w1  = (const float*)d_in[18];
  const float* n_b1  = (const float*)d_in[19];
  const float* n_w2  = (const float*)d_in[20];
  const float* n_b2  = (const float*)d_in[21];
  const float* ln_g  = (const float*)d_in[22];
  const float* ln_b  = (const float*)d_in[23];

  const int N = in_sizes[0] / 128;
  const int E = in_sizes[4];

  char* ws = (char*)d_ws;
  size_t off = 0;
  auto alloc = [&](size_t bytes) {
    size_t o = off;
    off += (bytes + 255) & ~(size_t)255;
    return o;
  };
  size_t off_wzr  = alloc(32768 * sizeof(__hip_bfloat16));
  size_t off_wz1  = alloc(49152 * sizeof(__hip_bfloat16));
  size_t off_wz2  = alloc(16384 * sizeof(__hip_bfloat16));
  size_t off_wzc  = alloc(16384 * sizeof(__hip_bfloat16));
  size_t off_wzn1 = alloc(32768 * sizeof(__hip_bfloat16));
  size_t off_wzn2 = alloc(16384 * sizeof(__hip_bfloat16));
  size_t off_wzc2 = alloc(2048 * sizeof(__hip_bfloat16));
  size_t off_atS  = alloc((size_t)N * 256 * sizeof(__hip_bfloat16));
  size_t off_hb   = alloc((size_t)N * 128 * sizeof(__hip_bfloat16));
  size_t off_px   = alloc((size_t)N * 3 * sizeof(float));
  size_t off_cs   = alloc((size_t)N * sizeof(int));
  size_t off_cntr = alloc((size_t)N * sizeof(unsigned));
  size_t off_cntc = alloc((size_t)N * sizeof(unsigned));
  size_t off_xacc = alloc((size_t)N * 21 * sizeof(__hip_bfloat162));
  size_t off_agg  = alloc((size_t)N * 64 * sizeof(__hip_bfloat162));

  __hip_bfloat16* wz_rad = (__hip_bfloat16*)(ws + off_wzr);
  __hip_bfloat16* wz_e1  = (__hip_bfloat16*)(ws + off_wz1);
  __hip_bfloat16* wz_e2  = (__hip_bfloat16*)(ws + off_wz2);
  __hip_bfloat16* wz_c1  = (__hip_bfloat16*)(ws + off_wzc);
  __hip_bfloat16* wz_n1  = (__hip_bfloat16*)(ws + off_wzn1);
  __hip_bfloat16* wz_n2  = (__hip_bfloat16*)(ws + off_wzn2);
  __hip_bfloat16* wz_c2  = (__hip_bfloat16*)(ws + off_wzc2);
  __hip_bfloat16* attrS  = (__hip_bfloat16*)(ws + off_atS);
  __hip_bfloat16* hb     = (__hip_bfloat16*)(ws + off_hb);
  float* pooled_x   = (float*)(ws + off_px);
  int* chsum        = (int*)(ws + off_cs);
  unsigned* cnt_row = (unsigned*)(ws + off_cntr);
  unsigned* cnt_col = (unsigned*)(ws + off_cntc);
  __hip_bfloat162* x_acc = (__hip_bfloat162*)(ws + off_xacc);
  __hip_bfloat162* agg   = (__hip_bfloat162*)(ws + off_agg);

  (void)hipMemsetAsync(ws + off_cntr, 0, off - off_cntr, stream);

  const int pack_items = 165888 + N * 32 + N * 16 + N;
  k_pack<<<dim3((pack_items + 255) / 256), dim3(256), 0, stream>>>(
      h, x, attr, cw, rad_w, e_w1, e_w2, c_w1, n_w1, n_w2, c_w2,
      wz_rad, wz_e1, wz_e2, wz_c1, wz_n1, wz_n2, wz_c2,
      attrS, hb, pooled_x, chsum, N);
  k_mega<<<dim3((E + TM - 1) / TM), dim3(256), 0, stream>>>(
      hb, x, attrS, row, col, pooled_x, chsum,
      wz_rad, rad_b, wz_e1, e_b1, wz_e2, e_b2, att_w, att_b,
      wz_c1, c_b1, wz_c2, c_b2, cnt_row, cnt_col, x_acc, agg, E);
  k_node<<<dim3((N + TN - 1) / TN), dim3(256), 0, stream>>>(
      h, hb, agg, cnt_col, wz_n1, n_b1, wz_n2, n_b2, ln_g, ln_b,
      x, x_acc, cnt_row, (float*)d_out, (float*)d_out + (size_t)N * 128, N);
}

// Round 9
// 329.749 us; speedup vs baseline: 1.3687x; 1.0597x over previous
//
#include <hip/hip_runtime.h>
#include <hip/hip_bf16.h>

// EnhancedGNNEncoder round 18: k_mega TM 64->48 for 4 blocks/CU.
//  - LDS 51.7 -> 38.6 KB (12 slots x 48 x 32 x 2B + extras) -> 4 blocks/CU,
//    16 waves/CU (was 12). __launch_bounds__(256,4). MF=3 M-fragments; einsum
//    12 edges/wave (3 batches); c2 stage on waves 0..2.
//  - Cost: weight re-load per edge x4/3 (HBM at 13%, cheap), grid 3125->4167.
//  - k_pack / k_node unchanged from round 17.
// MFMA 16x16x32: A[m=lane&15][k=quad*8+j], B[k=quad*8+j][n=lane&15].
// MFMA 16x16x16: A[m=lane&15][k=quad*4+j], B[k=quad*4+j][n=lane&15].
// D (both): col=lane&15, row=quad*4+reg.

#define TM 48
#define MF 3
#define TN 64

typedef __attribute__((ext_vector_type(8))) short bf16x8;
typedef __attribute__((ext_vector_type(4))) short bf16x4;
typedef __attribute__((ext_vector_type(4))) float f32x4;

__device__ __forceinline__ float siluf(float v) { return v / (1.f + __expf(-v)); }
__device__ __forceinline__ float sigmf(float v) { return 1.f / (1.f + __expf(-v)); }
__device__ __forceinline__ short f2bs(float f) {
  union { __hip_bfloat16 b; short s; } u;
  u.b = __float2bfloat16(f);
  return u.s;
}
__device__ __forceinline__ __hip_bfloat162 mk_bf162(float v0, float v1) {
  __hip_bfloat162 r;
  r.x = __float2bfloat16(v0);
  r.y = __float2bfloat16(v1);
  return r;
}

// ---- pack: weight swizzle (paired-col) + attrS + h_bf16 + per-node prep ----
__global__ __launch_bounds__(256) void k_pack(
    const float* __restrict__ h, const float* __restrict__ x,
    const float* __restrict__ attr, const float* __restrict__ cw,
    const float* __restrict__ rad_w, const float* __restrict__ e_w1,
    const float* __restrict__ e_w2, const float* __restrict__ c_w1,
    const float* __restrict__ n_w1, const float* __restrict__ n_w2,
    const float* __restrict__ c_w2,
    __hip_bfloat16* __restrict__ wz_rad, __hip_bfloat16* __restrict__ wz_e1,
    __hip_bfloat16* __restrict__ wz_e2, __hip_bfloat16* __restrict__ wz_c1,
    __hip_bfloat16* __restrict__ wz_n1, __hip_bfloat16* __restrict__ wz_n2,
    __hip_bfloat16* __restrict__ wz_c2,
    __hip_bfloat16* __restrict__ attrS, __hip_bfloat16* __restrict__ hb,
    float* __restrict__ pooled_x, int* __restrict__ chsum, int Nn) {
  int idx = blockIdx.x * 256 + threadIdx.x;
  if (idx < 165888) {  // weight swizzle
    int i = idx;
    if (i >= 163840) {  // c_w2: [128][14] -> [4][16][32], n=14,15 zero
      int base = i - 163840;
      int k = base >> 4, n = base & 15;
      wz_c2[(size_t)(k >> 5) * 512 + n * 32 + (k & 31)] =
          (n < 14) ? __float2bfloat16(c_w2[k * 14 + n]) : __float2bfloat16(0.f);
      return;
    }
    const float* W;
    __hip_bfloat16* O;
    int base;
    if (i < 32768) { W = rad_w; O = wz_rad; base = i; }
    else if (i < 81920) { W = e_w1; O = wz_e1; base = i - 32768; }
    else if (i < 98304) { W = e_w2; O = wz_e2; base = i - 81920; }
    else if (i < 114688) { W = c_w1; O = wz_c1; base = i - 98304; }
    else if (i < 147456) { W = n_w1; O = wz_n1; base = i - 114688; }
    else { W = n_w2; O = wz_n2; base = i - 147456; }
    int k = base >> 7, n = base & 127;
    // paired-col storage row: b0 slot (row g*32+mr) holds col g*32+2mr,
    // b1 slot (row g*32+16+mr) holds col g*32+2mr+1
    int nr_ = ((n >> 5) << 5) | ((n & 1) << 4) | ((n & 31) >> 1);
    O[(size_t)((k >> 5) * 128 + nr_) * 32 + (k & 31)] = __float2bfloat16(W[base]);
    return;
  }
  idx -= 165888;
  int na = Nn * 32, nh = Nn * 16;
  if (idx < na) {  // attrS: 8 outputs along channel dim, int4 write
    int n = idx >> 5, r = idx & 31, a = r >> 1, h8 = r & 1;
    __hip_bfloat16 outv[8];
#pragma unroll
    for (int j = 0; j < 8; j++) {
      int i2 = h8 * 8 + j;
      float v = 0.f;
      if (i2 < 14) v = attr[(size_t)n * 224 + i2 * 16 + a] * cw[(size_t)n * 14 + i2];
      outv[j] = __float2bfloat16(v);
    }
    *(int4*)&attrS[(size_t)n * 256 + a * 16 + h8 * 8] = *(int4*)outv;
    return;
  }
  idx -= na;
  if (idx < nh) {  // hb: 8 elems/thread, int4 write
    int n = idx >> 4, q = idx & 15;
    const float4 f0 = *(const float4*)&h[(size_t)n * 128 + q * 8];
    const float4 f1 = *(const float4*)&h[(size_t)n * 128 + q * 8 + 4];
    __hip_bfloat16 outv[8];
    outv[0] = __float2bfloat16(f0.x); outv[1] = __float2bfloat16(f0.y);
    outv[2] = __float2bfloat16(f0.z); outv[3] = __float2bfloat16(f0.w);
    outv[4] = __float2bfloat16(f1.x); outv[5] = __float2bfloat16(f1.y);
    outv[6] = __float2bfloat16(f1.z); outv[7] = __float2bfloat16(f1.w);
    *(int4*)&hb[(size_t)n * 128 + q * 8] = *(int4*)outv;
    return;
  }
  idx -= nh;
  if (idx >= Nn) return;
  int n = idx;
  int cnt = 0;
  float sx = 0.f, sy = 0.f, sz = 0.f;
#pragma unroll
  for (int c = 0; c < 14; c++) {
    float w = cw[n * 14 + c];
    if (w != 0.f) {
      cnt++;
      sx += x[n * 42 + c * 3 + 0];
      sy += x[n * 42 + c * 3 + 1];
      sz += x[n * 42 + c * 3 + 2];
    }
  }
  chsum[n] = cnt;
  float inv = 1.f / (float)(cnt > 0 ? cnt : 1);
  pooled_x[n * 3 + 0] = sx * inv;
  pooled_x[n * 3 + 1] = sy * inv;
  pooled_x[n * 3 + 2] = sz * inv;
}

// ---- k_mega: einsum + rad GEMM + edge MLP + gate + roller + scatters ----
// TM=48, 12 slots x [48][32] = 36.9 KB -> 4 blocks/CU.
__global__ __launch_bounds__(256, 4) void k_mega(
    const __hip_bfloat16* __restrict__ hb, const float* __restrict__ x,
    const __hip_bfloat16* __restrict__ attrS,
    const int* __restrict__ row, const int* __restrict__ col,
    const float* __restrict__ pooled_x, const int* __restrict__ chsum,
    const __hip_bfloat16* __restrict__ wz_rad, const float* __restrict__ rad_b,
    const __hip_bfloat16* __restrict__ wz_e1, const float* __restrict__ e_b1,
    const __hip_bfloat16* __restrict__ wz_e2, const float* __restrict__ e_b2,
    const float* __restrict__ att_w, const float* __restrict__ att_b,
    const __hip_bfloat16* __restrict__ wz_c1, const float* __restrict__ c_b1,
    const __hip_bfloat16* __restrict__ wz_c2, const float* __restrict__ c_b2,
    unsigned* __restrict__ cnt_row, unsigned* __restrict__ cnt_col,
    __hip_bfloat162* __restrict__ x_acc, __hip_bfloat162* __restrict__ agg,
    int Ee) {
  __shared__ __hip_bfloat16 S[12][TM][32];
  __shared__ float s_att[TM];
  __shared__ float s_red[4][TM];
  __shared__ float s_rn[TM];
  __shared__ int s_row[TM], s_col[TM], s_cs[TM];
  float* s_cm   = (float*)&S[0][0][0];  // [48*14] f32 = 2688 B (slot 0)
  float* s_pool = (float*)&S[1][0][0];

  const int t = threadIdx.x;
  const int e0 = blockIdx.x * TM;
  const int ne = min(TM, Ee - e0);
  const int lane = t & 63, wave = t >> 6, quad = lane >> 4, mr = lane & 15;
  const int n0 = wave * 32;
  const f32x4 zacc = {0.f, 0.f, 0.f, 0.f};
  const bf16x4 zero4 = {0, 0, 0, 0};

  // ---- phase 0: edge meta + degree atomics ----
  if (t < TM) {
    int ge = e0 + min(t, ne - 1);
    int r = row[ge], c = col[ge];
    s_row[t] = r;
    s_col[t] = c;
    s_cs[t] = chsum[r];
    if (t < ne) {
      atomicAdd(&cnt_row[r], 1u);
      atomicAdd(&cnt_col[c], 1u);
    }
  }

  // ---- phase 1: einsum via 16x16x16 MFMAs, 12 edges/wave in 3 batches ----
#pragma unroll 1
  for (int b = 0; b < MF; b++) {
    float xr0v[4], xr1v[4], xr2v[4], xc0v[4], xc1v[4], xc2v[4];
    bf16x4 bCv[4], aRv[4];
#pragma unroll
    for (int p = 0; p < 4; p++) {
      const int e = wave * (MF * 4) + b * 4 + p;
      const int ge = e0 + min(e, ne - 1);
      const int re = row[ge], ce = col[ge];  // wave-uniform -> scalar loads
      const int mrc = min(mr, 13);
      const float* xp = x + (size_t)re * 42 + mrc * 3;
      xr0v[p] = xp[0]; xr1v[p] = xp[1]; xr2v[p] = xp[2];
      const float* xq = x + (size_t)ce * 42 + mrc * 3;
      xc0v[p] = xq[0]; xc1v[p] = xq[1]; xc2v[p] = xq[2];
      // B-frag (16x16x16): attr[ch=quad*4+j][dim=mr]
      bCv[p] = *(const bf16x4*)&attrS[(size_t)ce * 256 + mr * 16 + quad * 4];
      aRv[p] = *(const bf16x4*)&attrS[(size_t)re * 256 + mr * 16 + quad * 4];
    }
#pragma unroll
    for (int p = 0; p < 4; p++) {
      const int e = wave * (MF * 4) + b * 4 + p;
      const float xr0 = xr0v[p], xr1 = xr1v[p], xr2 = xr2v[p];
      const float xc0 = xc0v[p], xc1 = xc1v[p], xc2 = xc2v[p];
      const float nr = xr0 * xr0 + xr1 * xr1 + xr2 * xr2;
      const float nc = xc0 * xc0 + xc1 * xc1 + xc2 * xc2;
      // G[quad*4+r][mr] = xc_{quad*4+r} . xr_{mr}
      bf16x4 aX = zero4, bX = zero4;
      if (quad == 0) {
        aX[0] = f2bs(xc0); aX[1] = f2bs(xc1); aX[2] = f2bs(xc2);
        bX[0] = f2bs(xr0); bX[1] = f2bs(xr1); bX[2] = f2bs(xr2);
      }
      f32x4 G = __builtin_amdgcn_mfma_f32_16x16x16bf16_1k(aX, bX, zacc, 0, 0, 0);
      // dD[r] = ||xr_mr - xc_{quad*4+r}|| -> directly the A-frag of m1
      bf16x4 aM;
#pragma unroll
      for (int r = 0; r < 4; r++) {
        float ncj = __shfl(nc, quad * 4 + r);
        aM[r] = f2bs(sqrtf(fmaxf(ncj + nr - 2.f * G[r], 0.f)));
      }
      f32x4 m1 = __builtin_amdgcn_mfma_f32_16x16x16bf16_1k(aM, bCv[p], zacc, 0, 0, 0);
      // m1 D-layout [c=quad*4+r][b=mr] IS the B-frag of the radial MFMA
      bf16x4 bM;
#pragma unroll
      for (int r = 0; r < 4; r++) bM[r] = f2bs(m1[r]);
      f32x4 rd = __builtin_amdgcn_mfma_f32_16x16x16bf16_1k(aRv[p], bM, zacc, 0, 0, 0);
      float ss = rd[0] * rd[0] + rd[1] * rd[1] + rd[2] * rd[2] + rd[3] * rd[3];
      ss += __shfl_xor(ss, 32); ss += __shfl_xor(ss, 16); ss += __shfl_xor(ss, 8);
      ss += __shfl_xor(ss, 4);  ss += __shfl_xor(ss, 2);  ss += __shfl_xor(ss, 1);
      if (lane == 0) s_rn[e] = sqrtf(ss) + 1.0f;
      // radial[a=quad*4+r][b=mr] -> feature aa*16+mr, natural order, e-swizzled
#pragma unroll
      for (int r = 0; r < 4; r++) {
        const int aa = quad * 4 + r;
        const int c = ((aa & 1) << 4) | mr;
        const int pcol = (((c >> 3) ^ ((e >> 1) & 3)) << 3) | (c & 7);
        S[aa >> 1][e][pcol] = __float2bfloat16(rd[r]);
      }
    }
  }
  __syncthreads();

  const int acol = ((quad ^ ((mr >> 1) & 3)) << 3);  // swizzled frag-read col
  const int m2 = 2 * mr;                             // paired output col base

  // ---- phase 2: rad GEMM radial@rad_w -> radf in S[8..11] (packed writes) ----
  {
    f32x4 a0[MF], a1[MF];
#pragma unroll
    for (int mf = 0; mf < MF; mf++) { a0[mf] = zacc; a1[mf] = zacc; }
#pragma unroll
    for (int kb = 0; kb < 8; kb++) {
      const __hip_bfloat16* wp = wz_rad + ((size_t)(kb * 128 + n0 + mr) * 32 + quad * 8);
      bf16x8 b0 = *(const bf16x8*)wp;
      bf16x8 b1 = *(const bf16x8*)(wp + 16 * 32);
#pragma unroll
      for (int mf = 0; mf < MF; mf++) {
        bf16x8 a = *(const bf16x8*)&S[kb][mf * 16 + mr][acol];
        a0[mf] = __builtin_amdgcn_mfma_f32_16x16x32_bf16(a, b0, a0[mf], 0, 0, 0);
        a1[mf] = __builtin_amdgcn_mfma_f32_16x16x32_bf16(a, b1, a1[mf], 0, 0, 0);
      }
    }
    const float2 rbp = *(const float2*)&rad_b[n0 + m2];
#pragma unroll
    for (int mf = 0; mf < MF; mf++)
#pragma unroll
      for (int r = 0; r < 4; r++) {
        int e = mf * 16 + quad * 4 + r;
        int pc2 = ((((m2) >> 3) ^ ((e >> 1) & 3)) << 3) | (m2 & 7);
        float inv = 1.f / s_rn[e];
        *(__hip_bfloat162*)&S[8 + wave][e][pc2] =
            mk_bf162((a0[mf][r] + rbp.x) * inv, (a1[mf][r] + rbp.y) * inv);
      }
  }
  __syncthreads();

  // ---- phase 3: stage h_row -> S[0..3], h_col -> S[4..7] ----
  {
    const int m = t >> 2, part = t & 3;
    if (m < TM) {
      const int pc = ((part ^ ((m >> 1) & 3)) << 3);
      const __hip_bfloat16* hr = hb + (size_t)s_row[m] * 128 + part * 8;
      const __hip_bfloat16* hc = hb + (size_t)s_col[m] * 128 + part * 8;
#pragma unroll
      for (int kb = 0; kb < 4; kb++) {
        *(int4*)&S[kb][m][pc]     = *(const int4*)&hr[kb * 32];
        *(int4*)&S[4 + kb][m][pc] = *(const int4*)&hc[kb * 32];
      }
    }
  }
  __syncthreads();

  // ---- stage 1: ef1 = silu(A @ e_w1 + e_b1), K=384, M=48 (acc in regs) ----
  f32x4 s1a0[MF], s1a1[MF];
#pragma unroll
  for (int mf = 0; mf < MF; mf++) { s1a0[mf] = zacc; s1a1[mf] = zacc; }
#pragma unroll
  for (int kb = 0; kb < 12; kb++) {
    const __hip_bfloat16* wp = wz_e1 + ((size_t)(kb * 128 + n0 + mr) * 32 + quad * 8);
    bf16x8 b0 = *(const bf16x8*)wp;
    bf16x8 b1 = *(const bf16x8*)(wp + 16 * 32);
#pragma unroll
    for (int mf = 0; mf < MF; mf++) {
      bf16x8 a = *(const bf16x8*)&S[kb][mf * 16 + mr][acol];
      s1a0[mf] = __builtin_amdgcn_mfma_f32_16x16x32_bf16(a, b0, s1a0[mf], 0, 0, 0);
      s1a1[mf] = __builtin_amdgcn_mfma_f32_16x16x32_bf16(a, b1, s1a1[mf], 0, 0, 0);
    }
  }
  __syncthreads();  // all waves done reading A before ef1 overwrites S[0..3]
  {
    const float2 b1p = *(const float2*)&e_b1[n0 + m2];
#pragma unroll
    for (int mf = 0; mf < MF; mf++)
#pragma unroll
      for (int r = 0; r < 4; r++) {
        int e = mf * 16 + quad * 4 + r;
        int pc2 = (((m2 >> 3) ^ ((e >> 1) & 3)) << 3) | (m2 & 7);
        *(__hip_bfloat162*)&S[wave][e][pc2] =
            mk_bf162(siluf(s1a0[mf][r] + b1p.x), siluf(s1a1[mf][r] + b1p.y));
      }
  }
  __syncthreads();

  // ---- stage 2: ef2 = silu(ef1 @ e_w2 + e_b2) -> S[4..7]; gate partials ----
  const float2 awp = *(const float2*)&att_w[n0 + m2];
  {
    f32x4 a0[MF], a1[MF];
#pragma unroll
    for (int mf = 0; mf < MF; mf++) { a0[mf] = zacc; a1[mf] = zacc; }
#pragma unroll
    for (int kb = 0; kb < 4; kb++) {
      const __hip_bfloat16* wp = wz_e2 + ((size_t)(kb * 128 + n0 + mr) * 32 + quad * 8);
      bf16x8 b0 = *(const bf16x8*)wp;
      bf16x8 b1 = *(const bf16x8*)(wp + 16 * 32);
#pragma unroll
      for (int mf = 0; mf < MF; mf++) {
        bf16x8 a = *(const bf16x8*)&S[kb][mf * 16 + mr][acol];
        a0[mf] = __builtin_amdgcn_mfma_f32_16x16x32_bf16(a, b0, a0[mf], 0, 0, 0);
        a1[mf] = __builtin_amdgcn_mfma_f32_16x16x32_bf16(a, b1, a1[mf], 0, 0, 0);
      }
    }
    const float2 b2p = *(const float2*)&e_b2[n0 + m2];
    float part[MF][4];
#pragma unroll
    for (int mf = 0; mf < MF; mf++)
#pragma unroll
      for (int r = 0; r < 4; r++) {
        int e = mf * 16 + quad * 4 + r;
        int pc2 = (((m2 >> 3) ^ ((e >> 1) & 3)) << 3) | (m2 & 7);
        float v0 = siluf(a0[mf][r] + b2p.x);
        float v1 = siluf(a1[mf][r] + b2p.y);
        *(__hip_bfloat162*)&S[4 + wave][e][pc2] = mk_bf162(v0, v1);
        part[mf][r] = v0 * awp.x + v1 * awp.y;
      }
#pragma unroll
    for (int msk = 1; msk < 16; msk <<= 1)
#pragma unroll
      for (int mf = 0; mf < MF; mf++)
#pragma unroll
        for (int r = 0; r < 4; r++) part[mf][r] += __shfl_xor(part[mf][r], msk);
    if (mr == 0) {
#pragma unroll
      for (int mf = 0; mf < MF; mf++)
#pragma unroll
        for (int r = 0; r < 4; r++)
          s_red[wave][mf * 16 + quad * 4 + r] = part[mf][r];
    }
  }
  __syncthreads();
  if (t < TM) {
    float s = s_red[0][t] + s_red[1][t] + s_red[2][t] + s_red[3][t];
    s_att[t] = sigmf(s + att_b[0]);
  }
  __syncthreads();

  // ---- stage 3: cmh = silu(att*(ef2 @ c_w1) + c_b1) -> S[8..11] ----
  {
    f32x4 a0[MF], a1[MF];
#pragma unroll
    for (int mf = 0; mf < MF; mf++) { a0[mf] = zacc; a1[mf] = zacc; }
#pragma unroll
    for (int kb = 0; kb < 4; kb++) {
      const __hip_bfloat16* wp = wz_c1 + ((size_t)(kb * 128 + n0 + mr) * 32 + quad * 8);
      bf16x8 b0 = *(const bf16x8*)wp;
      bf16x8 b1 = *(const bf16x8*)(wp + 16 * 32);
#pragma unroll
      for (int mf = 0; mf < MF; mf++) {
        bf16x8 a = *(const bf16x8*)&S[4 + kb][mf * 16 + mr][acol];
        a0[mf] = __builtin_amdgcn_mfma_f32_16x16x32_bf16(a, b0, a0[mf], 0, 0, 0);
        a1[mf] = __builtin_amdgcn_mfma_f32_16x16x32_bf16(a, b1, a1[mf], 0, 0, 0);
      }
    }
    const float2 cbp = *(const float2*)&c_b1[n0 + m2];
#pragma unroll
    for (int mf = 0; mf < MF; mf++)
#pragma unroll
      for (int r = 0; r < 4; r++) {
        int e = mf * 16 + quad * 4 + r;
        int pc2 = (((m2 >> 3) ^ ((e >> 1) & 3)) << 3) | (m2 & 7);
        float av = s_att[e];
        *(__hip_bfloat162*)&S[8 + wave][e][pc2] =
            mk_bf162(siluf(av * a0[mf][r] + cbp.x), siluf(av * a1[mf][r] + cbp.y));
      }
  }
  __syncthreads();

  // ---- cm = cmh @ c_w2 + c_b2 (waves 0..2, one 16-row tile each) ----
  if (wave < MF) {
    f32x4 acc = zacc;
#pragma unroll
    for (int kb = 0; kb < 4; kb++) {
      bf16x8 a = *(const bf16x8*)&S[8 + kb][wave * 16 + mr][acol];
      bf16x8 b = *(const bf16x8*)(wz_c2 + ((size_t)(kb * 16 + mr) * 32 + quad * 8));
      acc = __builtin_amdgcn_mfma_f32_16x16x32_bf16(a, b, acc, 0, 0, 0);
    }
    if (mr < 14) {
      float bias = c_b2[mr];
#pragma unroll
      for (int r = 0; r < 4; r++)
        s_cm[(wave * 16 + quad * 4 + r) * 14 + mr] = acc[r] + bias;
    }
  }
  __syncthreads();

  // ---- RollerPooling ----
  for (int i = t; i < TM * 14; i += 256) {
    int e = i / 14, c = i % 14;
    int wsz = 15 - s_cs[e];
    int hi = min(c + wsz, 14);
    float s = 0.f;
    for (int j = c; j < hi; j++) s += s_cm[e * 14 + j];
    s_pool[e * 14 + c] = s / (float)wsz;
  }
  __syncthreads();

  // ---- trans scatter (x re-gathered from L2; packed bf16 atomics) ----
  for (int i = t; i < TM * 21; i += 256) {
    int e = i / 21, pr = i % 21;
    if (e < ne) {
      int r0 = pr * 2, r1 = r0 + 1;
      const float* xp = x + (size_t)s_row[e] * 42;
      const float* pc = pooled_x + (size_t)s_col[e] * 3;
      float v0 = (xp[r0] - pc[r0 % 3]) * s_pool[e * 14 + r0 / 3];
      float v1 = (xp[r1] - pc[r1 % 3]) * s_pool[e * 14 + r1 / 3];
      unsafeAtomicAdd(&x_acc[(size_t)s_row[e] * 21 + pr], mk_bf162(v0, v1));
    }
  }
  // ---- agg scatter (gated ef2 from S[4..7], swizzled reads) ----
  for (int i = t; i < TM * 64; i += 256) {
    int e = i >> 6, o2 = i & 63;
    if (e < ne) {
      float av = s_att[e];
      int c = (o2 & 15) * 2;
      int pc = (((c >> 3) ^ ((e >> 1) & 3)) << 3) | (c & 7);
      const __hip_bfloat16* wp2 = &S[4 + (o2 >> 4)][e][pc];
      float v0 = __bfloat162float(wp2[0]) * av;
      float v1 = __bfloat162float(wp2[1]) * av;
      unsafeAtomicAdd(&agg[(size_t)s_col[e] * 64 + o2], mk_bf162(v0, v1));
    }
  }
}

// ---- k_node: TN=64 node MLP (M=64) + residual + 16-lane LN x4 + x_new ----
__global__ __launch_bounds__(256, 3) void k_node(
    const float* __restrict__ h, const __hip_bfloat16* __restrict__ hb,
    const __hip_bfloat162* __restrict__ agg,
    const unsigned* __restrict__ cnt_col,
    const __hip_bfloat16* __restrict__ wz_n1, const float* __restrict__ n_b1,
    const __hip_bfloat16* __restrict__ wz_n2, const float* __restrict__ n_b2,
    const float* __restrict__ ln_g, const float* __restrict__ ln_b,
    const float* __restrict__ x, const __hip_bfloat162* __restrict__ x_acc,
    const unsigned* __restrict__ cnt_row,
    float* __restrict__ out_h, float* __restrict__ out_x, int Nn) {
  __shared__ __hip_bfloat16 S[12][TN][32];
  float* s_o = (float*)&S[0][0][0];  // [64][128] f32 over S[0..7], col-swizzled

  const int t = threadIdx.x;
  const int nb0 = blockIdx.x * TN;
  const int nn = min(TN, Nn - nb0);
  const int lane = t & 63, wave = t >> 6, quad = lane >> 4, mr = lane & 15;
  const int n0 = wave * 32;
  const int m2 = 2 * mr;
  const f32x4 zacc = {0.f, 0.f, 0.f, 0.f};

  // fused x_new
  for (int i = t; i < TN * 21; i += 256) {
    int n = i / 21, pr = i % 21;
    if (n < nn) {
      int gn = nb0 + n;
      unsigned c = cnt_row[gn];
      float inv = 1.f / (float)(c > 0 ? c : 1);
      float2 xa = __bfloat1622float2(x_acc[(size_t)gn * 21 + pr]);
      size_t gi = (size_t)gn * 42 + pr * 2;
      out_x[gi]     = x[gi] + xa.x * inv;
      out_x[gi + 1] = x[gi + 1] + xa.y * inv;
    }
  }

  // ---- A staging: hb -> S[0..3], agg/deg -> S[4..7] (swizzled cols) ----
  {
    const int m = t >> 2, part = t & 3;
    const int gn = nb0 + min(m, nn - 1);
    const int pc = ((part ^ ((m >> 1) & 3)) << 3);
    const __hip_bfloat16* hr = hb + (size_t)gn * 128 + part * 8;
    unsigned c = cnt_col[gn];
    float inv = 1.f / (float)(c > 0 ? c : 1);
    const __hip_bfloat162* ag = agg + (size_t)gn * 64 + part * 4;
#pragma unroll
    for (int kb = 0; kb < 4; kb++) {
      *(int4*)&S[kb][m][pc] = *(const int4*)&hr[kb * 32];
      float2 f0 = __bfloat1622float2(ag[kb * 16 + 0]);
      float2 f1 = __bfloat1622float2(ag[kb * 16 + 1]);
      float2 f2 = __bfloat1622float2(ag[kb * 16 + 2]);
      float2 f3 = __bfloat1622float2(ag[kb * 16 + 3]);
      __hip_bfloat162 pk[4];
      pk[0] = mk_bf162(f0.x * inv, f0.y * inv);
      pk[1] = mk_bf162(f1.x * inv, f1.y * inv);
      pk[2] = mk_bf162(f2.x * inv, f2.y * inv);
      pk[3] = mk_bf162(f3.x * inv, f3.y * inv);
      *(int4*)&S[4 + kb][m][pc] = *(int4*)pk;
    }
  }
  __syncthreads();

  const int acol = ((quad ^ ((mr >> 1) & 3)) << 3);  // swizzled frag-read col

  // ---- stage 1: ef1 = silu(A @ n_w1 + n_b1), K=256, M=64 -> S[8..11] ----
  {
    f32x4 a0[4], a1[4];
#pragma unroll
    for (int mf = 0; mf < 4; mf++) { a0[mf] = zacc; a1[mf] = zacc; }
#pragma unroll
    for (int kb = 0; kb < 8; kb++) {
      const __hip_bfloat16* wp = wz_n1 + ((size_t)(kb * 128 + n0 + mr) * 32 + quad * 8);
      bf16x8 b0 = *(const bf16x8*)wp;
      bf16x8 b1 = *(const bf16x8*)(wp + 16 * 32);
#pragma unroll
      for (int mf = 0; mf < 4; mf++) {
        bf16x8 a = *(const bf16x8*)&S[kb][mf * 16 + mr][acol];
        a0[mf] = __builtin_amdgcn_mfma_f32_16x16x32_bf16(a, b0, a0[mf], 0, 0, 0);
        a1[mf] = __builtin_amdgcn_mfma_f32_16x16x32_bf16(a, b1, a1[mf], 0, 0, 0);
      }
    }
    // writes go to S[8..11] (disjoint from A reads) -> no barrier needed here
    const float2 b1p = *(const float2*)&n_b1[n0 + m2];
#pragma unroll
    for (int mf = 0; mf < 4; mf++)
#pragma unroll
      for (int r = 0; r < 4; r++) {
        int e = mf * 16 + quad * 4 + r;
        int pc2 = (((m2 >> 3) ^ ((e >> 1) & 3)) << 3) | (m2 & 7);
        *(__hip_bfloat162*)&S[8 + wave][e][pc2] =
            mk_bf162(siluf(a0[mf][r] + b1p.x), siluf(a1[mf][r] + b1p.y));
      }
  }
  __syncthreads();

  // ---- stage 2: nh = ef1 @ n_w2 + n_b2 -> s_o f32 (S[0..7], col-swizzled) ----
  {
    f32x4 a0[4], a1[4];
#pragma unroll
    for (int mf = 0; mf < 4; mf++) { a0[mf] = zacc; a1[mf] = zacc; }
#pragma unroll
    for (int kb = 0; kb < 4; kb++) {
      const __hip_bfloat16* wp = wz_n2 + ((size_t)(kb * 128 + n0 + mr) * 32 + quad * 8);
      bf16x8 b0 = *(const bf16x8*)wp;
      bf16x8 b1 = *(const bf16x8*)(wp + 16 * 32);
#pragma unroll
      for (int mf = 0; mf < 4; mf++) {
        bf16x8 a = *(const bf16x8*)&S[8 + kb][mf * 16 + mr][acol];
        a0[mf] = __builtin_amdgcn_mfma_f32_16x16x32_bf16(a, b0, a0[mf], 0, 0, 0);
        a1[mf] = __builtin_amdgcn_mfma_f32_16x16x32_bf16(a, b1, a1[mf], 0, 0, 0);
      }
    }
    const float2 b2p = *(const float2*)&n_b2[n0 + m2];
#pragma unroll
    for (int mf = 0; mf < 4; mf++)
#pragma unroll
      for (int r = 0; r < 4; r++) {
        int e = mf * 16 + quad * 4 + r;
        int s = (e & 3) ^ ((e >> 2) & 3);
        int colp = (n0 + m2) ^ (s << 3);
        *(float2*)&s_o[e * 128 + colp] =
            make_float2(a0[mf][r] + b2p.x, a1[mf][r] + b2p.y);
      }
  }
  __syncthreads();

  // ---- LayerNorm: 16 lanes/node (v[8]), looped over 4 groups of 16 nodes ----
#pragma unroll 1
  for (int g = 0; g < 4; g++) {
    int n = g * 16 + (t >> 4), p = t & 15;
    int gn = nb0 + min(n, nn - 1);
    int sw = (n & 3) ^ ((n >> 2) & 3);
    const float* op = s_o + n * 128 + ((p ^ sw) << 3);
    const float* hp = h + (size_t)gn * 128 + p * 8;
    float v[8];
    float s = 0.f;
#pragma unroll
    for (int j = 0; j < 8; j++) {
      v[j] = op[j] + hp[j];
      s += v[j];
    }
    s += __shfl_xor(s, 1); s += __shfl_xor(s, 2);
    s += __shfl_xor(s, 4); s += __shfl_xor(s, 8);
    float mu = s * (1.f / 128.f);
    float var = 0.f;
#pragma unroll
    for (int j = 0; j < 8; j++) {
      float d = v[j] - mu;
      var += d * d;
    }
    var += __shfl_xor(var, 1); var += __shfl_xor(var, 2);
    var += __shfl_xor(var, 4); var += __shfl_xor(var, 8);
    float rs = rsqrtf(var * (1.f / 128.f) + 1e-5f);
    if (n < nn) {
      size_t base = (size_t)gn * 128 + p * 8;
#pragma unroll
      for (int j = 0; j < 8; j++)
        out_h[base + j] = (v[j] - mu) * rs * ln_g[p * 8 + j] + ln_b[p * 8 + j];
    }
  }
}

extern "C" void kernel_launch(void* const* d_in, const int* in_sizes, int n_in,
                              void* d_out, int out_size, void* d_ws, size_t ws_size,
                              hipStream_t stream) {
  const float* h     = (const float*)d_in[0];
  const float* x     = (const float*)d_in[1];
  const float* attr  = (const float*)d_in[2];
  const float* cw    = (const float*)d_in[3];
  const int*   row   = (const int*)d_in[4];
  const int*   col   = (const int*)d_in[5];
  const float* rad_w = (const float*)d_in[6];
  const float* rad_b = (const float*)d_in[7];
  const float* e_w1  = (const float*)d_in[8];
  const float* e_b1  = (const float*)d_in[9];
  const float* e_w2  = (const float*)d_in[10];
  const float* e_b2  = (const float*)d_in[11];
  const float* att_w = (const float*)d_in[12];
  const float* att_b = (const float*)d_in[13];
  const float* c_w1  = (const float*)d_in[14];
  const float* c_b1  = (const float*)d_in[15];
  const float* c_w2  = (const float*)d_in[16];
  const float* c_b2  = (const float*)d_in[17];
  const float* n_w1  = (const float*)d_in[18];
  const float* n_b1  = (const float*)d_in[19];
  const float* n_w2  = (const float*)d_in[20];
  const float* n_b2  = (const float*)d_in[21];
  const float* ln_g  = (const float*)d_in[22];
  const float* ln_b  = (const float*)d_in[23];

  const int N = in_sizes[0] / 128;
  const int E = in_sizes[4];

  char* ws = (char*)d_ws;
  size_t off = 0;
  auto alloc = [&](size_t bytes) {
    size_t o = off;
    off += (bytes + 255) & ~(size_t)255;
    return o;
  };
  size_t off_wzr  = alloc(32768 * sizeof(__hip_bfloat16));
  size_t off_wz1  = alloc(49152 * sizeof(__hip_bfloat16));
  size_t off_wz2  = alloc(16384 * sizeof(__hip_bfloat16));
  size_t off_wzc  = alloc(16384 * sizeof(__hip_bfloat16));
  size_t off_wzn1 = alloc(32768 * sizeof(__hip_bfloat16));
  size_t off_wzn2 = alloc(16384 * sizeof(__hip_bfloat16));
  size_t off_wzc2 = alloc(2048 * sizeof(__hip_bfloat16));
  size_t off_atS  = alloc((size_t)N * 256 * sizeof(__hip_bfloat16));
  size_t off_hb   = alloc((size_t)N * 128 * sizeof(__hip_bfloat16));
  size_t off_px   = alloc((size_t)N * 3 * sizeof(float));
  size_t off_cs   = alloc((size_t)N * sizeof(int));
  size_t off_cntr = alloc((size_t)N * sizeof(unsigned));
  size_t off_cntc = alloc((size_t)N * sizeof(unsigned));
  size_t off_xacc = alloc((size_t)N * 21 * sizeof(__hip_bfloat162));
  size_t off_agg  = alloc((size_t)N * 64 * sizeof(__hip_bfloat162));

  __hip_bfloat16* wz_rad = (__hip_bfloat16*)(ws + off_wzr);
  __hip_bfloat16* wz_e1  = (__hip_bfloat16*)(ws + off_wz1);
  __hip_bfloat16* wz_e2  = (__hip_bfloat16*)(ws + off_wz2);
  __hip_bfloat16* wz_c1  = (__hip_bfloat16*)(ws + off_wzc);
  __hip_bfloat16* wz_n1  = (__hip_bfloat16*)(ws + off_wzn1);
  __hip_bfloat16* wz_n2  = (__hip_bfloat16*)(ws + off_wzn2);
  __hip_bfloat16* wz_c2  = (__hip_bfloat16*)(ws + off_wzc2);
  __hip_bfloat16* attrS  = (__hip_bfloat16*)(ws + off_atS);
  __hip_bfloat16* hb     = (__hip_bfloat16*)(ws + off_hb);
  float* pooled_x   = (float*)(ws + off_px);
  int* chsum        = (int*)(ws + off_cs);
  unsigned* cnt_row = (unsigned*)(ws + off_cntr);
  unsigned* cnt_col = (unsigned*)(ws + off_cntc);
  __hip_bfloat162* x_acc = (__hip_bfloat162*)(ws + off_xacc);
  __hip_bfloat162* agg   = (__hip_bfloat162*)(ws + off_agg);

  (void)hipMemsetAsync(ws + off_cntr, 0, off - off_cntr, stream);

  const int pack_items = 165888 + N * 32 + N * 16 + N;
  k_pack<<<dim3((pack_items + 255) / 256), dim3(256), 0, stream>>>(
      h, x, attr, cw, rad_w, e_w1, e_w2, c_w1, n_w1, n_w2, c_w2,
      wz_rad, wz_e1, wz_e2, wz_c1, wz_n1, wz_n2, wz_c2,
      attrS, hb, pooled_x, chsum, N);
  k_mega<<<dim3((E + TM - 1) / TM), dim3(256), 0, stream>>>(
      hb, x, attrS, row, col, pooled_x, chsum,
      wz_rad, rad_b, wz_e1, e_b1, wz_e2, e_b2, att_w, att_b,
      wz_c1, c_b1, wz_c2, c_b2, cnt_row, cnt_col, x_acc, agg, E);
  k_node<<<dim3((N + TN - 1) / TN), dim3(256), 0, stream>>>(
      h, hb, agg, cnt_col, wz_n1, n_b1, wz_n2, n_b2, ln_g, ln_b,
      x, x_acc, cnt_row, (float*)d_out, (float*)d_out + (size_t)N * 128, N);
}

// Round 10
// 325.881 us; speedup vs baseline: 1.3850x; 1.0119x over previous
//
#include <hip/hip_runtime.h>
#include <hip/hip_bf16.h>

// EnhancedGNNEncoder round 19: k_mega TM 48->32 for 6 blocks/CU.
//  - LDS 38.9 -> 25.8 KB (12 slots x 32 x 32 x 2B + extras) -> 6 blocks/CU,
//    24 waves/CU (was 16). __launch_bounds__(256,6). MF=2; einsum 8
//    edges/wave (2 batches); c2 stage on waves 0..1.
//  - Weight re-reads are L2-absorbed (r18: FETCH flat across TM 64->48);
//    L2 traffic ~9 TB/s << 34.5 ceiling.
//  - k_pack / k_node unchanged.
// MFMA 16x16x32: A[m=lane&15][k=quad*8+j], B[k=quad*8+j][n=lane&15].
// MFMA 16x16x16: A[m=lane&15][k=quad*4+j], B[k=quad*4+j][n=lane&15].
// D (both): col=lane&15, row=quad*4+reg.

#define TM 32
#define MF 2
#define TN 64

typedef __attribute__((ext_vector_type(8))) short bf16x8;
typedef __attribute__((ext_vector_type(4))) short bf16x4;
typedef __attribute__((ext_vector_type(4))) float f32x4;

__device__ __forceinline__ float siluf(float v) { return v / (1.f + __expf(-v)); }
__device__ __forceinline__ float sigmf(float v) { return 1.f / (1.f + __expf(-v)); }
__device__ __forceinline__ short f2bs(float f) {
  union { __hip_bfloat16 b; short s; } u;
  u.b = __float2bfloat16(f);
  return u.s;
}
__device__ __forceinline__ __hip_bfloat162 mk_bf162(float v0, float v1) {
  __hip_bfloat162 r;
  r.x = __float2bfloat16(v0);
  r.y = __float2bfloat16(v1);
  return r;
}

// ---- pack: weight swizzle (paired-col) + attrS + h_bf16 + per-node prep ----
__global__ __launch_bounds__(256) void k_pack(
    const float* __restrict__ h, const float* __restrict__ x,
    const float* __restrict__ attr, const float* __restrict__ cw,
    const float* __restrict__ rad_w, const float* __restrict__ e_w1,
    const float* __restrict__ e_w2, const float* __restrict__ c_w1,
    const float* __restrict__ n_w1, const float* __restrict__ n_w2,
    const float* __restrict__ c_w2,
    __hip_bfloat16* __restrict__ wz_rad, __hip_bfloat16* __restrict__ wz_e1,
    __hip_bfloat16* __restrict__ wz_e2, __hip_bfloat16* __restrict__ wz_c1,
    __hip_bfloat16* __restrict__ wz_n1, __hip_bfloat16* __restrict__ wz_n2,
    __hip_bfloat16* __restrict__ wz_c2,
    __hip_bfloat16* __restrict__ attrS, __hip_bfloat16* __restrict__ hb,
    float* __restrict__ pooled_x, int* __restrict__ chsum, int Nn) {
  int idx = blockIdx.x * 256 + threadIdx.x;
  if (idx < 165888) {  // weight swizzle
    int i = idx;
    if (i >= 163840) {  // c_w2: [128][14] -> [4][16][32], n=14,15 zero
      int base = i - 163840;
      int k = base >> 4, n = base & 15;
      wz_c2[(size_t)(k >> 5) * 512 + n * 32 + (k & 31)] =
          (n < 14) ? __float2bfloat16(c_w2[k * 14 + n]) : __float2bfloat16(0.f);
      return;
    }
    const float* W;
    __hip_bfloat16* O;
    int base;
    if (i < 32768) { W = rad_w; O = wz_rad; base = i; }
    else if (i < 81920) { W = e_w1; O = wz_e1; base = i - 32768; }
    else if (i < 98304) { W = e_w2; O = wz_e2; base = i - 81920; }
    else if (i < 114688) { W = c_w1; O = wz_c1; base = i - 98304; }
    else if (i < 147456) { W = n_w1; O = wz_n1; base = i - 114688; }
    else { W = n_w2; O = wz_n2; base = i - 147456; }
    int k = base >> 7, n = base & 127;
    // paired-col storage row: b0 slot (row g*32+mr) holds col g*32+2mr,
    // b1 slot (row g*32+16+mr) holds col g*32+2mr+1
    int nr_ = ((n >> 5) << 5) | ((n & 1) << 4) | ((n & 31) >> 1);
    O[(size_t)((k >> 5) * 128 + nr_) * 32 + (k & 31)] = __float2bfloat16(W[base]);
    return;
  }
  idx -= 165888;
  int na = Nn * 32, nh = Nn * 16;
  if (idx < na) {  // attrS: 8 outputs along channel dim, int4 write
    int n = idx >> 5, r = idx & 31, a = r >> 1, h8 = r & 1;
    __hip_bfloat16 outv[8];
#pragma unroll
    for (int j = 0; j < 8; j++) {
      int i2 = h8 * 8 + j;
      float v = 0.f;
      if (i2 < 14) v = attr[(size_t)n * 224 + i2 * 16 + a] * cw[(size_t)n * 14 + i2];
      outv[j] = __float2bfloat16(v);
    }
    *(int4*)&attrS[(size_t)n * 256 + a * 16 + h8 * 8] = *(int4*)outv;
    return;
  }
  idx -= na;
  if (idx < nh) {  // hb: 8 elems/thread, int4 write
    int n = idx >> 4, q = idx & 15;
    const float4 f0 = *(const float4*)&h[(size_t)n * 128 + q * 8];
    const float4 f1 = *(const float4*)&h[(size_t)n * 128 + q * 8 + 4];
    __hip_bfloat16 outv[8];
    outv[0] = __float2bfloat16(f0.x); outv[1] = __float2bfloat16(f0.y);
    outv[2] = __float2bfloat16(f0.z); outv[3] = __float2bfloat16(f0.w);
    outv[4] = __float2bfloat16(f1.x); outv[5] = __float2bfloat16(f1.y);
    outv[6] = __float2bfloat16(f1.z); outv[7] = __float2bfloat16(f1.w);
    *(int4*)&hb[(size_t)n * 128 + q * 8] = *(int4*)outv;
    return;
  }
  idx -= nh;
  if (idx >= Nn) return;
  int n = idx;
  int cnt = 0;
  float sx = 0.f, sy = 0.f, sz = 0.f;
#pragma unroll
  for (int c = 0; c < 14; c++) {
    float w = cw[n * 14 + c];
    if (w != 0.f) {
      cnt++;
      sx += x[n * 42 + c * 3 + 0];
      sy += x[n * 42 + c * 3 + 1];
      sz += x[n * 42 + c * 3 + 2];
    }
  }
  chsum[n] = cnt;
  float inv = 1.f / (float)(cnt > 0 ? cnt : 1);
  pooled_x[n * 3 + 0] = sx * inv;
  pooled_x[n * 3 + 1] = sy * inv;
  pooled_x[n * 3 + 2] = sz * inv;
}

// ---- k_mega: einsum + rad GEMM + edge MLP + gate + roller + scatters ----
// TM=32, 12 slots x [32][32] = 24.6 KB -> 6 blocks/CU.
__global__ __launch_bounds__(256, 6) void k_mega(
    const __hip_bfloat16* __restrict__ hb, const float* __restrict__ x,
    const __hip_bfloat16* __restrict__ attrS,
    const int* __restrict__ row, const int* __restrict__ col,
    const float* __restrict__ pooled_x, const int* __restrict__ chsum,
    const __hip_bfloat16* __restrict__ wz_rad, const float* __restrict__ rad_b,
    const __hip_bfloat16* __restrict__ wz_e1, const float* __restrict__ e_b1,
    const __hip_bfloat16* __restrict__ wz_e2, const float* __restrict__ e_b2,
    const float* __restrict__ att_w, const float* __restrict__ att_b,
    const __hip_bfloat16* __restrict__ wz_c1, const float* __restrict__ c_b1,
    const __hip_bfloat16* __restrict__ wz_c2, const float* __restrict__ c_b2,
    unsigned* __restrict__ cnt_row, unsigned* __restrict__ cnt_col,
    __hip_bfloat162* __restrict__ x_acc, __hip_bfloat162* __restrict__ agg,
    int Ee) {
  __shared__ __hip_bfloat16 S[12][TM][32];
  __shared__ float s_att[TM];
  __shared__ float s_red[4][TM];
  __shared__ float s_rn[TM];
  __shared__ int s_row[TM], s_col[TM], s_cs[TM];
  float* s_cm   = (float*)&S[0][0][0];  // [32*14] f32 = 1792 B (slot 0)
  float* s_pool = (float*)&S[1][0][0];

  const int t = threadIdx.x;
  const int e0 = blockIdx.x * TM;
  const int ne = min(TM, Ee - e0);
  const int lane = t & 63, wave = t >> 6, quad = lane >> 4, mr = lane & 15;
  const int n0 = wave * 32;
  const f32x4 zacc = {0.f, 0.f, 0.f, 0.f};
  const bf16x4 zero4 = {0, 0, 0, 0};

  // ---- phase 0: edge meta + degree atomics ----
  if (t < TM) {
    int ge = e0 + min(t, ne - 1);
    int r = row[ge], c = col[ge];
    s_row[t] = r;
    s_col[t] = c;
    s_cs[t] = chsum[r];
    if (t < ne) {
      atomicAdd(&cnt_row[r], 1u);
      atomicAdd(&cnt_col[c], 1u);
    }
  }

  // ---- phase 1: einsum via 16x16x16 MFMAs, 8 edges/wave in 2 batches ----
#pragma unroll 1
  for (int b = 0; b < MF; b++) {
    float xr0v[4], xr1v[4], xr2v[4], xc0v[4], xc1v[4], xc2v[4];
    bf16x4 bCv[4], aRv[4];
#pragma unroll
    for (int p = 0; p < 4; p++) {
      const int e = wave * (MF * 4) + b * 4 + p;
      const int ge = e0 + min(e, ne - 1);
      const int re = row[ge], ce = col[ge];  // wave-uniform -> scalar loads
      const int mrc = min(mr, 13);
      const float* xp = x + (size_t)re * 42 + mrc * 3;
      xr0v[p] = xp[0]; xr1v[p] = xp[1]; xr2v[p] = xp[2];
      const float* xq = x + (size_t)ce * 42 + mrc * 3;
      xc0v[p] = xq[0]; xc1v[p] = xq[1]; xc2v[p] = xq[2];
      // B-frag (16x16x16): attr[ch=quad*4+j][dim=mr]
      bCv[p] = *(const bf16x4*)&attrS[(size_t)ce * 256 + mr * 16 + quad * 4];
      aRv[p] = *(const bf16x4*)&attrS[(size_t)re * 256 + mr * 16 + quad * 4];
    }
#pragma unroll
    for (int p = 0; p < 4; p++) {
      const int e = wave * (MF * 4) + b * 4 + p;
      const float xr0 = xr0v[p], xr1 = xr1v[p], xr2 = xr2v[p];
      const float xc0 = xc0v[p], xc1 = xc1v[p], xc2 = xc2v[p];
      const float nr = xr0 * xr0 + xr1 * xr1 + xr2 * xr2;
      const float nc = xc0 * xc0 + xc1 * xc1 + xc2 * xc2;
      // G[quad*4+r][mr] = xc_{quad*4+r} . xr_{mr}
      bf16x4 aX = zero4, bX = zero4;
      if (quad == 0) {
        aX[0] = f2bs(xc0); aX[1] = f2bs(xc1); aX[2] = f2bs(xc2);
        bX[0] = f2bs(xr0); bX[1] = f2bs(xr1); bX[2] = f2bs(xr2);
      }
      f32x4 G = __builtin_amdgcn_mfma_f32_16x16x16bf16_1k(aX, bX, zacc, 0, 0, 0);
      // dD[r] = ||xr_mr - xc_{quad*4+r}|| -> directly the A-frag of m1
      bf16x4 aM;
#pragma unroll
      for (int r = 0; r < 4; r++) {
        float ncj = __shfl(nc, quad * 4 + r);
        aM[r] = f2bs(sqrtf(fmaxf(ncj + nr - 2.f * G[r], 0.f)));
      }
      f32x4 m1 = __builtin_amdgcn_mfma_f32_16x16x16bf16_1k(aM, bCv[p], zacc, 0, 0, 0);
      // m1 D-layout [c=quad*4+r][b=mr] IS the B-frag of the radial MFMA
      bf16x4 bM;
#pragma unroll
      for (int r = 0; r < 4; r++) bM[r] = f2bs(m1[r]);
      f32x4 rd = __builtin_amdgcn_mfma_f32_16x16x16bf16_1k(aRv[p], bM, zacc, 0, 0, 0);
      float ss = rd[0] * rd[0] + rd[1] * rd[1] + rd[2] * rd[2] + rd[3] * rd[3];
      ss += __shfl_xor(ss, 32); ss += __shfl_xor(ss, 16); ss += __shfl_xor(ss, 8);
      ss += __shfl_xor(ss, 4);  ss += __shfl_xor(ss, 2);  ss += __shfl_xor(ss, 1);
      if (lane == 0) s_rn[e] = sqrtf(ss) + 1.0f;
      // radial[a=quad*4+r][b=mr] -> feature aa*16+mr, natural order, e-swizzled
#pragma unroll
      for (int r = 0; r < 4; r++) {
        const int aa = quad * 4 + r;
        const int c = ((aa & 1) << 4) | mr;
        const int pcol = (((c >> 3) ^ ((e >> 1) & 3)) << 3) | (c & 7);
        S[aa >> 1][e][pcol] = __float2bfloat16(rd[r]);
      }
    }
  }
  __syncthreads();

  const int acol = ((quad ^ ((mr >> 1) & 3)) << 3);  // swizzled frag-read col
  const int m2 = 2 * mr;                             // paired output col base

  // ---- phase 2: rad GEMM radial@rad_w -> radf in S[8..11] (packed writes) ----
  {
    f32x4 a0[MF], a1[MF];
#pragma unroll
    for (int mf = 0; mf < MF; mf++) { a0[mf] = zacc; a1[mf] = zacc; }
#pragma unroll
    for (int kb = 0; kb < 8; kb++) {
      const __hip_bfloat16* wp = wz_rad + ((size_t)(kb * 128 + n0 + mr) * 32 + quad * 8);
      bf16x8 b0 = *(const bf16x8*)wp;
      bf16x8 b1 = *(const bf16x8*)(wp + 16 * 32);
#pragma unroll
      for (int mf = 0; mf < MF; mf++) {
        bf16x8 a = *(const bf16x8*)&S[kb][mf * 16 + mr][acol];
        a0[mf] = __builtin_amdgcn_mfma_f32_16x16x32_bf16(a, b0, a0[mf], 0, 0, 0);
        a1[mf] = __builtin_amdgcn_mfma_f32_16x16x32_bf16(a, b1, a1[mf], 0, 0, 0);
      }
    }
    const float2 rbp = *(const float2*)&rad_b[n0 + m2];
#pragma unroll
    for (int mf = 0; mf < MF; mf++)
#pragma unroll
      for (int r = 0; r < 4; r++) {
        int e = mf * 16 + quad * 4 + r;
        int pc2 = ((((m2) >> 3) ^ ((e >> 1) & 3)) << 3) | (m2 & 7);
        float inv = 1.f / s_rn[e];
        *(__hip_bfloat162*)&S[8 + wave][e][pc2] =
            mk_bf162((a0[mf][r] + rbp.x) * inv, (a1[mf][r] + rbp.y) * inv);
      }
  }
  __syncthreads();

  // ---- phase 3: stage h_row -> S[0..3], h_col -> S[4..7] ----
  {
    const int m = t >> 2, part = t & 3;
    if (m < TM) {
      const int pc = ((part ^ ((m >> 1) & 3)) << 3);
      const __hip_bfloat16* hr = hb + (size_t)s_row[m] * 128 + part * 8;
      const __hip_bfloat16* hc = hb + (size_t)s_col[m] * 128 + part * 8;
#pragma unroll
      for (int kb = 0; kb < 4; kb++) {
        *(int4*)&S[kb][m][pc]     = *(const int4*)&hr[kb * 32];
        *(int4*)&S[4 + kb][m][pc] = *(const int4*)&hc[kb * 32];
      }
    }
  }
  __syncthreads();

  // ---- stage 1: ef1 = silu(A @ e_w1 + e_b1), K=384, M=32 (acc in regs) ----
  f32x4 s1a0[MF], s1a1[MF];
#pragma unroll
  for (int mf = 0; mf < MF; mf++) { s1a0[mf] = zacc; s1a1[mf] = zacc; }
#pragma unroll
  for (int kb = 0; kb < 12; kb++) {
    const __hip_bfloat16* wp = wz_e1 + ((size_t)(kb * 128 + n0 + mr) * 32 + quad * 8);
    bf16x8 b0 = *(const bf16x8*)wp;
    bf16x8 b1 = *(const bf16x8*)(wp + 16 * 32);
#pragma unroll
    for (int mf = 0; mf < MF; mf++) {
      bf16x8 a = *(const bf16x8*)&S[kb][mf * 16 + mr][acol];
      s1a0[mf] = __builtin_amdgcn_mfma_f32_16x16x32_bf16(a, b0, s1a0[mf], 0, 0, 0);
      s1a1[mf] = __builtin_amdgcn_mfma_f32_16x16x32_bf16(a, b1, s1a1[mf], 0, 0, 0);
    }
  }
  __syncthreads();  // all waves done reading A before ef1 overwrites S[0..3]
  {
    const float2 b1p = *(const float2*)&e_b1[n0 + m2];
#pragma unroll
    for (int mf = 0; mf < MF; mf++)
#pragma unroll
      for (int r = 0; r < 4; r++) {
        int e = mf * 16 + quad * 4 + r;
        int pc2 = (((m2 >> 3) ^ ((e >> 1) & 3)) << 3) | (m2 & 7);
        *(__hip_bfloat162*)&S[wave][e][pc2] =
            mk_bf162(siluf(s1a0[mf][r] + b1p.x), siluf(s1a1[mf][r] + b1p.y));
      }
  }
  __syncthreads();

  // ---- stage 2: ef2 = silu(ef1 @ e_w2 + e_b2) -> S[4..7]; gate partials ----
  const float2 awp = *(const float2*)&att_w[n0 + m2];
  {
    f32x4 a0[MF], a1[MF];
#pragma unroll
    for (int mf = 0; mf < MF; mf++) { a0[mf] = zacc; a1[mf] = zacc; }
#pragma unroll
    for (int kb = 0; kb < 4; kb++) {
      const __hip_bfloat16* wp = wz_e2 + ((size_t)(kb * 128 + n0 + mr) * 32 + quad * 8);
      bf16x8 b0 = *(const bf16x8*)wp;
      bf16x8 b1 = *(const bf16x8*)(wp + 16 * 32);
#pragma unroll
      for (int mf = 0; mf < MF; mf++) {
        bf16x8 a = *(const bf16x8*)&S[kb][mf * 16 + mr][acol];
        a0[mf] = __builtin_amdgcn_mfma_f32_16x16x32_bf16(a, b0, a0[mf], 0, 0, 0);
        a1[mf] = __builtin_amdgcn_mfma_f32_16x16x32_bf16(a, b1, a1[mf], 0, 0, 0);
      }
    }
    const float2 b2p = *(const float2*)&e_b2[n0 + m2];
    float part[MF][4];
#pragma unroll
    for (int mf = 0; mf < MF; mf++)
#pragma unroll
      for (int r = 0; r < 4; r++) {
        int e = mf * 16 + quad * 4 + r;
        int pc2 = (((m2 >> 3) ^ ((e >> 1) & 3)) << 3) | (m2 & 7);
        float v0 = siluf(a0[mf][r] + b2p.x);
        float v1 = siluf(a1[mf][r] + b2p.y);
        *(__hip_bfloat162*)&S[4 + wave][e][pc2] = mk_bf162(v0, v1);
        part[mf][r] = v0 * awp.x + v1 * awp.y;
      }
#pragma unroll
    for (int msk = 1; msk < 16; msk <<= 1)
#pragma unroll
      for (int mf = 0; mf < MF; mf++)
#pragma unroll
        for (int r = 0; r < 4; r++) part[mf][r] += __shfl_xor(part[mf][r], msk);
    if (mr == 0) {
#pragma unroll
      for (int mf = 0; mf < MF; mf++)
#pragma unroll
        for (int r = 0; r < 4; r++)
          s_red[wave][mf * 16 + quad * 4 + r] = part[mf][r];
    }
  }
  __syncthreads();
  if (t < TM) {
    float s = s_red[0][t] + s_red[1][t] + s_red[2][t] + s_red[3][t];
    s_att[t] = sigmf(s + att_b[0]);
  }
  __syncthreads();

  // ---- stage 3: cmh = silu(att*(ef2 @ c_w1) + c_b1) -> S[8..11] ----
  {
    f32x4 a0[MF], a1[MF];
#pragma unroll
    for (int mf = 0; mf < MF; mf++) { a0[mf] = zacc; a1[mf] = zacc; }
#pragma unroll
    for (int kb = 0; kb < 4; kb++) {
      const __hip_bfloat16* wp = wz_c1 + ((size_t)(kb * 128 + n0 + mr) * 32 + quad * 8);
      bf16x8 b0 = *(const bf16x8*)wp;
      bf16x8 b1 = *(const bf16x8*)(wp + 16 * 32);
#pragma unroll
      for (int mf = 0; mf < MF; mf++) {
        bf16x8 a = *(const bf16x8*)&S[4 + kb][mf * 16 + mr][acol];
        a0[mf] = __builtin_amdgcn_mfma_f32_16x16x32_bf16(a, b0, a0[mf], 0, 0, 0);
        a1[mf] = __builtin_amdgcn_mfma_f32_16x16x32_bf16(a, b1, a1[mf], 0, 0, 0);
      }
    }
    const float2 cbp = *(const float2*)&c_b1[n0 + m2];
#pragma unroll
    for (int mf = 0; mf < MF; mf++)
#pragma unroll
      for (int r = 0; r < 4; r++) {
        int e = mf * 16 + quad * 4 + r;
        int pc2 = (((m2 >> 3) ^ ((e >> 1) & 3)) << 3) | (m2 & 7);
        float av = s_att[e];
        *(__hip_bfloat162*)&S[8 + wave][e][pc2] =
            mk_bf162(siluf(av * a0[mf][r] + cbp.x), siluf(av * a1[mf][r] + cbp.y));
      }
  }
  __syncthreads();

  // ---- cm = cmh @ c_w2 + c_b2 (waves 0..1, one 16-row tile each) ----
  if (wave < MF) {
    f32x4 acc = zacc;
#pragma unroll
    for (int kb = 0; kb < 4; kb++) {
      bf16x8 a = *(const bf16x8*)&S[8 + kb][wave * 16 + mr][acol];
      bf16x8 b = *(const bf16x8*)(wz_c2 + ((size_t)(kb * 16 + mr) * 32 + quad * 8));
      acc = __builtin_amdgcn_mfma_f32_16x16x32_bf16(a, b, acc, 0, 0, 0);
    }
    if (mr < 14) {
      float bias = c_b2[mr];
#pragma unroll
      for (int r = 0; r < 4; r++)
        s_cm[(wave * 16 + quad * 4 + r) * 14 + mr] = acc[r] + bias;
    }
  }
  __syncthreads();

  // ---- RollerPooling ----
  for (int i = t; i < TM * 14; i += 256) {
    int e = i / 14, c = i % 14;
    int wsz = 15 - s_cs[e];
    int hi = min(c + wsz, 14);
    float s = 0.f;
    for (int j = c; j < hi; j++) s += s_cm[e * 14 + j];
    s_pool[e * 14 + c] = s / (float)wsz;
  }
  __syncthreads();

  // ---- trans scatter (x re-gathered from L2; packed bf16 atomics) ----
  for (int i = t; i < TM * 21; i += 256) {
    int e = i / 21, pr = i % 21;
    if (e < ne) {
      int r0 = pr * 2, r1 = r0 + 1;
      const float* xp = x + (size_t)s_row[e] * 42;
      const float* pc = pooled_x + (size_t)s_col[e] * 3;
      float v0 = (xp[r0] - pc[r0 % 3]) * s_pool[e * 14 + r0 / 3];
      float v1 = (xp[r1] - pc[r1 % 3]) * s_pool[e * 14 + r1 / 3];
      unsafeAtomicAdd(&x_acc[(size_t)s_row[e] * 21 + pr], mk_bf162(v0, v1));
    }
  }
  // ---- agg scatter (gated ef2 from S[4..7], swizzled reads) ----
  for (int i = t; i < TM * 64; i += 256) {
    int e = i >> 6, o2 = i & 63;
    if (e < ne) {
      float av = s_att[e];
      int c = (o2 & 15) * 2;
      int pc = (((c >> 3) ^ ((e >> 1) & 3)) << 3) | (c & 7);
      const __hip_bfloat16* wp2 = &S[4 + (o2 >> 4)][e][pc];
      float v0 = __bfloat162float(wp2[0]) * av;
      float v1 = __bfloat162float(wp2[1]) * av;
      unsafeAtomicAdd(&agg[(size_t)s_col[e] * 64 + o2], mk_bf162(v0, v1));
    }
  }
}

// ---- k_node: TN=64 node MLP (M=64) + residual + 16-lane LN x4 + x_new ----
__global__ __launch_bounds__(256, 3) void k_node(
    const float* __restrict__ h, const __hip_bfloat16* __restrict__ hb,
    const __hip_bfloat162* __restrict__ agg,
    const unsigned* __restrict__ cnt_col,
    const __hip_bfloat16* __restrict__ wz_n1, const float* __restrict__ n_b1,
    const __hip_bfloat16* __restrict__ wz_n2, const float* __restrict__ n_b2,
    const float* __restrict__ ln_g, const float* __restrict__ ln_b,
    const float* __restrict__ x, const __hip_bfloat162* __restrict__ x_acc,
    const unsigned* __restrict__ cnt_row,
    float* __restrict__ out_h, float* __restrict__ out_x, int Nn) {
  __shared__ __hip_bfloat16 S[12][TN][32];
  float* s_o = (float*)&S[0][0][0];  // [64][128] f32 over S[0..7], col-swizzled

  const int t = threadIdx.x;
  const int nb0 = blockIdx.x * TN;
  const int nn = min(TN, Nn - nb0);
  const int lane = t & 63, wave = t >> 6, quad = lane >> 4, mr = lane & 15;
  const int n0 = wave * 32;
  const int m2 = 2 * mr;
  const f32x4 zacc = {0.f, 0.f, 0.f, 0.f};

  // fused x_new
  for (int i = t; i < TN * 21; i += 256) {
    int n = i / 21, pr = i % 21;
    if (n < nn) {
      int gn = nb0 + n;
      unsigned c = cnt_row[gn];
      float inv = 1.f / (float)(c > 0 ? c : 1);
      float2 xa = __bfloat1622float2(x_acc[(size_t)gn * 21 + pr]);
      size_t gi = (size_t)gn * 42 + pr * 2;
      out_x[gi]     = x[gi] + xa.x * inv;
      out_x[gi + 1] = x[gi + 1] + xa.y * inv;
    }
  }

  // ---- A staging: hb -> S[0..3], agg/deg -> S[4..7] (swizzled cols) ----
  {
    const int m = t >> 2, part = t & 3;
    const int gn = nb0 + min(m, nn - 1);
    const int pc = ((part ^ ((m >> 1) & 3)) << 3);
    const __hip_bfloat16* hr = hb + (size_t)gn * 128 + part * 8;
    unsigned c = cnt_col[gn];
    float inv = 1.f / (float)(c > 0 ? c : 1);
    const __hip_bfloat162* ag = agg + (size_t)gn * 64 + part * 4;
#pragma unroll
    for (int kb = 0; kb < 4; kb++) {
      *(int4*)&S[kb][m][pc] = *(const int4*)&hr[kb * 32];
      float2 f0 = __bfloat1622float2(ag[kb * 16 + 0]);
      float2 f1 = __bfloat1622float2(ag[kb * 16 + 1]);
      float2 f2 = __bfloat1622float2(ag[kb * 16 + 2]);
      float2 f3 = __bfloat1622float2(ag[kb * 16 + 3]);
      __hip_bfloat162 pk[4];
      pk[0] = mk_bf162(f0.x * inv, f0.y * inv);
      pk[1] = mk_bf162(f1.x * inv, f1.y * inv);
      pk[2] = mk_bf162(f2.x * inv, f2.y * inv);
      pk[3] = mk_bf162(f3.x * inv, f3.y * inv);
      *(int4*)&S[4 + kb][m][pc] = *(int4*)pk;
    }
  }
  __syncthreads();

  const int acol = ((quad ^ ((mr >> 1) & 3)) << 3);  // swizzled frag-read col

  // ---- stage 1: ef1 = silu(A @ n_w1 + n_b1), K=256, M=64 -> S[8..11] ----
  {
    f32x4 a0[4], a1[4];
#pragma unroll
    for (int mf = 0; mf < 4; mf++) { a0[mf] = zacc; a1[mf] = zacc; }
#pragma unroll
    for (int kb = 0; kb < 8; kb++) {
      const __hip_bfloat16* wp = wz_n1 + ((size_t)(kb * 128 + n0 + mr) * 32 + quad * 8);
      bf16x8 b0 = *(const bf16x8*)wp;
      bf16x8 b1 = *(const bf16x8*)(wp + 16 * 32);
#pragma unroll
      for (int mf = 0; mf < 4; mf++) {
        bf16x8 a = *(const bf16x8*)&S[kb][mf * 16 + mr][acol];
        a0[mf] = __builtin_amdgcn_mfma_f32_16x16x32_bf16(a, b0, a0[mf], 0, 0, 0);
        a1[mf] = __builtin_amdgcn_mfma_f32_16x16x32_bf16(a, b1, a1[mf], 0, 0, 0);
      }
    }
    // writes go to S[8..11] (disjoint from A reads) -> no barrier needed here
    const float2 b1p = *(const float2*)&n_b1[n0 + m2];
#pragma unroll
    for (int mf = 0; mf < 4; mf++)
#pragma unroll
      for (int r = 0; r < 4; r++) {
        int e = mf * 16 + quad * 4 + r;
        int pc2 = (((m2 >> 3) ^ ((e >> 1) & 3)) << 3) | (m2 & 7);
        *(__hip_bfloat162*)&S[8 + wave][e][pc2] =
            mk_bf162(siluf(a0[mf][r] + b1p.x), siluf(a1[mf][r] + b1p.y));
      }
  }
  __syncthreads();

  // ---- stage 2: nh = ef1 @ n_w2 + n_b2 -> s_o f32 (S[0..7], col-swizzled) ----
  {
    f32x4 a0[4], a1[4];
#pragma unroll
    for (int mf = 0; mf < 4; mf++) { a0[mf] = zacc; a1[mf] = zacc; }
#pragma unroll
    for (int kb = 0; kb < 4; kb++) {
      const __hip_bfloat16* wp = wz_n2 + ((size_t)(kb * 128 + n0 + mr) * 32 + quad * 8);
      bf16x8 b0 = *(const bf16x8*)wp;
      bf16x8 b1 = *(const bf16x8*)(wp + 16 * 32);
#pragma unroll
      for (int mf = 0; mf < 4; mf++) {
        bf16x8 a = *(const bf16x8*)&S[8 + kb][mf * 16 + mr][acol];
        a0[mf] = __builtin_amdgcn_mfma_f32_16x16x32_bf16(a, b0, a0[mf], 0, 0, 0);
        a1[mf] = __builtin_amdgcn_mfma_f32_16x16x32_bf16(a, b1, a1[mf], 0, 0, 0);
      }
    }
    const float2 b2p = *(const float2*)&n_b2[n0 + m2];
#pragma unroll
    for (int mf = 0; mf < 4; mf++)
#pragma unroll
      for (int r = 0; r < 4; r++) {
        int e = mf * 16 + quad * 4 + r;
        int s = (e & 3) ^ ((e >> 2) & 3);
        int colp = (n0 + m2) ^ (s << 3);
        *(float2*)&s_o[e * 128 + colp] =
            make_float2(a0[mf][r] + b2p.x, a1[mf][r] + b2p.y);
      }
  }
  __syncthreads();

  // ---- LayerNorm: 16 lanes/node (v[8]), looped over 4 groups of 16 nodes ----
#pragma unroll 1
  for (int g = 0; g < 4; g++) {
    int n = g * 16 + (t >> 4), p = t & 15;
    int gn = nb0 + min(n, nn - 1);
    int sw = (n & 3) ^ ((n >> 2) & 3);
    const float* op = s_o + n * 128 + ((p ^ sw) << 3);
    const float* hp = h + (size_t)gn * 128 + p * 8;
    float v[8];
    float s = 0.f;
#pragma unroll
    for (int j = 0; j < 8; j++) {
      v[j] = op[j] + hp[j];
      s += v[j];
    }
    s += __shfl_xor(s, 1); s += __shfl_xor(s, 2);
    s += __shfl_xor(s, 4); s += __shfl_xor(s, 8);
    float mu = s * (1.f / 128.f);
    float var = 0.f;
#pragma unroll
    for (int j = 0; j < 8; j++) {
      float d = v[j] - mu;
      var += d * d;
    }
    var += __shfl_xor(var, 1); var += __shfl_xor(var, 2);
    var += __shfl_xor(var, 4); var += __shfl_xor(var, 8);
    float rs = rsqrtf(var * (1.f / 128.f) + 1e-5f);
    if (n < nn) {
      size_t base = (size_t)gn * 128 + p * 8;
#pragma unroll
      for (int j = 0; j < 8; j++)
        out_h[base + j] = (v[j] - mu) * rs * ln_g[p * 8 + j] + ln_b[p * 8 + j];
    }
  }
}

extern "C" void kernel_launch(void* const* d_in, const int* in_sizes, int n_in,
                              void* d_out, int out_size, void* d_ws, size_t ws_size,
                              hipStream_t stream) {
  const float* h     = (const float*)d_in[0];
  const float* x     = (const float*)d_in[1];
  const float* attr  = (const float*)d_in[2];
  const float* cw    = (const float*)d_in[3];
  const int*   row   = (const int*)d_in[4];
  const int*   col   = (const int*)d_in[5];
  const float* rad_w = (const float*)d_in[6];
  const float* rad_b = (const float*)d_in[7];
  const float* e_w1  = (const float*)d_in[8];
  const float* e_b1  = (const float*)d_in[9];
  const float* e_w2  = (const float*)d_in[10];
  const float* e_b2  = (const float*)d_in[11];
  const float* att_w = (const float*)d_in[12];
  const float* att_b = (const float*)d_in[13];
  const float* c_w1  = (const float*)d_in[14];
  const float* c_b1  = (const float*)d_in[15];
  const float* c_w2  = (const float*)d_in[16];
  const float* c_b2  = (const float*)d_in[17];
  const float* n_w1  = (const float*)d_in[18];
  const float* n_b1  = (const float*)d_in[19];
  const float* n_w2  = (const float*)d_in[20];
  const float* n_b2  = (const float*)d_in[21];
  const float* ln_g  = (const float*)d_in[22];
  const float* ln_b  = (const float*)d_in[23];

  const int N = in_sizes[0] / 128;
  const int E = in_sizes[4];

  char* ws = (char*)d_ws;
  size_t off = 0;
  auto alloc = [&](size_t bytes) {
    size_t o = off;
    off += (bytes + 255) & ~(size_t)255;
    return o;
  };
  size_t off_wzr  = alloc(32768 * sizeof(__hip_bfloat16));
  size_t off_wz1  = alloc(49152 * sizeof(__hip_bfloat16));
  size_t off_wz2  = alloc(16384 * sizeof(__hip_bfloat16));
  size_t off_wzc  = alloc(16384 * sizeof(__hip_bfloat16));
  size_t off_wzn1 = alloc(32768 * sizeof(__hip_bfloat16));
  size_t off_wzn2 = alloc(16384 * sizeof(__hip_bfloat16));
  size_t off_wzc2 = alloc(2048 * sizeof(__hip_bfloat16));
  size_t off_atS  = alloc((size_t)N * 256 * sizeof(__hip_bfloat16));
  size_t off_hb   = alloc((size_t)N * 128 * sizeof(__hip_bfloat16));
  size_t off_px   = alloc((size_t)N * 3 * sizeof(float));
  size_t off_cs   = alloc((size_t)N * sizeof(int));
  size_t off_cntr = alloc((size_t)N * sizeof(unsigned));
  size_t off_cntc = alloc((size_t)N * sizeof(unsigned));
  size_t off_xacc = alloc((size_t)N * 21 * sizeof(__hip_bfloat162));
  size_t off_agg  = alloc((size_t)N * 64 * sizeof(__hip_bfloat162));

  __hip_bfloat16* wz_rad = (__hip_bfloat16*)(ws + off_wzr);
  __hip_bfloat16* wz_e1  = (__hip_bfloat16*)(ws + off_wz1);
  __hip_bfloat16* wz_e2  = (__hip_bfloat16*)(ws + off_wz2);
  __hip_bfloat16* wz_c1  = (__hip_bfloat16*)(ws + off_wzc);
  __hip_bfloat16* wz_n1  = (__hip_bfloat16*)(ws + off_wzn1);
  __hip_bfloat16* wz_n2  = (__hip_bfloat16*)(ws + off_wzn2);
  __hip_bfloat16* wz_c2  = (__hip_bfloat16*)(ws + off_wzc2);
  __hip_bfloat16* attrS  = (__hip_bfloat16*)(ws + off_atS);
  __hip_bfloat16* hb     = (__hip_bfloat16*)(ws + off_hb);
  float* pooled_x   = (float*)(ws + off_px);
  int* chsum        = (int*)(ws + off_cs);
  unsigned* cnt_row = (unsigned*)(ws + off_cntr);
  unsigned* cnt_col = (unsigned*)(ws + off_cntc);
  __hip_bfloat162* x_acc = (__hip_bfloat162*)(ws + off_xacc);
  __hip_bfloat162* agg   = (__hip_bfloat162*)(ws + off_agg);

  (void)hipMemsetAsync(ws + off_cntr, 0, off - off_cntr, stream);

  const int pack_items = 165888 + N * 32 + N * 16 + N;
  k_pack<<<dim3((pack_items + 255) / 256), dim3(256), 0, stream>>>(
      h, x, attr, cw, rad_w, e_w1, e_w2, c_w1, n_w1, n_w2, c_w2,
      wz_rad, wz_e1, wz_e2, wz_c1, wz_n1, wz_n2, wz_c2,
      attrS, hb, pooled_x, chsum, N);
  k_mega<<<dim3((E + TM - 1) / TM), dim3(256), 0, stream>>>(
      hb, x, attrS, row, col, pooled_x, chsum,
      wz_rad, rad_b, wz_e1, e_b1, wz_e2, e_b2, att_w, att_b,
      wz_c1, c_b1, wz_c2, c_b2, cnt_row, cnt_col, x_acc, agg, E);
  k_node<<<dim3((N + TN - 1) / TN), dim3(256), 0, stream>>>(
      h, hb, agg, cnt_col, wz_n1, n_b1, wz_n2, n_b2, ln_g, ln_b,
      x, x_acc, cnt_row, (float*)d_out, (float*)d_out + (size_t)N * 128, N);
}

// Round 11
// 318.392 us; speedup vs baseline: 1.4175x; 1.0235x over previous
//
#include <hip/hip_runtime.h>
#include <hip/hip_bf16.h>

// EnhancedGNNEncoder round 20: k_node TN 64->32 for 6 blocks/CU.
//  - k_node LDS 49.2 -> 24.6 KB (12 slots x 32 x 32 x 2B) -> 6 blocks/CU
//    (was 3). __launch_bounds__(256,6). Staging at 8 threads/row (4 hb parts +
//    4 agg parts); stage loops MF=2; s_o = [32][128] f32 exactly fills
//    S[0..7]; LN over 2 groups of 16 nodes. Weight re-reads x2 (L2-absorbed
//    per r18 FETCH-flat evidence).
//  - k_mega (TM=32, 6 blocks/CU) and k_pack unchanged from round 19.
// MFMA 16x16x32: A[m=lane&15][k=quad*8+j], B[k=quad*8+j][n=lane&15].
// MFMA 16x16x16: A[m=lane&15][k=quad*4+j], B[k=quad*4+j][n=lane&15].
// D (both): col=lane&15, row=quad*4+reg.

#define TM 32
#define MF 2
#define TN 32

typedef __attribute__((ext_vector_type(8))) short bf16x8;
typedef __attribute__((ext_vector_type(4))) short bf16x4;
typedef __attribute__((ext_vector_type(4))) float f32x4;

__device__ __forceinline__ float siluf(float v) { return v / (1.f + __expf(-v)); }
__device__ __forceinline__ float sigmf(float v) { return 1.f / (1.f + __expf(-v)); }
__device__ __forceinline__ short f2bs(float f) {
  union { __hip_bfloat16 b; short s; } u;
  u.b = __float2bfloat16(f);
  return u.s;
}
__device__ __forceinline__ __hip_bfloat162 mk_bf162(float v0, float v1) {
  __hip_bfloat162 r;
  r.x = __float2bfloat16(v0);
  r.y = __float2bfloat16(v1);
  return r;
}

// ---- pack: weight swizzle (paired-col) + attrS + h_bf16 + per-node prep ----
__global__ __launch_bounds__(256) void k_pack(
    const float* __restrict__ h, const float* __restrict__ x,
    const float* __restrict__ attr, const float* __restrict__ cw,
    const float* __restrict__ rad_w, const float* __restrict__ e_w1,
    const float* __restrict__ e_w2, const float* __restrict__ c_w1,
    const float* __restrict__ n_w1, const float* __restrict__ n_w2,
    const float* __restrict__ c_w2,
    __hip_bfloat16* __restrict__ wz_rad, __hip_bfloat16* __restrict__ wz_e1,
    __hip_bfloat16* __restrict__ wz_e2, __hip_bfloat16* __restrict__ wz_c1,
    __hip_bfloat16* __restrict__ wz_n1, __hip_bfloat16* __restrict__ wz_n2,
    __hip_bfloat16* __restrict__ wz_c2,
    __hip_bfloat16* __restrict__ attrS, __hip_bfloat16* __restrict__ hb,
    float* __restrict__ pooled_x, int* __restrict__ chsum, int Nn) {
  int idx = blockIdx.x * 256 + threadIdx.x;
  if (idx < 165888) {  // weight swizzle
    int i = idx;
    if (i >= 163840) {  // c_w2: [128][14] -> [4][16][32], n=14,15 zero
      int base = i - 163840;
      int k = base >> 4, n = base & 15;
      wz_c2[(size_t)(k >> 5) * 512 + n * 32 + (k & 31)] =
          (n < 14) ? __float2bfloat16(c_w2[k * 14 + n]) : __float2bfloat16(0.f);
      return;
    }
    const float* W;
    __hip_bfloat16* O;
    int base;
    if (i < 32768) { W = rad_w; O = wz_rad; base = i; }
    else if (i < 81920) { W = e_w1; O = wz_e1; base = i - 32768; }
    else if (i < 98304) { W = e_w2; O = wz_e2; base = i - 81920; }
    else if (i < 114688) { W = c_w1; O = wz_c1; base = i - 98304; }
    else if (i < 147456) { W = n_w1; O = wz_n1; base = i - 114688; }
    else { W = n_w2; O = wz_n2; base = i - 147456; }
    int k = base >> 7, n = base & 127;
    // paired-col storage row: b0 slot (row g*32+mr) holds col g*32+2mr,
    // b1 slot (row g*32+16+mr) holds col g*32+2mr+1
    int nr_ = ((n >> 5) << 5) | ((n & 1) << 4) | ((n & 31) >> 1);
    O[(size_t)((k >> 5) * 128 + nr_) * 32 + (k & 31)] = __float2bfloat16(W[base]);
    return;
  }
  idx -= 165888;
  int na = Nn * 32, nh = Nn * 16;
  if (idx < na) {  // attrS: 8 outputs along channel dim, int4 write
    int n = idx >> 5, r = idx & 31, a = r >> 1, h8 = r & 1;
    __hip_bfloat16 outv[8];
#pragma unroll
    for (int j = 0; j < 8; j++) {
      int i2 = h8 * 8 + j;
      float v = 0.f;
      if (i2 < 14) v = attr[(size_t)n * 224 + i2 * 16 + a] * cw[(size_t)n * 14 + i2];
      outv[j] = __float2bfloat16(v);
    }
    *(int4*)&attrS[(size_t)n * 256 + a * 16 + h8 * 8] = *(int4*)outv;
    return;
  }
  idx -= na;
  if (idx < nh) {  // hb: 8 elems/thread, int4 write
    int n = idx >> 4, q = idx & 15;
    const float4 f0 = *(const float4*)&h[(size_t)n * 128 + q * 8];
    const float4 f1 = *(const float4*)&h[(size_t)n * 128 + q * 8 + 4];
    __hip_bfloat16 outv[8];
    outv[0] = __float2bfloat16(f0.x); outv[1] = __float2bfloat16(f0.y);
    outv[2] = __float2bfloat16(f0.z); outv[3] = __float2bfloat16(f0.w);
    outv[4] = __float2bfloat16(f1.x); outv[5] = __float2bfloat16(f1.y);
    outv[6] = __float2bfloat16(f1.z); outv[7] = __float2bfloat16(f1.w);
    *(int4*)&hb[(size_t)n * 128 + q * 8] = *(int4*)outv;
    return;
  }
  idx -= nh;
  if (idx >= Nn) return;
  int n = idx;
  int cnt = 0;
  float sx = 0.f, sy = 0.f, sz = 0.f;
#pragma unroll
  for (int c = 0; c < 14; c++) {
    float w = cw[n * 14 + c];
    if (w != 0.f) {
      cnt++;
      sx += x[n * 42 + c * 3 + 0];
      sy += x[n * 42 + c * 3 + 1];
      sz += x[n * 42 + c * 3 + 2];
    }
  }
  chsum[n] = cnt;
  float inv = 1.f / (float)(cnt > 0 ? cnt : 1);
  pooled_x[n * 3 + 0] = sx * inv;
  pooled_x[n * 3 + 1] = sy * inv;
  pooled_x[n * 3 + 2] = sz * inv;
}

// ---- k_mega: einsum + rad GEMM + edge MLP + gate + roller + scatters ----
// TM=32, 12 slots x [32][32] = 24.6 KB -> 6 blocks/CU.
__global__ __launch_bounds__(256, 6) void k_mega(
    const __hip_bfloat16* __restrict__ hb, const float* __restrict__ x,
    const __hip_bfloat16* __restrict__ attrS,
    const int* __restrict__ row, const int* __restrict__ col,
    const float* __restrict__ pooled_x, const int* __restrict__ chsum,
    const __hip_bfloat16* __restrict__ wz_rad, const float* __restrict__ rad_b,
    const __hip_bfloat16* __restrict__ wz_e1, const float* __restrict__ e_b1,
    const __hip_bfloat16* __restrict__ wz_e2, const float* __restrict__ e_b2,
    const float* __restrict__ att_w, const float* __restrict__ att_b,
    const __hip_bfloat16* __restrict__ wz_c1, const float* __restrict__ c_b1,
    const __hip_bfloat16* __restrict__ wz_c2, const float* __restrict__ c_b2,
    unsigned* __restrict__ cnt_row, unsigned* __restrict__ cnt_col,
    __hip_bfloat162* __restrict__ x_acc, __hip_bfloat162* __restrict__ agg,
    int Ee) {
  __shared__ __hip_bfloat16 S[12][TM][32];
  __shared__ float s_att[TM];
  __shared__ float s_red[4][TM];
  __shared__ float s_rn[TM];
  __shared__ int s_row[TM], s_col[TM], s_cs[TM];
  float* s_cm   = (float*)&S[0][0][0];  // [32*14] f32 = 1792 B (slot 0)
  float* s_pool = (float*)&S[1][0][0];

  const int t = threadIdx.x;
  const int e0 = blockIdx.x * TM;
  const int ne = min(TM, Ee - e0);
  const int lane = t & 63, wave = t >> 6, quad = lane >> 4, mr = lane & 15;
  const int n0 = wave * 32;
  const f32x4 zacc = {0.f, 0.f, 0.f, 0.f};
  const bf16x4 zero4 = {0, 0, 0, 0};

  // ---- phase 0: edge meta + degree atomics ----
  if (t < TM) {
    int ge = e0 + min(t, ne - 1);
    int r = row[ge], c = col[ge];
    s_row[t] = r;
    s_col[t] = c;
    s_cs[t] = chsum[r];
    if (t < ne) {
      atomicAdd(&cnt_row[r], 1u);
      atomicAdd(&cnt_col[c], 1u);
    }
  }

  // ---- phase 1: einsum via 16x16x16 MFMAs, 8 edges/wave in 2 batches ----
#pragma unroll 1
  for (int b = 0; b < MF; b++) {
    float xr0v[4], xr1v[4], xr2v[4], xc0v[4], xc1v[4], xc2v[4];
    bf16x4 bCv[4], aRv[4];
#pragma unroll
    for (int p = 0; p < 4; p++) {
      const int e = wave * (MF * 4) + b * 4 + p;
      const int ge = e0 + min(e, ne - 1);
      const int re = row[ge], ce = col[ge];  // wave-uniform -> scalar loads
      const int mrc = min(mr, 13);
      const float* xp = x + (size_t)re * 42 + mrc * 3;
      xr0v[p] = xp[0]; xr1v[p] = xp[1]; xr2v[p] = xp[2];
      const float* xq = x + (size_t)ce * 42 + mrc * 3;
      xc0v[p] = xq[0]; xc1v[p] = xq[1]; xc2v[p] = xq[2];
      // B-frag (16x16x16): attr[ch=quad*4+j][dim=mr]
      bCv[p] = *(const bf16x4*)&attrS[(size_t)ce * 256 + mr * 16 + quad * 4];
      aRv[p] = *(const bf16x4*)&attrS[(size_t)re * 256 + mr * 16 + quad * 4];
    }
#pragma unroll
    for (int p = 0; p < 4; p++) {
      const int e = wave * (MF * 4) + b * 4 + p;
      const float xr0 = xr0v[p], xr1 = xr1v[p], xr2 = xr2v[p];
      const float xc0 = xc0v[p], xc1 = xc1v[p], xc2 = xc2v[p];
      const float nr = xr0 * xr0 + xr1 * xr1 + xr2 * xr2;
      const float nc = xc0 * xc0 + xc1 * xc1 + xc2 * xc2;
      // G[quad*4+r][mr] = xc_{quad*4+r} . xr_{mr}
      bf16x4 aX = zero4, bX = zero4;
      if (quad == 0) {
        aX[0] = f2bs(xc0); aX[1] = f2bs(xc1); aX[2] = f2bs(xc2);
        bX[0] = f2bs(xr0); bX[1] = f2bs(xr1); bX[2] = f2bs(xr2);
      }
      f32x4 G = __builtin_amdgcn_mfma_f32_16x16x16bf16_1k(aX, bX, zacc, 0, 0, 0);
      // dD[r] = ||xr_mr - xc_{quad*4+r}|| -> directly the A-frag of m1
      bf16x4 aM;
#pragma unroll
      for (int r = 0; r < 4; r++) {
        float ncj = __shfl(nc, quad * 4 + r);
        aM[r] = f2bs(sqrtf(fmaxf(ncj + nr - 2.f * G[r], 0.f)));
      }
      f32x4 m1 = __builtin_amdgcn_mfma_f32_16x16x16bf16_1k(aM, bCv[p], zacc, 0, 0, 0);
      // m1 D-layout [c=quad*4+r][b=mr] IS the B-frag of the radial MFMA
      bf16x4 bM;
#pragma unroll
      for (int r = 0; r < 4; r++) bM[r] = f2bs(m1[r]);
      f32x4 rd = __builtin_amdgcn_mfma_f32_16x16x16bf16_1k(aRv[p], bM, zacc, 0, 0, 0);
      float ss = rd[0] * rd[0] + rd[1] * rd[1] + rd[2] * rd[2] + rd[3] * rd[3];
      ss += __shfl_xor(ss, 32); ss += __shfl_xor(ss, 16); ss += __shfl_xor(ss, 8);
      ss += __shfl_xor(ss, 4);  ss += __shfl_xor(ss, 2);  ss += __shfl_xor(ss, 1);
      if (lane == 0) s_rn[e] = sqrtf(ss) + 1.0f;
      // radial[a=quad*4+r][b=mr] -> feature aa*16+mr, natural order, e-swizzled
#pragma unroll
      for (int r = 0; r < 4; r++) {
        const int aa = quad * 4 + r;
        const int c = ((aa & 1) << 4) | mr;
        const int pcol = (((c >> 3) ^ ((e >> 1) & 3)) << 3) | (c & 7);
        S[aa >> 1][e][pcol] = __float2bfloat16(rd[r]);
      }
    }
  }
  __syncthreads();

  const int acol = ((quad ^ ((mr >> 1) & 3)) << 3);  // swizzled frag-read col
  const int m2 = 2 * mr;                             // paired output col base

  // ---- phase 2: rad GEMM radial@rad_w -> radf in S[8..11] (packed writes) ----
  {
    f32x4 a0[MF], a1[MF];
#pragma unroll
    for (int mf = 0; mf < MF; mf++) { a0[mf] = zacc; a1[mf] = zacc; }
#pragma unroll
    for (int kb = 0; kb < 8; kb++) {
      const __hip_bfloat16* wp = wz_rad + ((size_t)(kb * 128 + n0 + mr) * 32 + quad * 8);
      bf16x8 b0 = *(const bf16x8*)wp;
      bf16x8 b1 = *(const bf16x8*)(wp + 16 * 32);
#pragma unroll
      for (int mf = 0; mf < MF; mf++) {
        bf16x8 a = *(const bf16x8*)&S[kb][mf * 16 + mr][acol];
        a0[mf] = __builtin_amdgcn_mfma_f32_16x16x32_bf16(a, b0, a0[mf], 0, 0, 0);
        a1[mf] = __builtin_amdgcn_mfma_f32_16x16x32_bf16(a, b1, a1[mf], 0, 0, 0);
      }
    }
    const float2 rbp = *(const float2*)&rad_b[n0 + m2];
#pragma unroll
    for (int mf = 0; mf < MF; mf++)
#pragma unroll
      for (int r = 0; r < 4; r++) {
        int e = mf * 16 + quad * 4 + r;
        int pc2 = ((((m2) >> 3) ^ ((e >> 1) & 3)) << 3) | (m2 & 7);
        float inv = 1.f / s_rn[e];
        *(__hip_bfloat162*)&S[8 + wave][e][pc2] =
            mk_bf162((a0[mf][r] + rbp.x) * inv, (a1[mf][r] + rbp.y) * inv);
      }
  }
  __syncthreads();

  // ---- phase 3: stage h_row -> S[0..3], h_col -> S[4..7] ----
  {
    const int m = t >> 2, part = t & 3;
    if (m < TM) {
      const int pc = ((part ^ ((m >> 1) & 3)) << 3);
      const __hip_bfloat16* hr = hb + (size_t)s_row[m] * 128 + part * 8;
      const __hip_bfloat16* hc = hb + (size_t)s_col[m] * 128 + part * 8;
#pragma unroll
      for (int kb = 0; kb < 4; kb++) {
        *(int4*)&S[kb][m][pc]     = *(const int4*)&hr[kb * 32];
        *(int4*)&S[4 + kb][m][pc] = *(const int4*)&hc[kb * 32];
      }
    }
  }
  __syncthreads();

  // ---- stage 1: ef1 = silu(A @ e_w1 + e_b1), K=384, M=32 (acc in regs) ----
  f32x4 s1a0[MF], s1a1[MF];
#pragma unroll
  for (int mf = 0; mf < MF; mf++) { s1a0[mf] = zacc; s1a1[mf] = zacc; }
#pragma unroll
  for (int kb = 0; kb < 12; kb++) {
    const __hip_bfloat16* wp = wz_e1 + ((size_t)(kb * 128 + n0 + mr) * 32 + quad * 8);
    bf16x8 b0 = *(const bf16x8*)wp;
    bf16x8 b1 = *(const bf16x8*)(wp + 16 * 32);
#pragma unroll
    for (int mf = 0; mf < MF; mf++) {
      bf16x8 a = *(const bf16x8*)&S[kb][mf * 16 + mr][acol];
      s1a0[mf] = __builtin_amdgcn_mfma_f32_16x16x32_bf16(a, b0, s1a0[mf], 0, 0, 0);
      s1a1[mf] = __builtin_amdgcn_mfma_f32_16x16x32_bf16(a, b1, s1a1[mf], 0, 0, 0);
    }
  }
  __syncthreads();  // all waves done reading A before ef1 overwrites S[0..3]
  {
    const float2 b1p = *(const float2*)&e_b1[n0 + m2];
#pragma unroll
    for (int mf = 0; mf < MF; mf++)
#pragma unroll
      for (int r = 0; r < 4; r++) {
        int e = mf * 16 + quad * 4 + r;
        int pc2 = (((m2 >> 3) ^ ((e >> 1) & 3)) << 3) | (m2 & 7);
        *(__hip_bfloat162*)&S[wave][e][pc2] =
            mk_bf162(siluf(s1a0[mf][r] + b1p.x), siluf(s1a1[mf][r] + b1p.y));
      }
  }
  __syncthreads();

  // ---- stage 2: ef2 = silu(ef1 @ e_w2 + e_b2) -> S[4..7]; gate partials ----
  const float2 awp = *(const float2*)&att_w[n0 + m2];
  {
    f32x4 a0[MF], a1[MF];
#pragma unroll
    for (int mf = 0; mf < MF; mf++) { a0[mf] = zacc; a1[mf] = zacc; }
#pragma unroll
    for (int kb = 0; kb < 4; kb++) {
      const __hip_bfloat16* wp = wz_e2 + ((size_t)(kb * 128 + n0 + mr) * 32 + quad * 8);
      bf16x8 b0 = *(const bf16x8*)wp;
      bf16x8 b1 = *(const bf16x8*)(wp + 16 * 32);
#pragma unroll
      for (int mf = 0; mf < MF; mf++) {
        bf16x8 a = *(const bf16x8*)&S[kb][mf * 16 + mr][acol];
        a0[mf] = __builtin_amdgcn_mfma_f32_16x16x32_bf16(a, b0, a0[mf], 0, 0, 0);
        a1[mf] = __builtin_amdgcn_mfma_f32_16x16x32_bf16(a, b1, a1[mf], 0, 0, 0);
      }
    }
    const float2 b2p = *(const float2*)&e_b2[n0 + m2];
    float part[MF][4];
#pragma unroll
    for (int mf = 0; mf < MF; mf++)
#pragma unroll
      for (int r = 0; r < 4; r++) {
        int e = mf * 16 + quad * 4 + r;
        int pc2 = (((m2 >> 3) ^ ((e >> 1) & 3)) << 3) | (m2 & 7);
        float v0 = siluf(a0[mf][r] + b2p.x);
        float v1 = siluf(a1[mf][r] + b2p.y);
        *(__hip_bfloat162*)&S[4 + wave][e][pc2] = mk_bf162(v0, v1);
        part[mf][r] = v0 * awp.x + v1 * awp.y;
      }
#pragma unroll
    for (int msk = 1; msk < 16; msk <<= 1)
#pragma unroll
      for (int mf = 0; mf < MF; mf++)
#pragma unroll
        for (int r = 0; r < 4; r++) part[mf][r] += __shfl_xor(part[mf][r], msk);
    if (mr == 0) {
#pragma unroll
      for (int mf = 0; mf < MF; mf++)
#pragma unroll
        for (int r = 0; r < 4; r++)
          s_red[wave][mf * 16 + quad * 4 + r] = part[mf][r];
    }
  }
  __syncthreads();
  if (t < TM) {
    float s = s_red[0][t] + s_red[1][t] + s_red[2][t] + s_red[3][t];
    s_att[t] = sigmf(s + att_b[0]);
  }
  __syncthreads();

  // ---- stage 3: cmh = silu(att*(ef2 @ c_w1) + c_b1) -> S[8..11] ----
  {
    f32x4 a0[MF], a1[MF];
#pragma unroll
    for (int mf = 0; mf < MF; mf++) { a0[mf] = zacc; a1[mf] = zacc; }
#pragma unroll
    for (int kb = 0; kb < 4; kb++) {
      const __hip_bfloat16* wp = wz_c1 + ((size_t)(kb * 128 + n0 + mr) * 32 + quad * 8);
      bf16x8 b0 = *(const bf16x8*)wp;
      bf16x8 b1 = *(const bf16x8*)(wp + 16 * 32);
#pragma unroll
      for (int mf = 0; mf < MF; mf++) {
        bf16x8 a = *(const bf16x8*)&S[4 + kb][mf * 16 + mr][acol];
        a0[mf] = __builtin_amdgcn_mfma_f32_16x16x32_bf16(a, b0, a0[mf], 0, 0, 0);
        a1[mf] = __builtin_amdgcn_mfma_f32_16x16x32_bf16(a, b1, a1[mf], 0, 0, 0);
      }
    }
    const float2 cbp = *(const float2*)&c_b1[n0 + m2];
#pragma unroll
    for (int mf = 0; mf < MF; mf++)
#pragma unroll
      for (int r = 0; r < 4; r++) {
        int e = mf * 16 + quad * 4 + r;
        int pc2 = (((m2 >> 3) ^ ((e >> 1) & 3)) << 3) | (m2 & 7);
        float av = s_att[e];
        *(__hip_bfloat162*)&S[8 + wave][e][pc2] =
            mk_bf162(siluf(av * a0[mf][r] + cbp.x), siluf(av * a1[mf][r] + cbp.y));
      }
  }
  __syncthreads();

  // ---- cm = cmh @ c_w2 + c_b2 (waves 0..1, one 16-row tile each) ----
  if (wave < MF) {
    f32x4 acc = zacc;
#pragma unroll
    for (int kb = 0; kb < 4; kb++) {
      bf16x8 a = *(const bf16x8*)&S[8 + kb][wave * 16 + mr][acol];
      bf16x8 b = *(const bf16x8*)(wz_c2 + ((size_t)(kb * 16 + mr) * 32 + quad * 8));
      acc = __builtin_amdgcn_mfma_f32_16x16x32_bf16(a, b, acc, 0, 0, 0);
    }
    if (mr < 14) {
      float bias = c_b2[mr];
#pragma unroll
      for (int r = 0; r < 4; r++)
        s_cm[(wave * 16 + quad * 4 + r) * 14 + mr] = acc[r] + bias;
    }
  }
  __syncthreads();

  // ---- RollerPooling ----
  for (int i = t; i < TM * 14; i += 256) {
    int e = i / 14, c = i % 14;
    int wsz = 15 - s_cs[e];
    int hi = min(c + wsz, 14);
    float s = 0.f;
    for (int j = c; j < hi; j++) s += s_cm[e * 14 + j];
    s_pool[e * 14 + c] = s / (float)wsz;
  }
  __syncthreads();

  // ---- trans scatter (x re-gathered from L2; packed bf16 atomics) ----
  for (int i = t; i < TM * 21; i += 256) {
    int e = i / 21, pr = i % 21;
    if (e < ne) {
      int r0 = pr * 2, r1 = r0 + 1;
      const float* xp = x + (size_t)s_row[e] * 42;
      const float* pc = pooled_x + (size_t)s_col[e] * 3;
      float v0 = (xp[r0] - pc[r0 % 3]) * s_pool[e * 14 + r0 / 3];
      float v1 = (xp[r1] - pc[r1 % 3]) * s_pool[e * 14 + r1 / 3];
      unsafeAtomicAdd(&x_acc[(size_t)s_row[e] * 21 + pr], mk_bf162(v0, v1));
    }
  }
  // ---- agg scatter (gated ef2 from S[4..7], swizzled reads) ----
  for (int i = t; i < TM * 64; i += 256) {
    int e = i >> 6, o2 = i & 63;
    if (e < ne) {
      float av = s_att[e];
      int c = (o2 & 15) * 2;
      int pc = (((c >> 3) ^ ((e >> 1) & 3)) << 3) | (c & 7);
      const __hip_bfloat16* wp2 = &S[4 + (o2 >> 4)][e][pc];
      float v0 = __bfloat162float(wp2[0]) * av;
      float v1 = __bfloat162float(wp2[1]) * av;
      unsafeAtomicAdd(&agg[(size_t)s_col[e] * 64 + o2], mk_bf162(v0, v1));
    }
  }
}

// ---- k_node: TN=32 node MLP + residual + 16-lane LN x2 + x_new ----
// 12 slots x [32][32] = 24.6 KB -> 6 blocks/CU.
__global__ __launch_bounds__(256, 6) void k_node(
    const float* __restrict__ h, const __hip_bfloat16* __restrict__ hb,
    const __hip_bfloat162* __restrict__ agg,
    const unsigned* __restrict__ cnt_col,
    const __hip_bfloat16* __restrict__ wz_n1, const float* __restrict__ n_b1,
    const __hip_bfloat16* __restrict__ wz_n2, const float* __restrict__ n_b2,
    const float* __restrict__ ln_g, const float* __restrict__ ln_b,
    const float* __restrict__ x, const __hip_bfloat162* __restrict__ x_acc,
    const unsigned* __restrict__ cnt_row,
    float* __restrict__ out_h, float* __restrict__ out_x, int Nn) {
  __shared__ __hip_bfloat16 S[12][TN][32];
  float* s_o = (float*)&S[0][0][0];  // [32][128] f32 over S[0..7], col-swizzled

  const int t = threadIdx.x;
  const int nb0 = blockIdx.x * TN;
  const int nn = min(TN, Nn - nb0);
  const int lane = t & 63, wave = t >> 6, quad = lane >> 4, mr = lane & 15;
  const int n0 = wave * 32;
  const int m2 = 2 * mr;
  const f32x4 zacc = {0.f, 0.f, 0.f, 0.f};

  // fused x_new
  for (int i = t; i < TN * 21; i += 256) {
    int n = i / 21, pr = i % 21;
    if (n < nn) {
      int gn = nb0 + n;
      unsigned c = cnt_row[gn];
      float inv = 1.f / (float)(c > 0 ? c : 1);
      float2 xa = __bfloat1622float2(x_acc[(size_t)gn * 21 + pr]);
      size_t gi = (size_t)gn * 42 + pr * 2;
      out_x[gi]     = x[gi] + xa.x * inv;
      out_x[gi + 1] = x[gi + 1] + xa.y * inv;
    }
  }

  // ---- A staging: hb -> S[0..3], agg/deg -> S[4..7]; 8 threads/row ----
  {
    const int m = t >> 3, part = t & 7;
    const int p4 = part & 3, half = part >> 2;
    const int gn = nb0 + min(m, nn - 1);
    const int pc = ((p4 ^ ((m >> 1) & 3)) << 3);
    if (half == 0) {
      const __hip_bfloat16* hr = hb + (size_t)gn * 128 + p4 * 8;
#pragma unroll
      for (int kb = 0; kb < 4; kb++)
        *(int4*)&S[kb][m][pc] = *(const int4*)&hr[kb * 32];
    } else {
      unsigned c = cnt_col[gn];
      float inv = 1.f / (float)(c > 0 ? c : 1);
      const __hip_bfloat162* ag = agg + (size_t)gn * 64 + p4 * 4;
#pragma unroll
      for (int kb = 0; kb < 4; kb++) {
        float2 f0 = __bfloat1622float2(ag[kb * 16 + 0]);
        float2 f1 = __bfloat1622float2(ag[kb * 16 + 1]);
        float2 f2 = __bfloat1622float2(ag[kb * 16 + 2]);
        float2 f3 = __bfloat1622float2(ag[kb * 16 + 3]);
        __hip_bfloat162 pk[4];
        pk[0] = mk_bf162(f0.x * inv, f0.y * inv);
        pk[1] = mk_bf162(f1.x * inv, f1.y * inv);
        pk[2] = mk_bf162(f2.x * inv, f2.y * inv);
        pk[3] = mk_bf162(f3.x * inv, f3.y * inv);
        *(int4*)&S[4 + kb][m][pc] = *(int4*)pk;
      }
    }
  }
  __syncthreads();

  const int acol = ((quad ^ ((mr >> 1) & 3)) << 3);  // swizzled frag-read col

  // ---- stage 1: ef1 = silu(A @ n_w1 + n_b1), K=256, M=32 -> S[8..11] ----
  {
    f32x4 a0[MF], a1[MF];
#pragma unroll
    for (int mf = 0; mf < MF; mf++) { a0[mf] = zacc; a1[mf] = zacc; }
#pragma unroll
    for (int kb = 0; kb < 8; kb++) {
      const __hip_bfloat16* wp = wz_n1 + ((size_t)(kb * 128 + n0 + mr) * 32 + quad * 8);
      bf16x8 b0 = *(const bf16x8*)wp;
      bf16x8 b1 = *(const bf16x8*)(wp + 16 * 32);
#pragma unroll
      for (int mf = 0; mf < MF; mf++) {
        bf16x8 a = *(const bf16x8*)&S[kb][mf * 16 + mr][acol];
        a0[mf] = __builtin_amdgcn_mfma_f32_16x16x32_bf16(a, b0, a0[mf], 0, 0, 0);
        a1[mf] = __builtin_amdgcn_mfma_f32_16x16x32_bf16(a, b1, a1[mf], 0, 0, 0);
      }
    }
    // writes go to S[8..11] (disjoint from A reads) -> no barrier needed here
    const float2 b1p = *(const float2*)&n_b1[n0 + m2];
#pragma unroll
    for (int mf = 0; mf < MF; mf++)
#pragma unroll
      for (int r = 0; r < 4; r++) {
        int e = mf * 16 + quad * 4 + r;
        int pc2 = (((m2 >> 3) ^ ((e >> 1) & 3)) << 3) | (m2 & 7);
        *(__hip_bfloat162*)&S[8 + wave][e][pc2] =
            mk_bf162(siluf(a0[mf][r] + b1p.x), siluf(a1[mf][r] + b1p.y));
      }
  }
  __syncthreads();

  // ---- stage 2: nh = ef1 @ n_w2 + n_b2 -> s_o f32 (S[0..7], col-swizzled) ----
  {
    f32x4 a0[MF], a1[MF];
#pragma unroll
    for (int mf = 0; mf < MF; mf++) { a0[mf] = zacc; a1[mf] = zacc; }
#pragma unroll
    for (int kb = 0; kb < 4; kb++) {
      const __hip_bfloat16* wp = wz_n2 + ((size_t)(kb * 128 + n0 + mr) * 32 + quad * 8);
      bf16x8 b0 = *(const bf16x8*)wp;
      bf16x8 b1 = *(const bf16x8*)(wp + 16 * 32);
#pragma unroll
      for (int mf = 0; mf < MF; mf++) {
        bf16x8 a = *(const bf16x8*)&S[8 + kb][mf * 16 + mr][acol];
        a0[mf] = __builtin_amdgcn_mfma_f32_16x16x32_bf16(a, b0, a0[mf], 0, 0, 0);
        a1[mf] = __builtin_amdgcn_mfma_f32_16x16x32_bf16(a, b1, a1[mf], 0, 0, 0);
      }
    }
    const float2 b2p = *(const float2*)&n_b2[n0 + m2];
#pragma unroll
    for (int mf = 0; mf < MF; mf++)
#pragma unroll
      for (int r = 0; r < 4; r++) {
        int e = mf * 16 + quad * 4 + r;
        int s = (e & 3) ^ ((e >> 2) & 3);
        int colp = (n0 + m2) ^ (s << 3);
        *(float2*)&s_o[e * 128 + colp] =
            make_float2(a0[mf][r] + b2p.x, a1[mf][r] + b2p.y);
      }
  }
  __syncthreads();

  // ---- LayerNorm: 16 lanes/node (v[8]), looped over 2 groups of 16 nodes ----
#pragma unroll 1
  for (int g = 0; g < 2; g++) {
    int n = g * 16 + (t >> 4), p = t & 15;
    int gn = nb0 + min(n, nn - 1);
    int sw = (n & 3) ^ ((n >> 2) & 3);
    const float* op = s_o + n * 128 + ((p ^ sw) << 3);
    const float* hp = h + (size_t)gn * 128 + p * 8;
    float v[8];
    float s = 0.f;
#pragma unroll
    for (int j = 0; j < 8; j++) {
      v[j] = op[j] + hp[j];
      s += v[j];
    }
    s += __shfl_xor(s, 1); s += __shfl_xor(s, 2);
    s += __shfl_xor(s, 4); s += __shfl_xor(s, 8);
    float mu = s * (1.f / 128.f);
    float var = 0.f;
#pragma unroll
    for (int j = 0; j < 8; j++) {
      float d = v[j] - mu;
      var += d * d;
    }
    var += __shfl_xor(var, 1); var += __shfl_xor(var, 2);
    var += __shfl_xor(var, 4); var += __shfl_xor(var, 8);
    float rs = rsqrtf(var * (1.f / 128.f) + 1e-5f);
    if (n < nn) {
      size_t base = (size_t)gn * 128 + p * 8;
#pragma unroll
      for (int j = 0; j < 8; j++)
        out_h[base + j] = (v[j] - mu) * rs * ln_g[p * 8 + j] + ln_b[p * 8 + j];
    }
  }
}

extern "C" void kernel_launch(void* const* d_in, const int* in_sizes, int n_in,
                              void* d_out, int out_size, void* d_ws, size_t ws_size,
                              hipStream_t stream) {
  const float* h     = (const float*)d_in[0];
  const float* x     = (const float*)d_in[1];
  const float* attr  = (const float*)d_in[2];
  const float* cw    = (const float*)d_in[3];
  const int*   row   = (const int*)d_in[4];
  const int*   col   = (const int*)d_in[5];
  const float* rad_w = (const float*)d_in[6];
  const float* rad_b = (const float*)d_in[7];
  const float* e_w1  = (const float*)d_in[8];
  const float* e_b1  = (const float*)d_in[9];
  const float* e_w2  = (const float*)d_in[10];
  const float* e_b2  = (const float*)d_in[11];
  const float* att_w = (const float*)d_in[12];
  const float* att_b = (const float*)d_in[13];
  const float* c_w1  = (const float*)d_in[14];
  const float* c_b1  = (const float*)d_in[15];
  const float* c_w2  = (const float*)d_in[16];
  const float* c_b2  = (const float*)d_in[17];
  const float* n_w1  = (const float*)d_in[18];
  const float* n_b1  = (const float*)d_in[19];
  const float* n_w2  = (const float*)d_in[20];
  const float* n_b2  = (const float*)d_in[21];
  const float* ln_g  = (const float*)d_in[22];
  const float* ln_b  = (const float*)d_in[23];

  const int N = in_sizes[0] / 128;
  const int E = in_sizes[4];

  char* ws = (char*)d_ws;
  size_t off = 0;
  auto alloc = [&](size_t bytes) {
    size_t o = off;
    off += (bytes + 255) & ~(size_t)255;
    return o;
  };
  size_t off_wzr  = alloc(32768 * sizeof(__hip_bfloat16));
  size_t off_wz1  = alloc(49152 * sizeof(__hip_bfloat16));
  size_t off_wz2  = alloc(16384 * sizeof(__hip_bfloat16));
  size_t off_wzc  = alloc(16384 * sizeof(__hip_bfloat16));
  size_t off_wzn1 = alloc(32768 * sizeof(__hip_bfloat16));
  size_t off_wzn2 = alloc(16384 * sizeof(__hip_bfloat16));
  size_t off_wzc2 = alloc(2048 * sizeof(__hip_bfloat16));
  size_t off_atS  = alloc((size_t)N * 256 * sizeof(__hip_bfloat16));
  size_t off_hb   = alloc((size_t)N * 128 * sizeof(__hip_bfloat16));
  size_t off_px   = alloc((size_t)N * 3 * sizeof(float));
  size_t off_cs   = alloc((size_t)N * sizeof(int));
  size_t off_cntr = alloc((size_t)N * sizeof(unsigned));
  size_t off_cntc = alloc((size_t)N * sizeof(unsigned));
  size_t off_xacc = alloc((size_t)N * 21 * sizeof(__hip_bfloat162));
  size_t off_agg  = alloc((size_t)N * 64 * sizeof(__hip_bfloat162));

  __hip_bfloat16* wz_rad = (__hip_bfloat16*)(ws + off_wzr);
  __hip_bfloat16* wz_e1  = (__hip_bfloat16*)(ws + off_wz1);
  __hip_bfloat16* wz_e2  = (__hip_bfloat16*)(ws + off_wz2);
  __hip_bfloat16* wz_c1  = (__hip_bfloat16*)(ws + off_wzc);
  __hip_bfloat16* wz_n1  = (__hip_bfloat16*)(ws + off_wzn1);
  __hip_bfloat16* wz_n2  = (__hip_bfloat16*)(ws + off_wzn2);
  __hip_bfloat16* wz_c2  = (__hip_bfloat16*)(ws + off_wzc2);
  __hip_bfloat16* attrS  = (__hip_bfloat16*)(ws + off_atS);
  __hip_bfloat16* hb     = (__hip_bfloat16*)(ws + off_hb);
  float* pooled_x   = (float*)(ws + off_px);
  int* chsum        = (int*)(ws + off_cs);
  unsigned* cnt_row = (unsigned*)(ws + off_cntr);
  unsigned* cnt_col = (unsigned*)(ws + off_cntc);
  __hip_bfloat162* x_acc = (__hip_bfloat162*)(ws + off_xacc);
  __hip_bfloat162* agg   = (__hip_bfloat162*)(ws + off_agg);

  (void)hipMemsetAsync(ws + off_cntr, 0, off - off_cntr, stream);

  const int pack_items = 165888 + N * 32 + N * 16 + N;
  k_pack<<<dim3((pack_items + 255) / 256), dim3(256), 0, stream>>>(
      h, x, attr, cw, rad_w, e_w1, e_w2, c_w1, n_w1, n_w2, c_w2,
      wz_rad, wz_e1, wz_e2, wz_c1, wz_n1, wz_n2, wz_c2,
      attrS, hb, pooled_x, chsum, N);
  k_mega<<<dim3((E + TM - 1) / TM), dim3(256), 0, stream>>>(
      hb, x, attrS, row, col, pooled_x, chsum,
      wz_rad, rad_b, wz_e1, e_b1, wz_e2, e_b2, att_w, att_b,
      wz_c1, c_b1, wz_c2, c_b2, cnt_row, cnt_col, x_acc, agg, E);
  k_node<<<dim3((N + TN - 1) / TN), dim3(256), 0, stream>>>(
      h, hb, agg, cnt_col, wz_n1, n_b1, wz_n2, n_b2, ln_g, ln_b,
      x, x_acc, cnt_row, (float*)d_out, (float*)d_out + (size_t)N * 128, N);
}